// Round 3
// baseline (2840.307 us; speedup 1.0000x reference)
//
#include <hip/hip_runtime.h>
#include <hip/hip_bf16.h>

typedef __hip_bfloat16 bf16;

static constexpr int Nn = 2, Cc = 64, Hh = 256, Wd = 256;
static constexpr int Pp = Nn * Hh * Wd;  // 131072 pixels

__device__ inline float tof(float v) { return v; }
__device__ inline float tof(bf16 v) { return __bfloat162float(v); }
__device__ inline void sto(float* p, size_t i, float v) { p[i] = v; }
__device__ inline void sto(bf16* p, size_t i, float v) { p[i] = __float2bfloat16(v); }

// ---- NCHW f32 -> NHWC f32 ----
__global__ void k_in_tr(const float* __restrict__ xin, float* __restrict__ X) {
  int i = blockIdx.x * blockDim.x + threadIdx.x;
  if (i >= Pp * Cc) return;
  int w = i & 255, h = (i >> 8) & 255, c = (i >> 16) & 63, n = i >> 22;
  int p = (n << 16) | (h << 8) | w;
  X[(size_t)p * 64 + c] = xin[i];
}

// ---- A = X + depthwise 3x3 (pos conv), NHWC f32 ----
__global__ void k_posconv(const float* __restrict__ X, float* __restrict__ A,
                          const float* __restrict__ wt, const float* __restrict__ bs) {
  int i = blockIdx.x * blockDim.x + threadIdx.x;
  if (i >= Pp * Cc) return;
  int c = i & 63, p = i >> 6;
  int w = p & 255, h = (p >> 8) & 255, n = p >> 16;
  float acc = bs[c];
#pragma unroll
  for (int ky = 0; ky < 3; ky++) {
    int hh = h + ky - 1;
    if ((unsigned)hh >= 256u) continue;
#pragma unroll
    for (int kx = 0; kx < 3; kx++) {
      int ww = w + kx - 1;
      if ((unsigned)ww >= 256u) continue;
      acc += wt[c * 9 + ky * 3 + kx] *
             X[(size_t)((n << 16) | (hh << 8) | ww) * 64 + c];
    }
  }
  A[i] = X[i] + acc;
}

// ---- LayerNorm over C=64, one wave per pixel ----
__global__ void k_ln(const float* __restrict__ In, float* __restrict__ Out,
                     const float* __restrict__ g, const float* __restrict__ b) {
  int gid = blockIdx.x * blockDim.x + threadIdx.x;
  int pix = gid >> 6, lane = gid & 63;
  if (pix >= Pp) return;
  float v = In[(size_t)pix * 64 + lane];
  float s = v;
#pragma unroll
  for (int off = 32; off; off >>= 1) s += __shfl_xor(s, off);
  float mean = s * (1.f / 64.f);
  float d = v - mean;
  float q = d * d;
#pragma unroll
  for (int off = 32; off; off >>= 1) q += __shfl_xor(q, off);
  float var = q * (1.f / 64.f);
  Out[(size_t)pix * 64 + lane] = d * rsqrtf(var + 1e-6f) * g[lane] + b[lane];
}

// ---- per-pixel GEMM: Out[m, o] = In[m, :K] @ W[:, o] + bias[o] (+Res) ----
template <typename TIN, typename TOUT, bool RES, int K, int NC>
__global__ void k_gemm(const TIN* __restrict__ In, const float* __restrict__ W, int ldw,
                       const float* __restrict__ bias, const float* __restrict__ Res,
                       TOUT* __restrict__ Out) {
  constexpr int ncg = NC / 4;
  int i = blockIdx.x * blockDim.x + threadIdx.x;
  if (i >= Pp * ncg) return;
  int og = i % ncg, m = i / ncg;
  int o0 = og << 2;
  const TIN* in = In + (size_t)m * K;
  float acc[4];
#pragma unroll
  for (int j = 0; j < 4; j++) acc[j] = bias[o0 + j];
  for (int k = 0; k < K; k++) {
    float a = tof(in[k]);
#pragma unroll
    for (int j = 0; j < 4; j++) acc[j] += a * W[(size_t)k * ldw + o0 + j];
  }
  if (RES) {
#pragma unroll
    for (int j = 0; j < 4; j++) acc[j] += Res[(size_t)m * NC + o0 + j];
  }
#pragma unroll
  for (int j = 0; j < 4; j++) sto(Out, (size_t)m * NC + o0 + j, acc[j]);
}

// ---- 8x8 block means of LN1 output: Y8[n][32][32][64] ----
__global__ void k_pool8(const float* __restrict__ T, float* __restrict__ Y8) {
  int b = blockIdx.x;  // 2048 = n*1024 + by*32 + bx
  int c = threadIdx.x; // 64
  int bx = b & 31, by = (b >> 5) & 31, n = b >> 10;
  float acc = 0.f;
  for (int r = 0; r < 8; r++)
    for (int s = 0; s < 8; s++) {
      int p = (n << 16) | ((by * 8 + r) << 8) | (bx * 8 + s);
      acc += T[(size_t)p * 64 + c];
    }
  Y8[(size_t)b * 64 + c] = acc * (1.f / 64.f);
}

// ---- window means from Y8: Ym[n][64][64] ----
__global__ void k_poolwin(const float* __restrict__ Y8, float* __restrict__ Ym) {
  int b = blockIdx.x;  // 128 = n*64 + win
  int c = threadIdx.x;
  int win = b & 63, n = b >> 6, wi = win >> 3, wj = win & 7;
  float acc = 0.f;
  for (int ti = 0; ti < 4; ti++)
    for (int tj = 0; tj < 4; tj++) {
      int y8 = (n * 32 + wi * 4 + ti) * 32 + wj * 4 + tj;
      acc += Y8[(size_t)y8 * 64 + c];
    }
  Ym[(size_t)b * 64 + c] = acc * (1.f / 16.f);
}

// ---- QW/KW = Ym @ Wq/Wk + b (exact f32 routing means via linearity) ----
__global__ void k_qkwin(const float* __restrict__ Ym, const float* __restrict__ qw,
                        const float* __restrict__ qb, float* __restrict__ QW,
                        float* __restrict__ KW) {
  int t = blockIdx.x * blockDim.x + threadIdx.x;  // 2*64*64*2 = 16384
  if (t >= 16384) return;
  int c = t & 63, row = (t >> 6) & 127, sel = t >> 13;
  const float* y = Ym + (size_t)row * 64;
  int col = sel * 64 + c;
  float acc = qb[col];
  for (int k = 0; k < 64; k++) acc += y[k] * qw[k * 192 + col];
  (sel ? KW : QW)[(size_t)row * 64 + c] = acc;
}

// ---- pooled k/v tokens: KVP[n][win][16][128] = Y8tok @ Wkv + b ----
__global__ void k_kvp(const float* __restrict__ Y8, const float* __restrict__ qw,
                      const float* __restrict__ qb, float* __restrict__ KVP) {
  int t = blockIdx.x * blockDim.x + threadIdx.x;  // 2*64*16*128 = 262144
  if (t >= 262144) return;
  int c2 = t & 127, tok = (t >> 7) & 15, win = (t >> 11) & 63, n = t >> 17;
  int wi = win >> 3, wj = win & 7, ti = tok >> 2, tj = tok & 3;
  int y8 = (n * 32 + wi * 4 + ti) * 32 + wj * 4 + tj;
  const float* y = Y8 + (size_t)y8 * 64;
  int col = 64 + c2;
  float acc = qb[col];
  for (int k = 0; k < 64; k++) acc += y[k] * qw[k * 192 + col];
  KVP[t] = acc;
}

// ---- routing: top-4 windows per query window ----
__global__ void k_route(const float* __restrict__ QW, const float* __restrict__ KW,
                        int* __restrict__ RIDX) {
  int n = blockIdx.x;
  int qw = threadIdx.x;  // 64 threads
  const float* qv = QW + (size_t)(n * 64 + qw) * 64;
  float bv0 = -1e30f, bv1 = -1e30f, bv2 = -1e30f, bv3 = -1e30f;
  int bi0 = 0, bi1 = 0, bi2 = 0, bi3 = 0;
  for (int kw = 0; kw < 64; kw++) {
    const float* kv = KW + (size_t)(n * 64 + kw) * 64;
    float t = 0.f;
    for (int c = 0; c < 64; c++) t += qv[c] * kv[c];
    t *= 0.125f;
    if (t > bv3) {
      if (t > bv0) { bv3=bv2;bi3=bi2; bv2=bv1;bi2=bi1; bv1=bv0;bi1=bi0; bv0=t;bi0=kw; }
      else if (t > bv1) { bv3=bv2;bi3=bi2; bv2=bv1;bi2=bi1; bv1=t;bi1=kw; }
      else if (t > bv2) { bv3=bv2;bi3=bi2; bv2=t;bi2=kw; }
      else { bv3=t;bi3=kw; }
    }
  }
  int* o = RIDX + (size_t)(n * 64 + qw) * 4;
  o[0]=bi0; o[1]=bi1; o[2]=bi2; o[3]=bi3;
}

// ---- per-window attention; 4 blocks per window; K/V in LDS ----
__global__ void __launch_bounds__(256) k_attn(const float* __restrict__ Q,
                                              const float* __restrict__ KVP,
                                              const int* __restrict__ RIDX,
                                              float* __restrict__ S) {
  __shared__ float ks[64][64];
  __shared__ float vs[64][64];
  __shared__ int idx[4];
  int blk = blockIdx.x;          // 512 = (n*64+win)*4 + part
  int part = blk & 3, bw = blk >> 2;
  int n = bw >> 6, win = bw & 63;
  if (threadIdx.x < 4) idx[threadIdx.x] = RIDX[bw * 4 + threadIdx.x];
  __syncthreads();
  for (int t = threadIdx.x; t < 4096; t += 256) {
    int tok = t >> 6, c = t & 63;
    const float* src = KVP + ((size_t)(n * 64 + idx[tok >> 4]) * 16 + (tok & 15)) * 128;
    ks[tok][c] = src[c];
    vs[tok][c] = src[64 + c];
  }
  __syncthreads();
  int wi = win >> 3, wj = win & 7;
  int q = part * 256 + threadIdx.x;  // 0..1023
  int r = q >> 5, s = q & 31;
  int p = (n << 16) | ((wi * 32 + r) << 8) | (wj * 32 + s);
  const float* qp = Q + (size_t)p * 64;
  float* op = S + (size_t)p * 64;
  for (int hd = 0; hd < 8; hd++) {
    float qv[8];
#pragma unroll
    for (int d = 0; d < 8; d++) qv[d] = qp[hd * 8 + d] * 0.125f;
    float m = -1e30f, l = 0.f;
    float out[8] = {0, 0, 0, 0, 0, 0, 0, 0};
    for (int k = 0; k < 64; k++) {
      float t = 0.f;
#pragma unroll
      for (int d = 0; d < 8; d++) t += qv[d] * ks[k][hd * 8 + d];
      float nm = fmaxf(m, t);
      float corr = __expf(m - nm);
      float e = __expf(t - nm);
      l = l * corr + e;
#pragma unroll
      for (int d = 0; d < 8; d++) out[d] = out[d] * corr + e * vs[k][hd * 8 + d];
      m = nm;
    }
    float inv = 1.f / l;
#pragma unroll
    for (int d = 0; d < 8; d++) op[hd * 8 + d] = out[d] * inv;
  }
}

// ---- LePE: S += depthwise 5x5 conv of V (bf16 internal) ----
__global__ void k_lepe(const bf16* __restrict__ V, float* __restrict__ S,
                       const float* __restrict__ wt, const float* __restrict__ bs) {
  int i = blockIdx.x * blockDim.x + threadIdx.x;
  if (i >= Pp * 64) return;
  int c = i & 63, p = i >> 6;
  int w = p & 255, h = (p >> 8) & 255, n = p >> 16;
  float acc = bs[c];
#pragma unroll
  for (int ky = 0; ky < 5; ky++) {
    int hh = h + ky - 2;
    if ((unsigned)hh >= 256u) continue;
#pragma unroll
    for (int kx = 0; kx < 5; kx++) {
      int ww = w + kx - 2;
      if ((unsigned)ww >= 256u) continue;
      acc += wt[c * 25 + ky * 5 + kx] *
             tof(V[(size_t)((n << 16) | (hh << 8) | ww) * 64 + c]);
    }
  }
  S[i] += acc;
}

// ---- Wc = W1a(64x128) @ pw^T(128x128); bc = b1a @ pw^T ----
__global__ void k_combine(const float* __restrict__ f1w, const float* __restrict__ f1b,
                          const float* __restrict__ pww, float* __restrict__ Wc,
                          float* __restrict__ bc) {
  int t = blockIdx.x * blockDim.x + threadIdx.x;  // 64*128 = 8192
  if (t >= 8192) return;
  int o = t & 127, k = t >> 7;
  float acc = 0.f;
  for (int j = 0; j < 128; j++) acc += f1w[k * 256 + j] * pww[o * 128 + j];
  Wc[k * 128 + o] = acc;
  if (k == 0) {
    float b = 0.f;
    for (int j = 0; j < 128; j++) b += f1b[j] * pww[o * 128 + j];
    bc[o] = b;
  }
}

// ---- GLU tail: G = gelu(dw3(PWO)+dwb) * VH ----
__global__ void k_gludw(const bf16* __restrict__ PWO, const bf16* __restrict__ VH,
                        const float* __restrict__ wt, const float* __restrict__ bs,
                        bf16* __restrict__ G) {
  int i = blockIdx.x * blockDim.x + threadIdx.x;
  if (i >= Pp * 128) return;
  int c = i & 127, p = i >> 7;
  int w = p & 255, h = (p >> 8) & 255, n = p >> 16;
  float acc = bs[c];
#pragma unroll
  for (int ky = 0; ky < 3; ky++) {
    int hh = h + ky - 1;
    if ((unsigned)hh >= 256u) continue;
#pragma unroll
    for (int kx = 0; kx < 3; kx++) {
      int ww = w + kx - 1;
      if ((unsigned)ww >= 256u) continue;
      acc += wt[c * 9 + ky * 3 + kx] *
             tof(PWO[(size_t)((n << 16) | (hh << 8) | ww) * 128 + c]);
    }
  }
  float ge = 0.5f * acc * (1.f + erff(acc * 0.70710678118f));
  G[i] = __float2bfloat16(ge * tof(VH[(size_t)p * 128 + c]));
}

// ---- NHWC f32 -> NCHW f32 out ----
__global__ void k_out(const float* __restrict__ X, float* __restrict__ out) {
  int i = blockIdx.x * blockDim.x + threadIdx.x;
  if (i >= Pp * Cc) return;
  int w = i & 255, h = (i >> 8) & 255, c = (i >> 16) & 63, n = i >> 22;
  int p = (n << 16) | (h << 8) | w;
  out[i] = X[(size_t)p * 64 + c];
}

extern "C" void kernel_launch(void* const* d_in, const int* in_sizes, int n_in,
                              void* d_out, int out_size, void* d_ws, size_t ws_size,
                              hipStream_t stream) {
  (void)in_sizes; (void)n_in; (void)out_size; (void)ws_size;
  const float* xin = (const float*)d_in[0];
  auto Wp = [&](int i) { return (const float*)d_in[i]; };
  char* ws = (char*)d_ws;
  const size_t MB = 1u << 20;
  float* X = (float*)(ws + 0 * MB);    // trunk / Q
  float* A = (float*)(ws + 32 * MB);   // trunk-res / LN2out / G(bf16)
  float* T = (float*)(ws + 64 * MB);   // LN1out / attn-out S / VH(bf16)
  char*  R = ws + 96 * MB;             // V bf16 [P][64] then PWO bf16 [P][128]
  char* sm = ws + 128 * MB;            // smalls (~1.8MB)
  size_t off = 0;
  auto alloc = [&](size_t bytes) {
    void* p = sm + off;
    off += (bytes + 255) & ~(size_t)255;
    return p;
  };
  float* Y8  = (float*)alloc(2 * 32 * 32 * 64 * 4);
  float* Ym  = (float*)alloc(2 * 64 * 64 * 4);
  float* QW  = (float*)alloc(2 * 64 * 64 * 4);
  float* KW  = (float*)alloc(2 * 64 * 64 * 4);
  float* KVP = (float*)alloc(2 * 64 * 16 * 128 * 4);
  int*  RIDX = (int*)alloc(2 * 64 * 4 * 4);
  float* Wc  = (float*)alloc(64 * 128 * 4);
  float* bc  = (float*)alloc(128 * 4);
  bf16* Vb  = (bf16*)R;
  bf16* PWO = (bf16*)R;
  bf16* VH  = (bf16*)T;
  bf16* G   = (bf16*)A;

  auto blocks = [](long long t) { return dim3((unsigned)((t + 255) / 256)); };

  k_in_tr<<<blocks((long long)Pp * 64), 256, 0, stream>>>(xin, X);
  for (int i = 0; i < 2; i++) {
    const float *posw = Wp(1) + i * 64 * 9, *posb = Wp(2) + i * 64;
    const float *l1g = Wp(3) + i * 64, *l1b = Wp(4) + i * 64;
    const float *qkvw = Wp(5) + i * 64 * 192, *qkvb = Wp(6) + i * 192;
    const float *lpw = Wp(7) + i * 64 * 25, *lpb = Wp(8) + i * 64;
    const float *wow = Wp(9) + i * 64 * 64, *wob = Wp(10) + i * 64;
    const float *l2g = Wp(11) + i * 64, *l2b = Wp(12) + i * 64;
    const float *f1w = Wp(13) + i * 64 * 256, *f1b = Wp(14) + i * 256;
    const float *pww = Wp(15) + i * 128 * 128;
    const float *dww = Wp(16) + i * 128 * 9, *dwb = Wp(17) + i * 128;
    const float *f2w = Wp(18) + i * 128 * 64, *f2b = Wp(19) + i * 64;

    // A = X + posconv(X);  T = LN1(A)
    k_posconv<<<blocks((long long)Pp * 64), 256, 0, stream>>>(X, A, posw, posb);
    k_ln<<<blocks((long long)Pp * 64), 256, 0, stream>>>(A, T, l1g, l1b);
    // Q (f32, into X) and V (bf16, into R)
    k_gemm<float, float, false, 64, 64><<<blocks((long long)Pp * 16), 256, 0, stream>>>(
        T, qkvw, 192, qkvb, nullptr, X);
    k_gemm<float, bf16, false, 64, 64><<<blocks((long long)Pp * 16), 256, 0, stream>>>(
        T, qkvw + 128, 192, qkvb + 128, nullptr, Vb);
    // pooled stats (exact f32 via linearity)
    k_pool8<<<dim3(2048), dim3(64), 0, stream>>>(T, Y8);
    k_poolwin<<<dim3(128), dim3(64), 0, stream>>>(Y8, Ym);
    k_qkwin<<<dim3(64), dim3(256), 0, stream>>>(Ym, qkvw, qkvb, QW, KW);
    k_kvp<<<dim3(1024), dim3(256), 0, stream>>>(Y8, qkvw, qkvb, KVP);
    k_route<<<dim3(2), dim3(64), 0, stream>>>(QW, KW, RIDX);
    // attention -> S(T); += lepe(V)
    k_attn<<<dim3(512), dim3(256), 0, stream>>>(X, KVP, RIDX, T);
    k_lepe<<<blocks((long long)Pp * 64), 256, 0, stream>>>(Vb, T, lpw, lpb);
    // trunk2 = S@wo + wob + A  -> X
    k_gemm<float, float, true, 64, 64><<<blocks((long long)Pp * 16), 256, 0, stream>>>(
        T, wow, 64, wob, A, X);
    // LN2 -> A
    k_ln<<<blocks((long long)Pp * 64), 256, 0, stream>>>(X, A, l2g, l2b);
    // GLU: Wc = W1a@pw^T;  VH = A@W1b (bf16,T);  PWO = A@Wc (bf16,R)
    k_combine<<<dim3(32), dim3(256), 0, stream>>>(f1w, f1b, pww, Wc, bc);
    k_gemm<float, bf16, false, 64, 128><<<blocks((long long)Pp * 32), 256, 0, stream>>>(
        A, f1w + 128, 256, f1b + 128, nullptr, VH);
    k_gemm<float, bf16, false, 64, 128><<<blocks((long long)Pp * 32), 256, 0, stream>>>(
        A, Wc, 128, bc, nullptr, PWO);
    // G = gelu(dw3(PWO)) * VH  -> A(bf16)
    k_gludw<<<blocks((long long)Pp * 128), 256, 0, stream>>>(PWO, VH, dww, dwb, G);
    // trunk3 = G@fc2 + f2b + X -> X (in-place residual, same-thread RMW)
    k_gemm<bf16, float, true, 128, 64><<<blocks((long long)Pp * 16), 256, 0, stream>>>(
        G, f2w, 64, f2b, X, X);
  }
  k_out<<<blocks((long long)Pp * 64), 256, 0, stream>>>(X, (float*)d_out);
}

// Round 4
// 2072.634 us; speedup vs baseline: 1.3704x; 1.3704x over previous
//
#include <hip/hip_runtime.h>
#include <hip/hip_bf16.h>

typedef __hip_bfloat16 bf16;

static constexpr int Nn = 2, Hh = 256, Wd = 256;
static constexpr int Pp = Nn * Hh * Wd;  // 131072 pixels

// ---- vector load/store helpers ----
__device__ inline void ld4(const float* p, float f[4]) {
  const float4 v = *(const float4*)p;
  f[0] = v.x; f[1] = v.y; f[2] = v.z; f[3] = v.w;
}
__device__ inline void ld4(const bf16* p, float f[4]) {
  uint2 u = *(const uint2*)p;
  f[0] = __uint_as_float(u.x << 16); f[1] = __uint_as_float(u.x & 0xffff0000u);
  f[2] = __uint_as_float(u.y << 16); f[3] = __uint_as_float(u.y & 0xffff0000u);
}
__device__ inline void st4(float* p, const float f[4]) {
  *(float4*)p = make_float4(f[0], f[1], f[2], f[3]);
}
__device__ inline void st4(bf16* p, const float f[4]) {
  union { bf16 h[4]; uint2 u; } x;
  x.h[0] = __float2bfloat16(f[0]); x.h[1] = __float2bfloat16(f[1]);
  x.h[2] = __float2bfloat16(f[2]); x.h[3] = __float2bfloat16(f[3]);
  *(uint2*)p = x.u;
}

// ---- NCHW f32 -> NHWC f32, LDS-tiled (both sides coalesced) ----
__global__ void __launch_bounds__(256) k_in_tr(const float* __restrict__ xin,
                                               float* __restrict__ X) {
  __shared__ float t[64][65];
  int blk = blockIdx.x;  // n*1024 + h*4 + wt
  int wt = blk & 3, h = (blk >> 2) & 255, n = blk >> 10;
  int w0 = wt * 64;
  int tx = threadIdx.x & 63, ty = threadIdx.x >> 6;
  const float* src = xin + ((size_t)n * 64 * 256 + h) * 256 + w0;
#pragma unroll
  for (int cc = 0; cc < 16; cc++) {
    int c = cc * 4 + ty;
    t[c][tx] = src[(size_t)c * 65536 + tx];
  }
  __syncthreads();
  float* dst = X + (size_t)(n * 65536 + h * 256 + w0) * 64;
#pragma unroll
  for (int jj = 0; jj < 16; jj++) {
    int j = jj * 4 + ty;
    dst[(size_t)j * 64 + tx] = t[tx][j];
  }
}

// ---- NHWC f32 -> NCHW f32, LDS-tiled ----
__global__ void __launch_bounds__(256) k_out(const float* __restrict__ X,
                                             float* __restrict__ out) {
  __shared__ float t[64][65];
  int blk = blockIdx.x;
  int wt = blk & 3, h = (blk >> 2) & 255, n = blk >> 10;
  int w0 = wt * 64;
  int tx = threadIdx.x & 63, ty = threadIdx.x >> 6;
  const float* src = X + (size_t)(n * 65536 + h * 256 + w0) * 64;
#pragma unroll
  for (int jj = 0; jj < 16; jj++) {
    int j = jj * 4 + ty;
    t[tx][j] = src[(size_t)j * 64 + tx];
  }
  __syncthreads();
  float* dst = out + ((size_t)n * 64 * 256 + h) * 256 + w0;
#pragma unroll
  for (int cc = 0; cc < 16; cc++) {
    int c = cc * 4 + ty;
    dst[(size_t)c * 65536 + tx] = t[c][tx];
  }
}

// ---- fused: A = X + dw3x3(X);  T = LN1(A).  lane = channel ----
__global__ void __launch_bounds__(256) k_pcln(const float* __restrict__ X,
                                              float* __restrict__ A, float* __restrict__ T,
                                              const float* __restrict__ pw,
                                              const float* __restrict__ pb,
                                              const float* __restrict__ g,
                                              const float* __restrict__ b) {
  int gid = blockIdx.x * 256 + threadIdx.x;
  int pix = gid >> 6, c = gid & 63;
  int w = pix & 255, h = (pix >> 8) & 255, n = pix >> 16;
  float acc = pb[c];
#pragma unroll
  for (int ky = 0; ky < 3; ky++) {
    int hh = h + ky - 1;
    if ((unsigned)hh >= 256u) continue;
#pragma unroll
    for (int kx = 0; kx < 3; kx++) {
      int ww = w + kx - 1;
      if ((unsigned)ww >= 256u) continue;
      acc += pw[c * 9 + ky * 3 + kx] * X[(size_t)((n << 16) | (hh << 8) | ww) * 64 + c];
    }
  }
  float a = X[gid] + acc;
  A[gid] = a;
  float s = a;
#pragma unroll
  for (int off = 32; off; off >>= 1) s += __shfl_xor(s, off);
  float mean = s * (1.f / 64.f);
  float d = a - mean;
  float q = d * d;
#pragma unroll
  for (int off = 32; off; off >>= 1) q += __shfl_xor(q, off);
  float var = q * (1.f / 64.f);
  T[gid] = d * rsqrtf(var + 1e-6f) * g[c] + b[c];
}

// ---- LayerNorm (LN2) ----
__global__ void __launch_bounds__(256) k_ln(const float* __restrict__ In,
                                            float* __restrict__ Out,
                                            const float* __restrict__ g,
                                            const float* __restrict__ b) {
  int gid = blockIdx.x * 256 + threadIdx.x;
  int c = gid & 63;
  float v = In[gid];
  float s = v;
#pragma unroll
  for (int off = 32; off; off >>= 1) s += __shfl_xor(s, off);
  float mean = s * (1.f / 64.f);
  float d = v - mean;
  float q = d * d;
#pragma unroll
  for (int off = 32; off; off >>= 1) q += __shfl_xor(q, off);
  float var = q * (1.f / 64.f);
  Out[gid] = d * rsqrtf(var + 1e-6f) * g[c] + b[c];
}

// ---- vectorized single GEMM: Out = In@W + bias (+Res), f32 out ----
template <typename TIN, int K, int NC, bool RES>
__global__ void __launch_bounds__(256) k_gemm4(const TIN* __restrict__ In,
                                               const float* __restrict__ W,
                                               const float* __restrict__ bias,
                                               const float* __restrict__ Res,
                                               float* __restrict__ Out) {
  constexpr int NG = NC / 4;
  int i = blockIdx.x * 256 + threadIdx.x;
  int og = i % NG, m = i / NG;
  int o0 = og << 2;
  const TIN* in = In + (size_t)m * K;
  float acc[4] = {bias[o0], bias[o0 + 1], bias[o0 + 2], bias[o0 + 3]};
  for (int k = 0; k < K; k += 4) {
    float a[4];
    ld4(in + k, a);
#pragma unroll
    for (int kk = 0; kk < 4; kk++) {
      const float4 wv = *(const float4*)&W[(size_t)(k + kk) * NC + o0];
      acc[0] += a[kk] * wv.x; acc[1] += a[kk] * wv.y;
      acc[2] += a[kk] * wv.z; acc[3] += a[kk] * wv.w;
    }
  }
  if (RES) {
    const float4 r = *(const float4*)&Res[(size_t)m * 64 + o0];
    acc[0] += r.x; acc[1] += r.y; acc[2] += r.z; acc[3] += r.w;
  }
  st4(Out + (size_t)m * NC + o0, acc);
}

// ---- vectorized dual-output GEMM (reads In once, two weight sets) ----
template <int K, int N1, int N2, typename TO1, typename TO2>
__global__ void __launch_bounds__(256) k_dual(const float* __restrict__ In,
                                              const float* __restrict__ W1, int ldw1,
                                              const float* __restrict__ b1,
                                              TO1* __restrict__ O1,
                                              const float* __restrict__ W2, int ldw2,
                                              const float* __restrict__ b2,
                                              TO2* __restrict__ O2) {
  constexpr int NG = (N1 + N2) / 4;
  int i = blockIdx.x * 256 + threadIdx.x;
  int og = i % NG, m = i / NG;
  const float* in = In + (size_t)m * K;
  bool first = og < N1 / 4;
  const float* W = first ? W1 : W2;
  const float* bp = first ? b1 : b2;
  int ldw = first ? ldw1 : ldw2;
  int o0 = (first ? og : og - N1 / 4) << 2;
  float acc[4] = {bp[o0], bp[o0 + 1], bp[o0 + 2], bp[o0 + 3]};
  for (int k = 0; k < K; k += 4) {
    const float4 a = *(const float4*)&in[k];
    float av[4] = {a.x, a.y, a.z, a.w};
#pragma unroll
    for (int kk = 0; kk < 4; kk++) {
      const float4 wv = *(const float4*)&W[(size_t)(k + kk) * ldw + o0];
      acc[0] += av[kk] * wv.x; acc[1] += av[kk] * wv.y;
      acc[2] += av[kk] * wv.z; acc[3] += av[kk] * wv.w;
    }
  }
  if (first) st4(O1 + (size_t)m * N1 + o0, acc);
  else       st4(O2 + (size_t)m * N2 + o0, acc);
}

// ---- 8x8 block means of LN1 output: Y8[n][32][32][64] ----
__global__ void k_pool8(const float* __restrict__ T, float* __restrict__ Y8) {
  int b = blockIdx.x;
  int c = threadIdx.x;
  int bx = b & 31, by = (b >> 5) & 31, n = b >> 10;
  float acc = 0.f;
  for (int r = 0; r < 8; r++)
    for (int s = 0; s < 8; s++) {
      int p = (n << 16) | ((by * 8 + r) << 8) | (bx * 8 + s);
      acc += T[(size_t)p * 64 + c];
    }
  Y8[(size_t)b * 64 + c] = acc * (1.f / 64.f);
}

// ---- window means from Y8 ----
__global__ void k_poolwin(const float* __restrict__ Y8, float* __restrict__ Ym) {
  int b = blockIdx.x;
  int c = threadIdx.x;
  int win = b & 63, n = b >> 6, wi = win >> 3, wj = win & 7;
  float acc = 0.f;
  for (int ti = 0; ti < 4; ti++)
    for (int tj = 0; tj < 4; tj++) {
      int y8 = (n * 32 + wi * 4 + ti) * 32 + wj * 4 + tj;
      acc += Y8[(size_t)y8 * 64 + c];
    }
  Ym[(size_t)b * 64 + c] = acc * (1.f / 16.f);
}

// ---- QW/KW = Ym @ Wq/Wk + b (exact f32 routing) ----
__global__ void k_qkwin(const float* __restrict__ Ym, const float* __restrict__ qw,
                        const float* __restrict__ qb, float* __restrict__ QW,
                        float* __restrict__ KW) {
  int t = blockIdx.x * blockDim.x + threadIdx.x;
  if (t >= 16384) return;
  int c = t & 63, row = (t >> 6) & 127, sel = t >> 13;
  const float* y = Ym + (size_t)row * 64;
  int col = sel * 64 + c;
  float acc = qb[col];
  for (int k = 0; k < 64; k++) acc += y[k] * qw[k * 192 + col];
  (sel ? KW : QW)[(size_t)row * 64 + c] = acc;
}

// ---- pooled k/v tokens: KVP[n][win][16][128] ----
__global__ void k_kvp(const float* __restrict__ Y8, const float* __restrict__ qw,
                      const float* __restrict__ qb, float* __restrict__ KVP) {
  int t = blockIdx.x * blockDim.x + threadIdx.x;
  if (t >= 262144) return;
  int c2 = t & 127, tok = (t >> 7) & 15, win = (t >> 11) & 63, n = t >> 17;
  int wi = win >> 3, wj = win & 7, ti = tok >> 2, tj = tok & 3;
  int y8 = (n * 32 + wi * 4 + ti) * 32 + wj * 4 + tj;
  const float* y = Y8 + (size_t)y8 * 64;
  int col = 64 + c2;
  float acc = qb[col];
  for (int k = 0; k < 64; k++) acc += y[k] * qw[k * 192 + col];
  KVP[t] = acc;
}

// ---- routing: top-4 windows per query window ----
__global__ void k_route(const float* __restrict__ QW, const float* __restrict__ KW,
                        int* __restrict__ RIDX) {
  int n = blockIdx.x;
  int qw = threadIdx.x;
  const float* qv = QW + (size_t)(n * 64 + qw) * 64;
  float bv0 = -1e30f, bv1 = -1e30f, bv2 = -1e30f, bv3 = -1e30f;
  int bi0 = 0, bi1 = 0, bi2 = 0, bi3 = 0;
  for (int kw = 0; kw < 64; kw++) {
    const float* kv = KW + (size_t)(n * 64 + kw) * 64;
    float t = 0.f;
    for (int c = 0; c < 64; c++) t += qv[c] * kv[c];
    t *= 0.125f;
    if (t > bv3) {
      if (t > bv0) { bv3=bv2;bi3=bi2; bv2=bv1;bi2=bi1; bv1=bv0;bi1=bi0; bv0=t;bi0=kw; }
      else if (t > bv1) { bv3=bv2;bi3=bi2; bv2=bv1;bi2=bi1; bv1=t;bi1=kw; }
      else if (t > bv2) { bv3=bv2;bi3=bi2; bv2=t;bi2=kw; }
      else { bv3=t;bi3=kw; }
    }
  }
  int* o = RIDX + (size_t)(n * 64 + qw) * 4;
  o[0]=bi0; o[1]=bi1; o[2]=bi2; o[3]=bi3;
}

// ---- attention: 8 parts/window, 2 thr/query x 4 heads, float4 LDS ----
__global__ void __launch_bounds__(256) k_attn(const float* __restrict__ Q,
                                              const float* __restrict__ KVP,
                                              const int* __restrict__ RIDX,
                                              float* __restrict__ S) {
  __shared__ float ks[64][64];
  __shared__ float vs[64][64];
  __shared__ int idx[4];
  int blk = blockIdx.x;            // 1024 = (n*64+win)*8 + part
  int part = blk & 7, bw = blk >> 3;
  int n = bw >> 6, win = bw & 63;
  if (threadIdx.x < 4) idx[threadIdx.x] = RIDX[bw * 4 + threadIdx.x];
  __syncthreads();
  for (int t = threadIdx.x; t < 1024; t += 256) {
    int tok = t >> 4, c4 = (t & 15) << 2;
    const float* src = KVP + ((size_t)(n * 64 + idx[tok >> 4]) * 16 + (tok & 15)) * 128;
    *(float4*)&ks[tok][c4] = *(const float4*)&src[c4];
    *(float4*)&vs[tok][c4] = *(const float4*)&src[64 + c4];
  }
  __syncthreads();
  int ql = threadIdx.x >> 1, half = threadIdx.x & 1;
  int q = part * 128 + ql;
  int wi = win >> 3, wj = win & 7;
  int r = q >> 5, s = q & 31;
  int p = (n << 16) | ((wi * 32 + r) << 8) | (wj * 32 + s);
  const float* qp = Q + (size_t)p * 64 + half * 32;
  float qr[4][8];
#pragma unroll
  for (int hh = 0; hh < 4; hh++) {
    const float4 a = *(const float4*)&qp[hh * 8];
    const float4 b = *(const float4*)&qp[hh * 8 + 4];
    qr[hh][0] = a.x * 0.125f; qr[hh][1] = a.y * 0.125f;
    qr[hh][2] = a.z * 0.125f; qr[hh][3] = a.w * 0.125f;
    qr[hh][4] = b.x * 0.125f; qr[hh][5] = b.y * 0.125f;
    qr[hh][6] = b.z * 0.125f; qr[hh][7] = b.w * 0.125f;
  }
  float m[4] = {-1e30f, -1e30f, -1e30f, -1e30f};
  float l[4] = {0, 0, 0, 0};
  float out[4][8];
#pragma unroll
  for (int hh = 0; hh < 4; hh++)
#pragma unroll
    for (int d = 0; d < 8; d++) out[hh][d] = 0.f;
  for (int k = 0; k < 64; k++) {
    const float* kk = &ks[k][half * 32];
    const float* vv = &vs[k][half * 32];
#pragma unroll
    for (int hh = 0; hh < 4; hh++) {
      const float4 ka = *(const float4*)&kk[hh * 8];
      const float4 kb = *(const float4*)&kk[hh * 8 + 4];
      float t = qr[hh][0] * ka.x + qr[hh][1] * ka.y + qr[hh][2] * ka.z + qr[hh][3] * ka.w +
                qr[hh][4] * kb.x + qr[hh][5] * kb.y + qr[hh][6] * kb.z + qr[hh][7] * kb.w;
      float nm = fmaxf(m[hh], t);
      float corr = __expf(m[hh] - nm);
      float e = __expf(t - nm);
      l[hh] = l[hh] * corr + e;
      const float4 va = *(const float4*)&vv[hh * 8];
      const float4 vb = *(const float4*)&vv[hh * 8 + 4];
      out[hh][0] = out[hh][0] * corr + e * va.x;
      out[hh][1] = out[hh][1] * corr + e * va.y;
      out[hh][2] = out[hh][2] * corr + e * va.z;
      out[hh][3] = out[hh][3] * corr + e * va.w;
      out[hh][4] = out[hh][4] * corr + e * vb.x;
      out[hh][5] = out[hh][5] * corr + e * vb.y;
      out[hh][6] = out[hh][6] * corr + e * vb.z;
      out[hh][7] = out[hh][7] * corr + e * vb.w;
      m[hh] = nm;
    }
  }
  float* op = S + (size_t)p * 64 + half * 32;
#pragma unroll
  for (int hh = 0; hh < 4; hh++) {
    float inv = 1.f / l[hh];
    *(float4*)&op[hh * 8] = make_float4(out[hh][0] * inv, out[hh][1] * inv,
                                        out[hh][2] * inv, out[hh][3] * inv);
    *(float4*)&op[hh * 8 + 4] = make_float4(out[hh][4] * inv, out[hh][5] * inv,
                                            out[hh][6] * inv, out[hh][7] * inv);
  }
}

// ---- LePE vectorized: 4ch/thread, LDS-transposed weights ----
__global__ void __launch_bounds__(256) k_lepe4(const bf16* __restrict__ V,
                                               float* __restrict__ S,
                                               const float* __restrict__ wt,
                                               const float* __restrict__ bs) {
  __shared__ float w5[25][64];
  __shared__ float bb[64];
  int tid = threadIdx.x;
  for (int j = tid; j < 1600; j += 256) w5[j % 25][j / 25] = wt[j];
  if (tid < 64) bb[tid] = bs[tid];
  __syncthreads();
  int i = blockIdx.x * 256 + tid;
  int cg = i & 15, p = i >> 4;
  int c0 = cg << 2;
  int w = p & 255, h = (p >> 8) & 255, n = p >> 16;
  float acc[4];
  {
    const float4 b4 = *(const float4*)&bb[c0];
    acc[0] = b4.x; acc[1] = b4.y; acc[2] = b4.z; acc[3] = b4.w;
  }
#pragma unroll
  for (int ky = 0; ky < 5; ky++) {
    int hh = h + ky - 2;
    if ((unsigned)hh >= 256u) continue;
#pragma unroll
    for (int kx = 0; kx < 5; kx++) {
      int ww = w + kx - 2;
      if ((unsigned)ww >= 256u) continue;
      const float4 wv = *(const float4*)&w5[ky * 5 + kx][c0];
      float f[4];
      ld4(V + (size_t)((n << 16) | (hh << 8) | ww) * 64 + c0, f);
      acc[0] += wv.x * f[0]; acc[1] += wv.y * f[1];
      acc[2] += wv.z * f[2]; acc[3] += wv.w * f[3];
    }
  }
  float4* sp = (float4*)&S[(size_t)p * 64 + c0];
  float4 sv = *sp;
  *sp = make_float4(sv.x + acc[0], sv.y + acc[1], sv.z + acc[2], sv.w + acc[3]);
}

// ---- Wc = W1a @ pw^T; bc = b1a @ pw^T ----
__global__ void k_combine(const float* __restrict__ f1w, const float* __restrict__ f1b,
                          const float* __restrict__ pww, float* __restrict__ Wc,
                          float* __restrict__ bc) {
  int t = blockIdx.x * blockDim.x + threadIdx.x;
  if (t >= 8192) return;
  int o = t & 127, k = t >> 7;
  float acc = 0.f;
  for (int j = 0; j < 128; j++) acc += f1w[k * 256 + j] * pww[o * 128 + j];
  Wc[k * 128 + o] = acc;
  if (k == 0) {
    float b = 0.f;
    for (int j = 0; j < 128; j++) b += f1b[j] * pww[o * 128 + j];
    bc[o] = b;
  }
}

// ---- GLU tail vectorized: G = gelu(dw3(PWO)+dwb) * VH, 4ch/thread ----
__global__ void __launch_bounds__(256) k_gludw4(const bf16* __restrict__ PWO,
                                                const bf16* __restrict__ VH,
                                                const float* __restrict__ wt,
                                                const float* __restrict__ bs,
                                                bf16* __restrict__ G) {
  __shared__ float wd[9][128];
  __shared__ float bb[128];
  int tid = threadIdx.x;
  for (int j = tid; j < 1152; j += 256) wd[j % 9][j / 9] = wt[j];
  if (tid < 128) bb[tid] = bs[tid];
  __syncthreads();
  int i = blockIdx.x * 256 + tid;
  int cg = i & 31, p = i >> 5;
  int c0 = cg << 2;
  int w = p & 255, h = (p >> 8) & 255, n = p >> 16;
  float acc[4];
  {
    const float4 b4 = *(const float4*)&bb[c0];
    acc[0] = b4.x; acc[1] = b4.y; acc[2] = b4.z; acc[3] = b4.w;
  }
#pragma unroll
  for (int ky = 0; ky < 3; ky++) {
    int hh = h + ky - 1;
    if ((unsigned)hh >= 256u) continue;
#pragma unroll
    for (int kx = 0; kx < 3; kx++) {
      int ww = w + kx - 1;
      if ((unsigned)ww >= 256u) continue;
      const float4 wv = *(const float4*)&wd[ky * 3 + kx][c0];
      float f[4];
      ld4(PWO + (size_t)((n << 16) | (hh << 8) | ww) * 128 + c0, f);
      acc[0] += wv.x * f[0]; acc[1] += wv.y * f[1];
      acc[2] += wv.z * f[2]; acc[3] += wv.w * f[3];
    }
  }
  float vh[4];
  ld4(VH + (size_t)p * 128 + c0, vh);
  float g[4];
#pragma unroll
  for (int j = 0; j < 4; j++) {
    float ge = 0.5f * acc[j] * (1.f + erff(acc[j] * 0.70710678118f));
    g[j] = ge * vh[j];
  }
  st4(G + (size_t)p * 128 + c0, g);
}

extern "C" void kernel_launch(void* const* d_in, const int* in_sizes, int n_in,
                              void* d_out, int out_size, void* d_ws, size_t ws_size,
                              hipStream_t stream) {
  (void)in_sizes; (void)n_in; (void)out_size; (void)ws_size;
  const float* xin = (const float*)d_in[0];
  auto Wp = [&](int i) { return (const float*)d_in[i]; };
  char* ws = (char*)d_ws;
  const size_t MB = 1u << 20;
  float* X = (float*)(ws + 0 * MB);    // trunk / Q
  float* A = (float*)(ws + 32 * MB);   // residual / LN2out / G(bf16)
  float* T = (float*)(ws + 64 * MB);   // LN1out / S / VH(bf16)
  char*  R = ws + 96 * MB;             // V bf16 then PWO bf16
  char* sm = ws + 128 * MB;
  size_t off = 0;
  auto alloc = [&](size_t bytes) {
    void* p = sm + off;
    off += (bytes + 255) & ~(size_t)255;
    return p;
  };
  float* Y8  = (float*)alloc(2 * 32 * 32 * 64 * 4);
  float* Ym  = (float*)alloc(2 * 64 * 64 * 4);
  float* QW  = (float*)alloc(2 * 64 * 64 * 4);
  float* KW  = (float*)alloc(2 * 64 * 64 * 4);
  float* KVP = (float*)alloc(2 * 64 * 16 * 128 * 4);
  int*  RIDX = (int*)alloc(2 * 64 * 4 * 4);
  float* Wc  = (float*)alloc(64 * 128 * 4);
  float* bc  = (float*)alloc(128 * 4);
  bf16* Vb  = (bf16*)R;
  bf16* PWO = (bf16*)R;
  bf16* VH  = (bf16*)T;
  bf16* G   = (bf16*)A;

  k_in_tr<<<dim3(2048), dim3(256), 0, stream>>>(xin, X);
  for (int i = 0; i < 2; i++) {
    const float *posw = Wp(1) + i * 64 * 9, *posb = Wp(2) + i * 64;
    const float *l1g = Wp(3) + i * 64, *l1b = Wp(4) + i * 64;
    const float *qkvw = Wp(5) + i * 64 * 192, *qkvb = Wp(6) + i * 192;
    const float *lpw = Wp(7) + i * 64 * 25, *lpb = Wp(8) + i * 64;
    const float *wow = Wp(9) + i * 64 * 64, *wob = Wp(10) + i * 64;
    const float *l2g = Wp(11) + i * 64, *l2b = Wp(12) + i * 64;
    const float *f1w = Wp(13) + i * 64 * 256, *f1b = Wp(14) + i * 256;
    const float *pww = Wp(15) + i * 128 * 128;
    const float *dww = Wp(16) + i * 128 * 9, *dwb = Wp(17) + i * 128;
    const float *f2w = Wp(18) + i * 128 * 64, *f2b = Wp(19) + i * 64;

    k_pcln<<<dim3(Pp / 4), dim3(256), 0, stream>>>(X, A, T, posw, posb, l1g, l1b);
    // Q -> X (f32), V -> Vb (bf16), one read of T
    k_dual<64, 64, 64, float, bf16><<<dim3(Pp / 8), dim3(256), 0, stream>>>(
        T, qkvw, 192, qkvb, X, qkvw + 128, 192, qkvb + 128, Vb);
    k_pool8<<<dim3(2048), dim3(64), 0, stream>>>(T, Y8);
    k_poolwin<<<dim3(128), dim3(64), 0, stream>>>(Y8, Ym);
    k_qkwin<<<dim3(64), dim3(256), 0, stream>>>(Ym, qkvw, qkvb, QW, KW);
    k_kvp<<<dim3(1024), dim3(256), 0, stream>>>(Y8, qkvw, qkvb, KVP);
    k_route<<<dim3(2), dim3(64), 0, stream>>>(QW, KW, RIDX);
    k_attn<<<dim3(1024), dim3(256), 0, stream>>>(X, KVP, RIDX, T);
    k_lepe4<<<dim3(Pp / 16), dim3(256), 0, stream>>>(Vb, T, lpw, lpb);
    k_gemm4<float, 64, 64, true><<<dim3(Pp / 16), dim3(256), 0, stream>>>(
        T, wow, wob, A, X);
    k_ln<<<dim3(Pp / 4), dim3(256), 0, stream>>>(X, A, l2g, l2b);
    k_combine<<<dim3(32), dim3(256), 0, stream>>>(f1w, f1b, pww, Wc, bc);
    // VH -> T (bf16), PWO -> R (bf16), one read of A
    k_dual<64, 128, 128, bf16, bf16><<<dim3(Pp / 4), dim3(256), 0, stream>>>(
        A, f1w + 128, 256, f1b + 128, VH, Wc, 128, bc, PWO);
    k_gludw4<<<dim3(Pp / 8), dim3(256), 0, stream>>>(PWO, VH, dww, dwb, G);
    k_gemm4<bf16, 128, 64, true><<<dim3(Pp / 16), dim3(256), 0, stream>>>(
        G, f2w, f2b, X, X);
  }
  k_out<<<dim3(2048), dim3(256), 0, stream>>>(X, (float*)d_out);
}

// Round 5
// 948.529 us; speedup vs baseline: 2.9944x; 2.1851x over previous
//
#include <hip/hip_runtime.h>
#include <hip/hip_bf16.h>

typedef __hip_bfloat16 bf16;
typedef __attribute__((ext_vector_type(8))) short short8v;
typedef __attribute__((ext_vector_type(4))) float f32x4;

static constexpr int Nn = 2, Hh = 256, Wd = 256;
static constexpr int Pp = Nn * Hh * Wd;  // 131072 pixels

// ---- scalar/vector load-store helpers ----
__device__ inline void sto(float* p, size_t i, float v) { p[i] = v; }
__device__ inline void sto(bf16* p, size_t i, float v) { p[i] = __float2bfloat16(v); }
__device__ inline void ld4(const float* p, float f[4]) {
  const float4 v = *(const float4*)p;
  f[0] = v.x; f[1] = v.y; f[2] = v.z; f[3] = v.w;
}
__device__ inline void ld4(const bf16* p, float f[4]) {
  uint2 u = *(const uint2*)p;
  f[0] = __uint_as_float(u.x << 16); f[1] = __uint_as_float(u.x & 0xffff0000u);
  f[2] = __uint_as_float(u.y << 16); f[3] = __uint_as_float(u.y & 0xffff0000u);
}
__device__ inline void st4(float* p, const float f[4]) {
  *(float4*)p = make_float4(f[0], f[1], f[2], f[3]);
}
__device__ inline void st4(bf16* p, const float f[4]) {
  union { bf16 h[4]; uint2 u; } x;
  x.h[0] = __float2bfloat16(f[0]); x.h[1] = __float2bfloat16(f[1]);
  x.h[2] = __float2bfloat16(f[2]); x.h[3] = __float2bfloat16(f[3]);
  *(uint2*)p = x.u;
}

// ---- NCHW f32 -> NHWC f32, LDS-tiled ----
__global__ void __launch_bounds__(256) k_in_tr(const float* __restrict__ xin,
                                               float* __restrict__ X) {
  __shared__ float t[64][65];
  int blk = blockIdx.x;
  int wt = blk & 3, h = (blk >> 2) & 255, n = blk >> 10;
  int w0 = wt * 64;
  int tx = threadIdx.x & 63, ty = threadIdx.x >> 6;
  const float* src = xin + ((size_t)n * 64 * 256 + h) * 256 + w0;
#pragma unroll
  for (int cc = 0; cc < 16; cc++) {
    int c = cc * 4 + ty;
    t[c][tx] = src[(size_t)c * 65536 + tx];
  }
  __syncthreads();
  float* dst = X + (size_t)(n * 65536 + h * 256 + w0) * 64;
#pragma unroll
  for (int jj = 0; jj < 16; jj++) {
    int j = jj * 4 + ty;
    dst[(size_t)j * 64 + tx] = t[tx][j];
  }
}

// ---- NHWC f32 -> NCHW f32 ----
__global__ void __launch_bounds__(256) k_out(const float* __restrict__ X,
                                             float* __restrict__ out) {
  __shared__ float t[64][65];
  int blk = blockIdx.x;
  int wt = blk & 3, h = (blk >> 2) & 255, n = blk >> 10;
  int w0 = wt * 64;
  int tx = threadIdx.x & 63, ty = threadIdx.x >> 6;
  const float* src = X + (size_t)(n * 65536 + h * 256 + w0) * 64;
#pragma unroll
  for (int jj = 0; jj < 16; jj++) {
    int j = jj * 4 + ty;
    t[tx][j] = src[(size_t)j * 64 + tx];
  }
  __syncthreads();
  float* dst = out + ((size_t)n * 64 * 256 + h) * 256 + w0;
#pragma unroll
  for (int cc = 0; cc < 16; cc++) {
    int c = cc * 4 + ty;
    dst[(size_t)c * 65536 + tx] = t[c][tx];
  }
}

// ---- fused: A = X + dw3x3(X);  T = LN1(A) f32;  Tb = bf16(T) ----
__global__ void __launch_bounds__(256) k_pcln(const float* __restrict__ X,
                                              float* __restrict__ A, float* __restrict__ T,
                                              bf16* __restrict__ Tb,
                                              const float* __restrict__ pw,
                                              const float* __restrict__ pb,
                                              const float* __restrict__ g,
                                              const float* __restrict__ b) {
  int gid = blockIdx.x * 256 + threadIdx.x;
  int pix = gid >> 6, c = gid & 63;
  int w = pix & 255, h = (pix >> 8) & 255, n = pix >> 16;
  float acc = pb[c];
#pragma unroll
  for (int ky = 0; ky < 3; ky++) {
    int hh = h + ky - 1;
    if ((unsigned)hh >= 256u) continue;
#pragma unroll
    for (int kx = 0; kx < 3; kx++) {
      int ww = w + kx - 1;
      if ((unsigned)ww >= 256u) continue;
      acc += pw[c * 9 + ky * 3 + kx] * X[(size_t)((n << 16) | (hh << 8) | ww) * 64 + c];
    }
  }
  float a = X[gid] + acc;
  A[gid] = a;
  float s = a;
#pragma unroll
  for (int off = 32; off; off >>= 1) s += __shfl_xor(s, off);
  float mean = s * (1.f / 64.f);
  float d = a - mean;
  float q = d * d;
#pragma unroll
  for (int off = 32; off; off >>= 1) q += __shfl_xor(q, off);
  float var = q * (1.f / 64.f);
  float y = d * rsqrtf(var + 1e-6f) * g[c] + b[c];
  T[gid] = y;
  Tb[gid] = __float2bfloat16(y);
}

// ---- LayerNorm -> bf16 out (LN2) ----
__global__ void __launch_bounds__(256) k_lnb(const float* __restrict__ In,
                                             bf16* __restrict__ Out,
                                             const float* __restrict__ g,
                                             const float* __restrict__ b) {
  int gid = blockIdx.x * 256 + threadIdx.x;
  int c = gid & 63;
  float v = In[gid];
  float s = v;
#pragma unroll
  for (int off = 32; off; off >>= 1) s += __shfl_xor(s, off);
  float mean = s * (1.f / 64.f);
  float d = v - mean;
  float q = d * d;
#pragma unroll
  for (int off = 32; off; off >>= 1) q += __shfl_xor(q, off);
  float var = q * (1.f / 64.f);
  Out[gid] = __float2bfloat16(d * rsqrtf(var + 1e-6f) * g[c] + b[c]);
}

// ---- weight prep 1: WTq[128][64], WTo[64][64], WT2[64][128] (bf16 transposed) ----
__global__ void k_prep1(const float* __restrict__ qkvw, const float* __restrict__ wow,
                        const float* __restrict__ f2w, bf16* __restrict__ WTq,
                        bf16* __restrict__ WTo, bf16* __restrict__ WT2) {
  int t = blockIdx.x * 256 + threadIdx.x;
  if (t < 8192) {
    int r = t >> 6, k = t & 63;
    int src = r < 64 ? r : r + 64;  // Q cols 0..63, V cols 128..191
    WTq[t] = __float2bfloat16(qkvw[k * 192 + src]);
  } else if (t < 12288) {
    int t2 = t - 8192;
    int r = t2 >> 6, k = t2 & 63;
    WTo[t2] = __float2bfloat16(wow[k * 64 + r]);
  } else if (t < 20480) {
    int t2 = t - 12288;
    int r = t2 >> 7, k = t2 & 127;
    WT2[t2] = __float2bfloat16(f2w[k * 64 + r]);
  }
}

// ---- Wc = W1a @ pw^T (f32); bc = b1a @ pw^T ----
__global__ void k_combine(const float* __restrict__ f1w, const float* __restrict__ f1b,
                          const float* __restrict__ pww, float* __restrict__ Wc,
                          float* __restrict__ bc) {
  int t = blockIdx.x * blockDim.x + threadIdx.x;
  if (t >= 8192) return;
  int o = t & 127, k = t >> 7;
  float acc = 0.f;
  for (int j = 0; j < 128; j++) acc += f1w[k * 256 + j] * pww[o * 128 + j];
  Wc[k * 128 + o] = acc;
  if (k == 0) {
    float b = 0.f;
    for (int j = 0; j < 128; j++) b += f1b[j] * pww[o * 128 + j];
    bc[o] = b;
  }
}

// ---- weight prep 2: WTf1[256][64] = [W1b^T ; Wc^T] bf16 ----
__global__ void k_prep2(const float* __restrict__ f1w, const float* __restrict__ Wc,
                        bf16* __restrict__ WTf1) {
  int t = blockIdx.x * 256 + threadIdx.x;
  if (t >= 16384) return;
  int r = t >> 6, k = t & 63;
  float v = r < 128 ? f1w[k * 256 + 128 + r] : Wc[k * 128 + (r - 128)];
  WTf1[t] = __float2bfloat16(v);
}

// ---- unified MFMA GEMM: Out[m, 0..N1) -> O1, [N1..N1+N2) -> O2 ----
// In: [P][K] bf16 row-major. WT: [N1+N2][K] bf16 (transposed weights).
// 256 thr / 4 waves; block = 128 rows; wave owns NC/4 cols across all rows.
template <int K, int N1, int N2, typename TO1, typename TO2, bool RES>
__global__ void __launch_bounds__(256) k_mf(const bf16* __restrict__ In,
                                            const bf16* __restrict__ WT,
                                            const float* __restrict__ b1,
                                            const float* __restrict__ b2,
                                            const float* __restrict__ Res,
                                            TO1* __restrict__ O1, TO2* __restrict__ O2) {
  constexpr int NC = N1 + N2;
  constexpr int KS = K / 32;       // k-steps
  constexpr int NTW = NC / 64;     // n-tiles per wave
  constexpr int KB = K * 2;        // bytes per WT row
  constexpr int CH = NC * K / 8;   // 16B staging chunks
  __shared__ char lw[NC * K * 2];
  int tid = threadIdx.x;
  for (int ch = tid; ch < CH; ch += 256) {
    int r = ch / (K / 8), cg = ch % (K / 8);
    int byte = (r * KB + cg * 16) ^ ((r & 7) << 4);  // G4 XOR swizzle
    *(uint4*)(lw + byte) = *(const uint4*)((const short*)WT + ch * 8);
  }
  __syncthreads();
  int wid = tid >> 6, lane = tid & 63;
  int lr = lane & 15, lg = lane >> 4;
  int mb = blockIdx.x * 128;
#pragma unroll 2
  for (int ms = 0; ms < 8; ms++) {
    int m0 = mb + ms * 16;
    short8v a[KS];
#pragma unroll
    for (int ks = 0; ks < KS; ks++)
      a[ks] = *(const short8v*)((const short*)In + (size_t)(m0 + lr) * K + ks * 32 + lg * 8);
#pragma unroll
    for (int t = 0; t < NTW; t++) {
      int nt = wid * NTW + t;
      int col = nt * 16 + lr;
      float bv = (N2 == 0 || col < N1) ? b1[col] : b2[col - N1];
      f32x4 acc = {bv, bv, bv, bv};
#pragma unroll
      for (int ks = 0; ks < KS; ks++) {
        int byte = (col * KB + ks * 64 + lg * 16) ^ ((col & 7) << 4);
        short8v bfrag = *(const short8v*)(lw + byte);
        acc = __builtin_amdgcn_mfma_f32_16x16x32_bf16(a[ks], bfrag, acc, 0, 0, 0);
      }
      int r0 = m0 + lg * 4;
#pragma unroll
      for (int j = 0; j < 4; j++) {
        float v = acc[j];
        size_t row = r0 + j;
        if (RES) v += Res[row * N1 + col];
        if (N2 == 0 || col < N1) sto(O1, row * N1 + col, v);
        else sto(O2, row * N2 + (col - N1), v);
      }
    }
  }
}

// ---- 8x8 block means of LN1 (f32, exact routing path) ----
__global__ void k_pool8(const float* __restrict__ T, float* __restrict__ Y8) {
  int b = blockIdx.x;
  int c = threadIdx.x;
  int bx = b & 31, by = (b >> 5) & 31, n = b >> 10;
  float acc = 0.f;
  for (int r = 0; r < 8; r++)
    for (int s = 0; s < 8; s++) {
      int p = (n << 16) | ((by * 8 + r) << 8) | (bx * 8 + s);
      acc += T[(size_t)p * 64 + c];
    }
  Y8[(size_t)b * 64 + c] = acc * (1.f / 64.f);
}

__global__ void k_poolwin(const float* __restrict__ Y8, float* __restrict__ Ym) {
  int b = blockIdx.x;
  int c = threadIdx.x;
  int win = b & 63, n = b >> 6, wi = win >> 3, wj = win & 7;
  float acc = 0.f;
  for (int ti = 0; ti < 4; ti++)
    for (int tj = 0; tj < 4; tj++) {
      int y8 = (n * 32 + wi * 4 + ti) * 32 + wj * 4 + tj;
      acc += Y8[(size_t)y8 * 64 + c];
    }
  Ym[(size_t)b * 64 + c] = acc * (1.f / 16.f);
}

__global__ void k_qkwin(const float* __restrict__ Ym, const float* __restrict__ qw,
                        const float* __restrict__ qb, float* __restrict__ QW,
                        float* __restrict__ KW) {
  int t = blockIdx.x * blockDim.x + threadIdx.x;
  if (t >= 16384) return;
  int c = t & 63, row = (t >> 6) & 127, sel = t >> 13;
  const float* y = Ym + (size_t)row * 64;
  int col = sel * 64 + c;
  float acc = qb[col];
  for (int k = 0; k < 64; k++) acc += y[k] * qw[k * 192 + col];
  (sel ? KW : QW)[(size_t)row * 64 + c] = acc;
}

__global__ void k_kvp(const float* __restrict__ Y8, const float* __restrict__ qw,
                      const float* __restrict__ qb, float* __restrict__ KVP) {
  int t = blockIdx.x * blockDim.x + threadIdx.x;
  if (t >= 262144) return;
  int c2 = t & 127, tok = (t >> 7) & 15, win = (t >> 11) & 63, n = t >> 17;
  int wi = win >> 3, wj = win & 7, ti = tok >> 2, tj = tok & 3;
  int y8 = (n * 32 + wi * 4 + ti) * 32 + wj * 4 + tj;
  const float* y = Y8 + (size_t)y8 * 64;
  int col = 64 + c2;
  float acc = qb[col];
  for (int k = 0; k < 64; k++) acc += y[k] * qw[k * 192 + col];
  KVP[t] = acc;
}

__global__ void k_route(const float* __restrict__ QW, const float* __restrict__ KW,
                        int* __restrict__ RIDX) {
  int n = blockIdx.x;
  int qw = threadIdx.x;
  const float* qv = QW + (size_t)(n * 64 + qw) * 64;
  float bv0 = -1e30f, bv1 = -1e30f, bv2 = -1e30f, bv3 = -1e30f;
  int bi0 = 0, bi1 = 0, bi2 = 0, bi3 = 0;
  for (int kw = 0; kw < 64; kw++) {
    const float* kv = KW + (size_t)(n * 64 + kw) * 64;
    float t = 0.f;
    for (int c = 0; c < 64; c++) t += qv[c] * kv[c];
    t *= 0.125f;
    if (t > bv3) {
      if (t > bv0) { bv3=bv2;bi3=bi2; bv2=bv1;bi2=bi1; bv1=bv0;bi1=bi0; bv0=t;bi0=kw; }
      else if (t > bv1) { bv3=bv2;bi3=bi2; bv2=bv1;bi2=bi1; bv1=t;bi1=kw; }
      else if (t > bv2) { bv3=bv2;bi3=bi2; bv2=t;bi2=kw; }
      else { bv3=t;bi3=kw; }
    }
  }
  int* o = RIDX + (size_t)(n * 64 + qw) * 4;
  o[0]=bi0; o[1]=bi1; o[2]=bi2; o[3]=bi3;
}

// ---- attention: 8 parts/window, 2 thr/query x 4 heads, float4 LDS ----
__global__ void __launch_bounds__(256) k_attn(const float* __restrict__ Q,
                                              const float* __restrict__ KVP,
                                              const int* __restrict__ RIDX,
                                              float* __restrict__ S) {
  __shared__ float ks[64][64];
  __shared__ float vs[64][64];
  __shared__ int idx[4];
  int blk = blockIdx.x;
  int part = blk & 7, bw = blk >> 3;
  int n = bw >> 6, win = bw & 63;
  if (threadIdx.x < 4) idx[threadIdx.x] = RIDX[bw * 4 + threadIdx.x];
  __syncthreads();
  for (int t = threadIdx.x; t < 1024; t += 256) {
    int tok = t >> 4, c4 = (t & 15) << 2;
    const float* src = KVP + ((size_t)(n * 64 + idx[tok >> 4]) * 16 + (tok & 15)) * 128;
    *(float4*)&ks[tok][c4] = *(const float4*)&src[c4];
    *(float4*)&vs[tok][c4] = *(const float4*)&src[64 + c4];
  }
  __syncthreads();
  int ql = threadIdx.x >> 1, half = threadIdx.x & 1;
  int q = part * 128 + ql;
  int wi = win >> 3, wj = win & 7;
  int r = q >> 5, s = q & 31;
  int p = (n << 16) | ((wi * 32 + r) << 8) | (wj * 32 + s);
  const float* qp = Q + (size_t)p * 64 + half * 32;
  float qr[4][8];
#pragma unroll
  for (int hh = 0; hh < 4; hh++) {
    const float4 a = *(const float4*)&qp[hh * 8];
    const float4 b = *(const float4*)&qp[hh * 8 + 4];
    qr[hh][0] = a.x * 0.125f; qr[hh][1] = a.y * 0.125f;
    qr[hh][2] = a.z * 0.125f; qr[hh][3] = a.w * 0.125f;
    qr[hh][4] = b.x * 0.125f; qr[hh][5] = b.y * 0.125f;
    qr[hh][6] = b.z * 0.125f; qr[hh][7] = b.w * 0.125f;
  }
  float m[4] = {-1e30f, -1e30f, -1e30f, -1e30f};
  float l[4] = {0, 0, 0, 0};
  float out[4][8];
#pragma unroll
  for (int hh = 0; hh < 4; hh++)
#pragma unroll
    for (int d = 0; d < 8; d++) out[hh][d] = 0.f;
  for (int k = 0; k < 64; k++) {
    const float* kk = &ks[k][half * 32];
    const float* vv = &vs[k][half * 32];
#pragma unroll
    for (int hh = 0; hh < 4; hh++) {
      const float4 ka = *(const float4*)&kk[hh * 8];
      const float4 kb = *(const float4*)&kk[hh * 8 + 4];
      float t = qr[hh][0] * ka.x + qr[hh][1] * ka.y + qr[hh][2] * ka.z + qr[hh][3] * ka.w +
                qr[hh][4] * kb.x + qr[hh][5] * kb.y + qr[hh][6] * kb.z + qr[hh][7] * kb.w;
      float nm = fmaxf(m[hh], t);
      float corr = __expf(m[hh] - nm);
      float e = __expf(t - nm);
      l[hh] = l[hh] * corr + e;
      const float4 va = *(const float4*)&vv[hh * 8];
      const float4 vb = *(const float4*)&vv[hh * 8 + 4];
      out[hh][0] = out[hh][0] * corr + e * va.x;
      out[hh][1] = out[hh][1] * corr + e * va.y;
      out[hh][2] = out[hh][2] * corr + e * va.z;
      out[hh][3] = out[hh][3] * corr + e * va.w;
      out[hh][4] = out[hh][4] * corr + e * vb.x;
      out[hh][5] = out[hh][5] * corr + e * vb.y;
      out[hh][6] = out[hh][6] * corr + e * vb.z;
      out[hh][7] = out[hh][7] * corr + e * vb.w;
      m[hh] = nm;
    }
  }
  float* op = S + (size_t)p * 64 + half * 32;
#pragma unroll
  for (int hh = 0; hh < 4; hh++) {
    float inv = 1.f / l[hh];
    *(float4*)&op[hh * 8] = make_float4(out[hh][0] * inv, out[hh][1] * inv,
                                        out[hh][2] * inv, out[hh][3] * inv);
    *(float4*)&op[hh * 8 + 4] = make_float4(out[hh][4] * inv, out[hh][5] * inv,
                                            out[hh][6] * inv, out[hh][7] * inv);
  }
}

// ---- LePE: Sb = bf16(S + dw5x5(V)) ----
__global__ void __launch_bounds__(256) k_lepe4(const bf16* __restrict__ V,
                                               const float* __restrict__ S,
                                               bf16* __restrict__ Sb,
                                               const float* __restrict__ wt,
                                               const float* __restrict__ bs) {
  __shared__ float w5[25][64];
  __shared__ float bb[64];
  int tid = threadIdx.x;
  for (int j = tid; j < 1600; j += 256) w5[j % 25][j / 25] = wt[j];
  if (tid < 64) bb[tid] = bs[tid];
  __syncthreads();
  int i = blockIdx.x * 256 + tid;
  int cg = i & 15, p = i >> 4;
  int c0 = cg << 2;
  int w = p & 255, h = (p >> 8) & 255, n = p >> 16;
  float acc[4];
  {
    const float4 b4 = *(const float4*)&bb[c0];
    acc[0] = b4.x; acc[1] = b4.y; acc[2] = b4.z; acc[3] = b4.w;
  }
#pragma unroll
  for (int ky = 0; ky < 5; ky++) {
    int hh = h + ky - 2;
    if ((unsigned)hh >= 256u) continue;
#pragma unroll
    for (int kx = 0; kx < 5; kx++) {
      int ww = w + kx - 2;
      if ((unsigned)ww >= 256u) continue;
      const float4 wv = *(const float4*)&w5[ky * 5 + kx][c0];
      float f[4];
      ld4(V + (size_t)((n << 16) | (hh << 8) | ww) * 64 + c0, f);
      acc[0] += wv.x * f[0]; acc[1] += wv.y * f[1];
      acc[2] += wv.z * f[2]; acc[3] += wv.w * f[3];
    }
  }
  const float4 sv = *(const float4*)&S[(size_t)p * 64 + c0];
  float o[4] = {sv.x + acc[0], sv.y + acc[1], sv.z + acc[2], sv.w + acc[3]};
  st4(Sb + (size_t)p * 64 + c0, o);
}

// ---- GLU tail: G = gelu(dw3(PWO)+dwb) * VH ----
__global__ void __launch_bounds__(256) k_gludw4(const bf16* __restrict__ PWO,
                                                const bf16* __restrict__ VH,
                                                const float* __restrict__ wt,
                                                const float* __restrict__ bs,
                                                bf16* __restrict__ G) {
  __shared__ float wd[9][128];
  __shared__ float bb[128];
  int tid = threadIdx.x;
  for (int j = tid; j < 1152; j += 256) wd[j % 9][j / 9] = wt[j];
  if (tid < 128) bb[tid] = bs[tid];
  __syncthreads();
  int i = blockIdx.x * 256 + tid;
  int cg = i & 31, p = i >> 5;
  int c0 = cg << 2;
  int w = p & 255, h = (p >> 8) & 255, n = p >> 16;
  float acc[4];
  {
    const float4 b4 = *(const float4*)&bb[c0];
    acc[0] = b4.x; acc[1] = b4.y; acc[2] = b4.z; acc[3] = b4.w;
  }
#pragma unroll
  for (int ky = 0; ky < 3; ky++) {
    int hh = h + ky - 1;
    if ((unsigned)hh >= 256u) continue;
#pragma unroll
    for (int kx = 0; kx < 3; kx++) {
      int ww = w + kx - 1;
      if ((unsigned)ww >= 256u) continue;
      const float4 wv = *(const float4*)&wd[ky * 3 + kx][c0];
      float f[4];
      ld4(PWO + (size_t)((n << 16) | (hh << 8) | ww) * 128 + c0, f);
      acc[0] += wv.x * f[0]; acc[1] += wv.y * f[1];
      acc[2] += wv.z * f[2]; acc[3] += wv.w * f[3];
    }
  }
  float vh[4];
  ld4(VH + (size_t)p * 128 + c0, vh);
  float g[4];
#pragma unroll
  for (int j = 0; j < 4; j++) {
    float ge = 0.5f * acc[j] * (1.f + erff(acc[j] * 0.70710678118f));
    g[j] = ge * vh[j];
  }
  st4(G + (size_t)p * 128 + c0, g);
}

extern "C" void kernel_launch(void* const* d_in, const int* in_sizes, int n_in,
                              void* d_out, int out_size, void* d_ws, size_t ws_size,
                              hipStream_t stream) {
  (void)in_sizes; (void)n_in; (void)out_size; (void)ws_size;
  const float* xin = (const float*)d_in[0];
  auto Wp = [&](int i) { return (const float*)d_in[i]; };
  char* ws = (char*)d_ws;
  const size_t MB = 1u << 20;
  float* X  = (float*)(ws + 0 * MB);    // trunk / Q (f32)
  float* A  = (float*)(ws + 32 * MB);   // residual f32; later A2b bf16 @32, G bf16 @48
  float* T  = (float*)(ws + 64 * MB);   // LN1 f32 / S f32; later VH bf16
  char*  R  = ws + 96 * MB;             // Vb bf16 @96; Tb/Sb bf16 @112; PWO bf16 @96
  char*  sm = ws + 128 * MB;
  size_t off = 0;
  auto alloc = [&](size_t bytes) {
    void* p = sm + off;
    off += (bytes + 255) & ~(size_t)255;
    return p;
  };
  float* Y8   = (float*)alloc(2 * 32 * 32 * 64 * 4);
  float* Ym   = (float*)alloc(2 * 64 * 64 * 4);
  float* QW   = (float*)alloc(2 * 64 * 64 * 4);
  float* KW   = (float*)alloc(2 * 64 * 64 * 4);
  float* KVP  = (float*)alloc(2 * 64 * 16 * 128 * 4);
  int*  RIDX  = (int*)alloc(2 * 64 * 4 * 4);
  float* Wc   = (float*)alloc(64 * 128 * 4);
  float* bc   = (float*)alloc(128 * 4);
  bf16* WTq   = (bf16*)alloc(128 * 64 * 2);
  bf16* WTo   = (bf16*)alloc(64 * 64 * 2);
  bf16* WT2   = (bf16*)alloc(64 * 128 * 2);
  bf16* WTf1  = (bf16*)alloc(256 * 64 * 2);
  bf16* Vb   = (bf16*)R;                 // [P][64]
  bf16* Tb   = (bf16*)(ws + 112 * MB);   // [P][64]
  bf16* Sb   = Tb;                       // reuse after QKV GEMM
  bf16* PWO  = (bf16*)R;                 // [P][128] after lepe
  bf16* VH   = (bf16*)T;                 // [P][128] after pool8
  bf16* A2b  = (bf16*)A;                 // [P][64] after wo
  bf16* G    = (bf16*)(ws + 48 * MB);    // [P][128]

  k_in_tr<<<dim3(2048), dim3(256), 0, stream>>>(xin, X);
  for (int i = 0; i < 2; i++) {
    const float *posw = Wp(1) + i * 64 * 9, *posb = Wp(2) + i * 64;
    const float *l1g = Wp(3) + i * 64, *l1b = Wp(4) + i * 64;
    const float *qkvw = Wp(5) + i * 64 * 192, *qkvb = Wp(6) + i * 192;
    const float *lpw = Wp(7) + i * 64 * 25, *lpb = Wp(8) + i * 64;
    const float *wow = Wp(9) + i * 64 * 64, *wob = Wp(10) + i * 64;
    const float *l2g = Wp(11) + i * 64, *l2b = Wp(12) + i * 64;
    const float *f1w = Wp(13) + i * 64 * 256, *f1b = Wp(14) + i * 256;
    const float *pww = Wp(15) + i * 128 * 128;
    const float *dww = Wp(16) + i * 128 * 9, *dwb = Wp(17) + i * 128;
    const float *f2w = Wp(18) + i * 128 * 64, *f2b = Wp(19) + i * 64;

    k_prep1<<<dim3(80), dim3(256), 0, stream>>>(qkvw, wow, f2w, WTq, WTo, WT2);
    k_pcln<<<dim3(Pp / 4), dim3(256), 0, stream>>>(X, A, T, Tb, posw, posb, l1g, l1b);
    // QKV: Q -> X (f32), V -> Vb (bf16)
    k_mf<64, 64, 64, float, bf16, false><<<dim3(Pp / 128), dim3(256), 0, stream>>>(
        Tb, WTq, qkvb, qkvb + 128, nullptr, X, Vb);
    k_pool8<<<dim3(2048), dim3(64), 0, stream>>>(T, Y8);
    k_poolwin<<<dim3(128), dim3(64), 0, stream>>>(Y8, Ym);
    k_qkwin<<<dim3(64), dim3(256), 0, stream>>>(Ym, qkvw, qkvb, QW, KW);
    k_kvp<<<dim3(1024), dim3(256), 0, stream>>>(Y8, qkvw, qkvb, KVP);
    k_route<<<dim3(2), dim3(64), 0, stream>>>(QW, KW, RIDX);
    k_attn<<<dim3(1024), dim3(256), 0, stream>>>(X, KVP, RIDX, T);
    k_lepe4<<<dim3(Pp / 16), dim3(256), 0, stream>>>(Vb, T, Sb, lpw, lpb);
    // wo: X = Sb@wo + wob + A
    k_mf<64, 64, 0, float, float, true><<<dim3(Pp / 128), dim3(256), 0, stream>>>(
        Sb, WTo, wob, nullptr, A, X, nullptr);
    k_lnb<<<dim3(Pp / 4), dim3(256), 0, stream>>>(X, A2b, l2g, l2b);
    k_combine<<<dim3(32), dim3(256), 0, stream>>>(f1w, f1b, pww, Wc, bc);
    k_prep2<<<dim3(64), dim3(256), 0, stream>>>(f1w, Wc, WTf1);
    // FC1: VH -> T (bf16), PWO -> R (bf16)
    k_mf<64, 128, 128, bf16, bf16, false><<<dim3(Pp / 128), dim3(256), 0, stream>>>(
        A2b, WTf1, f1b + 128, bc, nullptr, VH, PWO);
    k_gludw4<<<dim3(Pp / 8), dim3(256), 0, stream>>>(PWO, VH, dww, dwb, G);
    // fc2: X = G@fc2 + f2b + X
    k_mf<128, 64, 0, float, float, true><<<dim3(Pp / 128), dim3(256), 0, stream>>>(
        G, WT2, f2b, nullptr, X, X, nullptr);
  }
  k_out<<<dim3(2048), dim3(256), 0, stream>>>(X, (float*)d_out);
}

// Round 6
// 677.766 us; speedup vs baseline: 4.1907x; 1.3995x over previous
//
#include <hip/hip_runtime.h>
#include <hip/hip_bf16.h>

typedef __hip_bfloat16 bf16;
typedef __attribute__((ext_vector_type(8))) short short8v;
typedef __attribute__((ext_vector_type(4))) float f32x4;

static constexpr int Nn = 2, Hh = 256, Wd = 256;
static constexpr int Pp = Nn * Hh * Wd;  // 131072 pixels

// ---- scalar/vector load-store helpers ----
__device__ inline void sto(float* p, size_t i, float v) { p[i] = v; }
__device__ inline void sto(bf16* p, size_t i, float v) { p[i] = __float2bfloat16(v); }
__device__ inline void ld4(const float* p, float f[4]) {
  const float4 v = *(const float4*)p;
  f[0] = v.x; f[1] = v.y; f[2] = v.z; f[3] = v.w;
}
__device__ inline void ld4(const bf16* p, float f[4]) {
  uint2 u = *(const uint2*)p;
  f[0] = __uint_as_float(u.x << 16); f[1] = __uint_as_float(u.x & 0xffff0000u);
  f[2] = __uint_as_float(u.y << 16); f[3] = __uint_as_float(u.y & 0xffff0000u);
}
__device__ inline void st4(float* p, const float f[4]) {
  *(float4*)p = make_float4(f[0], f[1], f[2], f[3]);
}
__device__ inline void st4(bf16* p, const float f[4]) {
  union { bf16 h[4]; uint2 u; } x;
  x.h[0] = __float2bfloat16(f[0]); x.h[1] = __float2bfloat16(f[1]);
  x.h[2] = __float2bfloat16(f[2]); x.h[3] = __float2bfloat16(f[3]);
  *(uint2*)p = x.u;
}

// ---- NCHW f32 -> NHWC f32, LDS-tiled ----
__global__ void __launch_bounds__(256) k_in_tr(const float* __restrict__ xin,
                                               float* __restrict__ X) {
  __shared__ float t[64][65];
  int blk = blockIdx.x;
  int wt = blk & 3, h = (blk >> 2) & 255, n = blk >> 10;
  int w0 = wt * 64;
  int tx = threadIdx.x & 63, ty = threadIdx.x >> 6;
  const float* src = xin + ((size_t)n * 64 * 256 + h) * 256 + w0;
#pragma unroll
  for (int cc = 0; cc < 16; cc++) {
    int c = cc * 4 + ty;
    t[c][tx] = src[(size_t)c * 65536 + tx];
  }
  __syncthreads();
  float* dst = X + (size_t)(n * 65536 + h * 256 + w0) * 64;
#pragma unroll
  for (int jj = 0; jj < 16; jj++) {
    int j = jj * 4 + ty;
    dst[(size_t)j * 64 + tx] = t[tx][j];
  }
}

// ---- NHWC f32 -> NCHW f32 ----
__global__ void __launch_bounds__(256) k_out(const float* __restrict__ X,
                                             float* __restrict__ out) {
  __shared__ float t[64][65];
  int blk = blockIdx.x;
  int wt = blk & 3, h = (blk >> 2) & 255, n = blk >> 10;
  int w0 = wt * 64;
  int tx = threadIdx.x & 63, ty = threadIdx.x >> 6;
  const float* src = X + (size_t)(n * 65536 + h * 256 + w0) * 64;
#pragma unroll
  for (int jj = 0; jj < 16; jj++) {
    int j = jj * 4 + ty;
    t[tx][j] = src[(size_t)j * 64 + tx];
  }
  __syncthreads();
  float* dst = out + ((size_t)n * 64 * 256 + h) * 256 + w0;
#pragma unroll
  for (int cc = 0; cc < 16; cc++) {
    int c = cc * 4 + ty;
    dst[(size_t)c * 65536 + tx] = t[c][tx];
  }
}

// ---- fused, 4ch/thread: A = X + dw3x3(X); T = LN1(A) f32; Tb = bf16 ----
__global__ void __launch_bounds__(256) k_pcln4(const float* __restrict__ X,
                                               float* __restrict__ A, float* __restrict__ T,
                                               bf16* __restrict__ Tb,
                                               const float* __restrict__ pw,
                                               const float* __restrict__ pb,
                                               const float* __restrict__ g,
                                               const float* __restrict__ b) {
  __shared__ float w9[9][64];
  __shared__ float bb[64];
  int tid = threadIdx.x;
  for (int j = tid; j < 576; j += 256) w9[j % 9][j / 9] = pw[j];
  if (tid < 64) bb[tid] = pb[tid];
  __syncthreads();
  int gid = blockIdx.x * 256 + tid;
  int pix = gid >> 4, cq = (gid & 15) << 2;
  int w = pix & 255, h = (pix >> 8) & 255, n = pix >> 16;
  float acc[4];
  {
    const float4 b4 = *(const float4*)&bb[cq];
    acc[0] = b4.x; acc[1] = b4.y; acc[2] = b4.z; acc[3] = b4.w;
  }
#pragma unroll
  for (int ky = 0; ky < 3; ky++) {
    int hh = h + ky - 1;
    if ((unsigned)hh >= 256u) continue;
#pragma unroll
    for (int kx = 0; kx < 3; kx++) {
      int ww = w + kx - 1;
      if ((unsigned)ww >= 256u) continue;
      const float4 wv = *(const float4*)&w9[ky * 3 + kx][cq];
      float f[4];
      ld4(X + (size_t)((n << 16) | (hh << 8) | ww) * 64 + cq, f);
      acc[0] += wv.x * f[0]; acc[1] += wv.y * f[1];
      acc[2] += wv.z * f[2]; acc[3] += wv.w * f[3];
    }
  }
  float a[4];
  {
    float xc[4];
    ld4(X + (size_t)pix * 64 + cq, xc);
#pragma unroll
    for (int j = 0; j < 4; j++) a[j] = xc[j] + acc[j];
  }
  st4(A + (size_t)pix * 64 + cq, a);
  float s = a[0] + a[1] + a[2] + a[3];
#pragma unroll
  for (int off = 8; off; off >>= 1) s += __shfl_xor(s, off);
  float mean = s * (1.f / 64.f);
  float d[4], q = 0.f;
#pragma unroll
  for (int j = 0; j < 4; j++) { d[j] = a[j] - mean; q += d[j] * d[j]; }
#pragma unroll
  for (int off = 8; off; off >>= 1) q += __shfl_xor(q, off);
  float inv = rsqrtf(q * (1.f / 64.f) + 1e-6f);
  const float4 g4 = *(const float4*)&g[cq];
  const float4 b4 = *(const float4*)&b[cq];
  float y[4] = {d[0] * inv * g4.x + b4.x, d[1] * inv * g4.y + b4.y,
                d[2] * inv * g4.z + b4.z, d[3] * inv * g4.w + b4.w};
  st4(T + (size_t)pix * 64 + cq, y);
  st4(Tb + (size_t)pix * 64 + cq, y);
}

// ---- LN2, 4ch/thread -> bf16 ----
__global__ void __launch_bounds__(256) k_lnb4(const float* __restrict__ In,
                                              bf16* __restrict__ Out,
                                              const float* __restrict__ g,
                                              const float* __restrict__ b) {
  int gid = blockIdx.x * 256 + threadIdx.x;
  int pix = gid >> 4, cq = (gid & 15) << 2;
  float a[4];
  ld4(In + (size_t)pix * 64 + cq, a);
  float s = a[0] + a[1] + a[2] + a[3];
#pragma unroll
  for (int off = 8; off; off >>= 1) s += __shfl_xor(s, off);
  float mean = s * (1.f / 64.f);
  float d[4], q = 0.f;
#pragma unroll
  for (int j = 0; j < 4; j++) { d[j] = a[j] - mean; q += d[j] * d[j]; }
#pragma unroll
  for (int off = 8; off; off >>= 1) q += __shfl_xor(q, off);
  float inv = rsqrtf(q * (1.f / 64.f) + 1e-6f);
  const float4 g4 = *(const float4*)&g[cq];
  const float4 b4 = *(const float4*)&b[cq];
  float y[4] = {d[0] * inv * g4.x + b4.x, d[1] * inv * g4.y + b4.y,
                d[2] * inv * g4.z + b4.z, d[3] * inv * g4.w + b4.w};
  st4(Out + (size_t)pix * 64 + cq, y);
}

// ---- weight prep 1: WTq[128][64], WTo[64][64], WT2[64][128] (bf16 transposed) ----
__global__ void k_prep1(const float* __restrict__ qkvw, const float* __restrict__ wow,
                        const float* __restrict__ f2w, bf16* __restrict__ WTq,
                        bf16* __restrict__ WTo, bf16* __restrict__ WT2) {
  int t = blockIdx.x * 256 + threadIdx.x;
  if (t < 8192) {
    int r = t >> 6, k = t & 63;
    int src = r < 64 ? r : r + 64;  // Q cols 0..63, V cols 128..191
    WTq[t] = __float2bfloat16(qkvw[k * 192 + src]);
  } else if (t < 12288) {
    int t2 = t - 8192;
    int r = t2 >> 6, k = t2 & 63;
    WTo[t2] = __float2bfloat16(wow[k * 64 + r]);
  } else if (t < 20480) {
    int t2 = t - 12288;
    int r = t2 >> 7, k = t2 & 127;
    WT2[t2] = __float2bfloat16(f2w[k * 64 + r]);
  }
}

// ---- Wc = W1a @ pw^T (f32); bc = b1a @ pw^T ----
__global__ void k_combine(const float* __restrict__ f1w, const float* __restrict__ f1b,
                          const float* __restrict__ pww, float* __restrict__ Wc,
                          float* __restrict__ bc) {
  int t = blockIdx.x * blockDim.x + threadIdx.x;
  if (t >= 8192) return;
  int o = t & 127, k = t >> 7;
  float acc = 0.f;
  for (int j = 0; j < 128; j++) acc += f1w[k * 256 + j] * pww[o * 128 + j];
  Wc[k * 128 + o] = acc;
  if (k == 0) {
    float b = 0.f;
    for (int j = 0; j < 128; j++) b += f1b[j] * pww[o * 128 + j];
    bc[o] = b;
  }
}

// ---- weight prep 2: WTf1[256][64] = [W1b^T ; Wc^T] bf16 ----
__global__ void k_prep2(const float* __restrict__ f1w, const float* __restrict__ Wc,
                        bf16* __restrict__ WTf1) {
  int t = blockIdx.x * 256 + threadIdx.x;
  if (t >= 16384) return;
  int r = t >> 6, k = t & 63;
  float v = r < 128 ? f1w[k * 256 + 128 + r] : Wc[k * 128 + (r - 128)];
  WTf1[t] = __float2bfloat16(v);
}

// ---- unified MFMA GEMM (see round-5 notes) ----
template <int K, int N1, int N2, typename TO1, typename TO2, bool RES>
__global__ void __launch_bounds__(256) k_mf(const bf16* __restrict__ In,
                                            const bf16* __restrict__ WT,
                                            const float* __restrict__ b1,
                                            const float* __restrict__ b2,
                                            const float* __restrict__ Res,
                                            TO1* __restrict__ O1, TO2* __restrict__ O2) {
  constexpr int NC = N1 + N2;
  constexpr int KS = K / 32;
  constexpr int NTW = NC / 64;
  constexpr int KB = K * 2;
  constexpr int CH = NC * K / 8;
  __shared__ char lw[NC * K * 2];
  int tid = threadIdx.x;
  for (int ch = tid; ch < CH; ch += 256) {
    int r = ch / (K / 8), cg = ch % (K / 8);
    int byte = (r * KB + cg * 16) ^ ((r & 7) << 4);
    *(uint4*)(lw + byte) = *(const uint4*)((const short*)WT + ch * 8);
  }
  __syncthreads();
  int wid = tid >> 6, lane = tid & 63;
  int lr = lane & 15, lg = lane >> 4;
  int mb = blockIdx.x * 128;
#pragma unroll 2
  for (int ms = 0; ms < 8; ms++) {
    int m0 = mb + ms * 16;
    short8v a[KS];
#pragma unroll
    for (int ks = 0; ks < KS; ks++)
      a[ks] = *(const short8v*)((const short*)In + (size_t)(m0 + lr) * K + ks * 32 + lg * 8);
#pragma unroll
    for (int t = 0; t < NTW; t++) {
      int nt = wid * NTW + t;
      int col = nt * 16 + lr;
      float bv = (N2 == 0 || col < N1) ? b1[col] : b2[col - N1];
      f32x4 acc = {bv, bv, bv, bv};
#pragma unroll
      for (int ks = 0; ks < KS; ks++) {
        int byte = (col * KB + ks * 64 + lg * 16) ^ ((col & 7) << 4);
        short8v bfrag = *(const short8v*)(lw + byte);
        acc = __builtin_amdgcn_mfma_f32_16x16x32_bf16(a[ks], bfrag, acc, 0, 0, 0);
      }
      int r0 = m0 + lg * 4;
#pragma unroll
      for (int j = 0; j < 4; j++) {
        float v = acc[j];
        size_t row = r0 + j;
        if (RES) v += Res[row * N1 + col];
        if (N2 == 0 || col < N1) sto(O1, row * N1 + col, v);
        else sto(O2, row * N2 + (col - N1), v);
      }
    }
  }
}

// ---- 8x8 block means of LN1 (f32, exact routing path) ----
__global__ void k_pool8(const float* __restrict__ T, float* __restrict__ Y8) {
  int b = blockIdx.x;
  int c = threadIdx.x;
  int bx = b & 31, by = (b >> 5) & 31, n = b >> 10;
  float acc = 0.f;
  for (int r = 0; r < 8; r++)
    for (int s = 0; s < 8; s++) {
      int p = (n << 16) | ((by * 8 + r) << 8) | (bx * 8 + s);
      acc += T[(size_t)p * 64 + c];
    }
  Y8[(size_t)b * 64 + c] = acc * (1.f / 64.f);
}

__global__ void k_poolwin(const float* __restrict__ Y8, float* __restrict__ Ym) {
  int b = blockIdx.x;
  int c = threadIdx.x;
  int win = b & 63, n = b >> 6, wi = win >> 3, wj = win & 7;
  float acc = 0.f;
  for (int ti = 0; ti < 4; ti++)
    for (int tj = 0; tj < 4; tj++) {
      int y8 = (n * 32 + wi * 4 + ti) * 32 + wj * 4 + tj;
      acc += Y8[(size_t)y8 * 64 + c];
    }
  Ym[(size_t)b * 64 + c] = acc * (1.f / 16.f);
}

__global__ void k_qkwin(const float* __restrict__ Ym, const float* __restrict__ qw,
                        const float* __restrict__ qb, float* __restrict__ QW,
                        float* __restrict__ KW) {
  int t = blockIdx.x * blockDim.x + threadIdx.x;
  if (t >= 16384) return;
  int c = t & 63, row = (t >> 6) & 127, sel = t >> 13;
  const float* y = Ym + (size_t)row * 64;
  int col = sel * 64 + c;
  float acc = qb[col];
  for (int k = 0; k < 64; k++) acc += y[k] * qw[k * 192 + col];
  (sel ? KW : QW)[(size_t)row * 64 + c] = acc;
}

__global__ void k_kvp(const float* __restrict__ Y8, const float* __restrict__ qw,
                      const float* __restrict__ qb, float* __restrict__ KVP) {
  int t = blockIdx.x * blockDim.x + threadIdx.x;
  if (t >= 262144) return;
  int c2 = t & 127, tok = (t >> 7) & 15, win = (t >> 11) & 63, n = t >> 17;
  int wi = win >> 3, wj = win & 7, ti = tok >> 2, tj = tok & 3;
  int y8 = (n * 32 + wi * 4 + ti) * 32 + wj * 4 + tj;
  const float* y = Y8 + (size_t)y8 * 64;
  int col = 64 + c2;
  float acc = qb[col];
  for (int k = 0; k < 64; k++) acc += y[k] * qw[k * 192 + col];
  KVP[t] = acc;
}

// ---- routing: top-4, one block per query window, lane = candidate ----
__global__ void __launch_bounds__(64) k_route(const float* __restrict__ QW,
                                              const float* __restrict__ KW,
                                              int* __restrict__ RIDX) {
  __shared__ float kk[64][65];
  __shared__ float qq[64];
  int b = blockIdx.x;          // 128 = n*64 + qw
  int lane = threadIdx.x;      // candidate window
  int n = b >> 6;
  qq[lane] = QW[(size_t)b * 64 + lane];
  for (int r = 0; r < 64; r++) kk[r][lane] = KW[(size_t)(n * 64 + r) * 64 + lane];
  __syncthreads();
  float t = 0.f;
  for (int c = 0; c < 64; c++) t += qq[c] * kk[lane][c];
  t *= 0.125f;
  int o0 = 0, o1 = 0, o2 = 0, o3 = 0;
#pragma unroll
  for (int j = 0; j < 4; j++) {
    float v = t; int idx = lane;
#pragma unroll
    for (int off = 32; off; off >>= 1) {
      float ov = __shfl_xor(v, off);
      int oi = __shfl_xor(idx, off);
      if (ov > v || (ov == v && oi < idx)) { v = ov; idx = oi; }
    }
    if (j == 0) o0 = idx; else if (j == 1) o1 = idx;
    else if (j == 2) o2 = idx; else o3 = idx;
    if (lane == idx) t = -1e30f;
  }
  if (lane == 0) {
    int* o = RIDX + (size_t)b * 4;
    o[0] = o0; o[1] = o1; o[2] = o2; o[3] = o3;
  }
}

// ---- attention: 8 parts/window, 2 thr/query x 4 heads, float4 LDS ----
__global__ void __launch_bounds__(256) k_attn(const float* __restrict__ Q,
                                              const float* __restrict__ KVP,
                                              const int* __restrict__ RIDX,
                                              float* __restrict__ S) {
  __shared__ float ks[64][64];
  __shared__ float vs[64][64];
  __shared__ int idx[4];
  int blk = blockIdx.x;
  int part = blk & 7, bw = blk >> 3;
  int n = bw >> 6, win = bw & 63;
  if (threadIdx.x < 4) idx[threadIdx.x] = RIDX[bw * 4 + threadIdx.x];
  __syncthreads();
  for (int t = threadIdx.x; t < 1024; t += 256) {
    int tok = t >> 4, c4 = (t & 15) << 2;
    const float* src = KVP + ((size_t)(n * 64 + idx[tok >> 4]) * 16 + (tok & 15)) * 128;
    *(float4*)&ks[tok][c4] = *(const float4*)&src[c4];
    *(float4*)&vs[tok][c4] = *(const float4*)&src[64 + c4];
  }
  __syncthreads();
  int ql = threadIdx.x >> 1, half = threadIdx.x & 1;
  int q = part * 128 + ql;
  int wi = win >> 3, wj = win & 7;
  int r = q >> 5, s = q & 31;
  int p = (n << 16) | ((wi * 32 + r) << 8) | (wj * 32 + s);
  const float* qp = Q + (size_t)p * 64 + half * 32;
  float qr[4][8];
#pragma unroll
  for (int hh = 0; hh < 4; hh++) {
    const float4 a = *(const float4*)&qp[hh * 8];
    const float4 b = *(const float4*)&qp[hh * 8 + 4];
    qr[hh][0] = a.x * 0.125f; qr[hh][1] = a.y * 0.125f;
    qr[hh][2] = a.z * 0.125f; qr[hh][3] = a.w * 0.125f;
    qr[hh][4] = b.x * 0.125f; qr[hh][5] = b.y * 0.125f;
    qr[hh][6] = b.z * 0.125f; qr[hh][7] = b.w * 0.125f;
  }
  float m[4] = {-1e30f, -1e30f, -1e30f, -1e30f};
  float l[4] = {0, 0, 0, 0};
  float out[4][8];
#pragma unroll
  for (int hh = 0; hh < 4; hh++)
#pragma unroll
    for (int d = 0; d < 8; d++) out[hh][d] = 0.f;
  for (int k = 0; k < 64; k++) {
    const float* kk = &ks[k][half * 32];
    const float* vv = &vs[k][half * 32];
#pragma unroll
    for (int hh = 0; hh < 4; hh++) {
      const float4 ka = *(const float4*)&kk[hh * 8];
      const float4 kb = *(const float4*)&kk[hh * 8 + 4];
      float t = qr[hh][0] * ka.x + qr[hh][1] * ka.y + qr[hh][2] * ka.z + qr[hh][3] * ka.w +
                qr[hh][4] * kb.x + qr[hh][5] * kb.y + qr[hh][6] * kb.z + qr[hh][7] * kb.w;
      float nm = fmaxf(m[hh], t);
      float corr = __expf(m[hh] - nm);
      float e = __expf(t - nm);
      l[hh] = l[hh] * corr + e;
      const float4 va = *(const float4*)&vv[hh * 8];
      const float4 vb = *(const float4*)&vv[hh * 8 + 4];
      out[hh][0] = out[hh][0] * corr + e * va.x;
      out[hh][1] = out[hh][1] * corr + e * va.y;
      out[hh][2] = out[hh][2] * corr + e * va.z;
      out[hh][3] = out[hh][3] * corr + e * va.w;
      out[hh][4] = out[hh][4] * corr + e * vb.x;
      out[hh][5] = out[hh][5] * corr + e * vb.y;
      out[hh][6] = out[hh][6] * corr + e * vb.z;
      out[hh][7] = out[hh][7] * corr + e * vb.w;
      m[hh] = nm;
    }
  }
  float* op = S + (size_t)p * 64 + half * 32;
#pragma unroll
  for (int hh = 0; hh < 4; hh++) {
    float inv = 1.f / l[hh];
    *(float4*)&op[hh * 8] = make_float4(out[hh][0] * inv, out[hh][1] * inv,
                                        out[hh][2] * inv, out[hh][3] * inv);
    *(float4*)&op[hh * 8 + 4] = make_float4(out[hh][4] * inv, out[hh][5] * inv,
                                            out[hh][6] * inv, out[hh][7] * inv);
  }
}

// ---- LePE: Sb = bf16(S + dw5x5(V)) ----
__global__ void __launch_bounds__(256) k_lepe4(const bf16* __restrict__ V,
                                               const float* __restrict__ S,
                                               bf16* __restrict__ Sb,
                                               const float* __restrict__ wt,
                                               const float* __restrict__ bs) {
  __shared__ float w5[25][64];
  __shared__ float bb[64];
  int tid = threadIdx.x;
  for (int j = tid; j < 1600; j += 256) w5[j % 25][j / 25] = wt[j];
  if (tid < 64) bb[tid] = bs[tid];
  __syncthreads();
  int i = blockIdx.x * 256 + tid;
  int cg = i & 15, p = i >> 4;
  int c0 = cg << 2;
  int w = p & 255, h = (p >> 8) & 255, n = p >> 16;
  float acc[4];
  {
    const float4 b4 = *(const float4*)&bb[c0];
    acc[0] = b4.x; acc[1] = b4.y; acc[2] = b4.z; acc[3] = b4.w;
  }
#pragma unroll
  for (int ky = 0; ky < 5; ky++) {
    int hh = h + ky - 2;
    if ((unsigned)hh >= 256u) continue;
#pragma unroll
    for (int kx = 0; kx < 5; kx++) {
      int ww = w + kx - 2;
      if ((unsigned)ww >= 256u) continue;
      const float4 wv = *(const float4*)&w5[ky * 5 + kx][c0];
      float f[4];
      ld4(V + (size_t)((n << 16) | (hh << 8) | ww) * 64 + c0, f);
      acc[0] += wv.x * f[0]; acc[1] += wv.y * f[1];
      acc[2] += wv.z * f[2]; acc[3] += wv.w * f[3];
    }
  }
  const float4 sv = *(const float4*)&S[(size_t)p * 64 + c0];
  float o[4] = {sv.x + acc[0], sv.y + acc[1], sv.z + acc[2], sv.w + acc[3]};
  st4(Sb + (size_t)p * 64 + c0, o);
}

// ---- GLU tail: G = gelu(dw3(PWO)+dwb) * VH ----
__global__ void __launch_bounds__(256) k_gludw4(const bf16* __restrict__ PWO,
                                                const bf16* __restrict__ VH,
                                                const float* __restrict__ wt,
                                                const float* __restrict__ bs,
                                                bf16* __restrict__ G) {
  __shared__ float wd[9][128];
  __shared__ float bb[128];
  int tid = threadIdx.x;
  for (int j = tid; j < 1152; j += 256) wd[j % 9][j / 9] = wt[j];
  if (tid < 128) bb[tid] = bs[tid];
  __syncthreads();
  int i = blockIdx.x * 256 + tid;
  int cg = i & 31, p = i >> 5;
  int c0 = cg << 2;
  int w = p & 255, h = (p >> 8) & 255, n = p >> 16;
  float acc[4];
  {
    const float4 b4 = *(const float4*)&bb[c0];
    acc[0] = b4.x; acc[1] = b4.y; acc[2] = b4.z; acc[3] = b4.w;
  }
#pragma unroll
  for (int ky = 0; ky < 3; ky++) {
    int hh = h + ky - 1;
    if ((unsigned)hh >= 256u) continue;
#pragma unroll
    for (int kx = 0; kx < 3; kx++) {
      int ww = w + kx - 1;
      if ((unsigned)ww >= 256u) continue;
      const float4 wv = *(const float4*)&wd[ky * 3 + kx][c0];
      float f[4];
      ld4(PWO + (size_t)((n << 16) | (hh << 8) | ww) * 128 + c0, f);
      acc[0] += wv.x * f[0]; acc[1] += wv.y * f[1];
      acc[2] += wv.z * f[2]; acc[3] += wv.w * f[3];
    }
  }
  float vh[4];
  ld4(VH + (size_t)p * 128 + c0, vh);
  float g[4];
#pragma unroll
  for (int j = 0; j < 4; j++) {
    float ge = 0.5f * acc[j] * (1.f + erff(acc[j] * 0.70710678118f));
    g[j] = ge * vh[j];
  }
  st4(G + (size_t)p * 128 + c0, g);
}

extern "C" void kernel_launch(void* const* d_in, const int* in_sizes, int n_in,
                              void* d_out, int out_size, void* d_ws, size_t ws_size,
                              hipStream_t stream) {
  (void)in_sizes; (void)n_in; (void)out_size; (void)ws_size;
  const float* xin = (const float*)d_in[0];
  auto Wp = [&](int i) { return (const float*)d_in[i]; };
  char* ws = (char*)d_ws;
  const size_t MB = 1u << 20;
  float* X  = (float*)(ws + 0 * MB);    // trunk / Q (f32)
  float* A  = (float*)(ws + 32 * MB);   // residual f32; later A2b bf16 @32, G bf16 @48
  float* T  = (float*)(ws + 64 * MB);   // LN1 f32 / S f32; later VH bf16
  char*  R  = ws + 96 * MB;             // Vb bf16 @96; Tb/Sb bf16 @112; PWO bf16 @96
  char*  sm = ws + 128 * MB;
  size_t off = 0;
  auto alloc = [&](size_t bytes) {
    void* p = sm + off;
    off += (bytes + 255) & ~(size_t)255;
    return p;
  };
  float* Y8   = (float*)alloc(2 * 32 * 32 * 64 * 4);
  float* Ym   = (float*)alloc(2 * 64 * 64 * 4);
  float* QW   = (float*)alloc(2 * 64 * 64 * 4);
  float* KW   = (float*)alloc(2 * 64 * 64 * 4);
  float* KVP  = (float*)alloc(2 * 64 * 16 * 128 * 4);
  int*  RIDX  = (int*)alloc(2 * 64 * 4 * 4);
  float* Wc   = (float*)alloc(64 * 128 * 4);
  float* bc   = (float*)alloc(128 * 4);
  bf16* WTq   = (bf16*)alloc(128 * 64 * 2);
  bf16* WTo   = (bf16*)alloc(64 * 64 * 2);
  bf16* WT2   = (bf16*)alloc(64 * 128 * 2);
  bf16* WTf1  = (bf16*)alloc(256 * 64 * 2);
  bf16* Vb   = (bf16*)R;                 // [P][64]
  bf16* Tb   = (bf16*)(ws + 112 * MB);   // [P][64]
  bf16* Sb   = Tb;                       // reuse after QKV GEMM
  bf16* PWO  = (bf16*)R;                 // [P][128] after lepe
  bf16* VH   = (bf16*)T;                 // [P][128] after pool8
  bf16* A2b  = (bf16*)A;                 // [P][64] after wo
  bf16* G    = (bf16*)(ws + 48 * MB);    // [P][128]

  k_in_tr<<<dim3(2048), dim3(256), 0, stream>>>(xin, X);
  for (int i = 0; i < 2; i++) {
    const float *posw = Wp(1) + i * 64 * 9, *posb = Wp(2) + i * 64;
    const float *l1g = Wp(3) + i * 64, *l1b = Wp(4) + i * 64;
    const float *qkvw = Wp(5) + i * 64 * 192, *qkvb = Wp(6) + i * 192;
    const float *lpw = Wp(7) + i * 64 * 25, *lpb = Wp(8) + i * 64;
    const float *wow = Wp(9) + i * 64 * 64, *wob = Wp(10) + i * 64;
    const float *l2g = Wp(11) + i * 64, *l2b = Wp(12) + i * 64;
    const float *f1w = Wp(13) + i * 64 * 256, *f1b = Wp(14) + i * 256;
    const float *pww = Wp(15) + i * 128 * 128;
    const float *dww = Wp(16) + i * 128 * 9, *dwb = Wp(17) + i * 128;
    const float *f2w = Wp(18) + i * 128 * 64, *f2b = Wp(19) + i * 64;

    k_prep1<<<dim3(80), dim3(256), 0, stream>>>(qkvw, wow, f2w, WTq, WTo, WT2);
    k_pcln4<<<dim3(Pp / 16), dim3(256), 0, stream>>>(X, A, T, Tb, posw, posb, l1g, l1b);
    // QKV: Q -> X (f32), V -> Vb (bf16)
    k_mf<64, 64, 64, float, bf16, false><<<dim3(Pp / 128), dim3(256), 0, stream>>>(
        Tb, WTq, qkvb, qkvb + 128, nullptr, X, Vb);
    k_pool8<<<dim3(2048), dim3(64), 0, stream>>>(T, Y8);
    k_poolwin<<<dim3(128), dim3(64), 0, stream>>>(Y8, Ym);
    k_qkwin<<<dim3(64), dim3(256), 0, stream>>>(Ym, qkvw, qkvb, QW, KW);
    k_kvp<<<dim3(1024), dim3(256), 0, stream>>>(Y8, qkvw, qkvb, KVP);
    k_route<<<dim3(128), dim3(64), 0, stream>>>(QW, KW, RIDX);
    k_attn<<<dim3(1024), dim3(256), 0, stream>>>(X, KVP, RIDX, T);
    k_lepe4<<<dim3(Pp / 16), dim3(256), 0, stream>>>(Vb, T, Sb, lpw, lpb);
    // wo: X = Sb@wo + wob + A
    k_mf<64, 64, 0, float, float, true><<<dim3(Pp / 128), dim3(256), 0, stream>>>(
        Sb, WTo, wob, nullptr, A, X, nullptr);
    k_lnb4<<<dim3(Pp / 16), dim3(256), 0, stream>>>(X, A2b, l2g, l2b);
    k_combine<<<dim3(32), dim3(256), 0, stream>>>(f1w, f1b, pww, Wc, bc);
    k_prep2<<<dim3(64), dim3(256), 0, stream>>>(f1w, Wc, WTf1);
    // FC1: VH -> T (bf16), PWO -> R (bf16)
    k_mf<64, 128, 128, bf16, bf16, false><<<dim3(Pp / 128), dim3(256), 0, stream>>>(
        A2b, WTf1, f1b + 128, bc, nullptr, VH, PWO);
    k_gludw4<<<dim3(Pp / 8), dim3(256), 0, stream>>>(PWO, VH, dww, dwb, G);
    // fc2: X = G@fc2 + f2b + X
    k_mf<128, 64, 0, float, float, true><<<dim3(Pp / 128), dim3(256), 0, stream>>>(
        G, WT2, f2b, nullptr, X, X, nullptr);
  }
  k_out<<<dim3(2048), dim3(256), 0, stream>>>(X, (float*)d_out);
}

// Round 7
// 555.688 us; speedup vs baseline: 5.1113x; 1.2197x over previous
//
#include <hip/hip_runtime.h>
#include <hip/hip_bf16.h>

typedef __hip_bfloat16 bf16;
typedef __attribute__((ext_vector_type(8))) short short8v;
typedef __attribute__((ext_vector_type(4))) float f32x4;

static constexpr int Nn = 2, Hh = 256, Wd = 256;
static constexpr int Pp = Nn * Hh * Wd;  // 131072 pixels

// ---- scalar/vector load-store helpers ----
__device__ inline void sto(float* p, size_t i, float v) { p[i] = v; }
__device__ inline void sto(bf16* p, size_t i, float v) { p[i] = __float2bfloat16(v); }
__device__ inline void ld4(const float* p, float f[4]) {
  const float4 v = *(const float4*)p;
  f[0] = v.x; f[1] = v.y; f[2] = v.z; f[3] = v.w;
}
__device__ inline void ld4(const bf16* p, float f[4]) {
  uint2 u = *(const uint2*)p;
  f[0] = __uint_as_float(u.x << 16); f[1] = __uint_as_float(u.x & 0xffff0000u);
  f[2] = __uint_as_float(u.y << 16); f[3] = __uint_as_float(u.y & 0xffff0000u);
}
__device__ inline void st4(float* p, const float f[4]) {
  *(float4*)p = make_float4(f[0], f[1], f[2], f[3]);
}
__device__ inline void st4(bf16* p, const float f[4]) {
  union { bf16 h[4]; uint2 u; } x;
  x.h[0] = __float2bfloat16(f[0]); x.h[1] = __float2bfloat16(f[1]);
  x.h[2] = __float2bfloat16(f[2]); x.h[3] = __float2bfloat16(f[3]);
  *(uint2*)p = x.u;
}
__device__ inline uint2 pk4(float a, float b, float c, float d) {
  union { bf16 h[4]; uint2 u; } x;
  x.h[0] = __float2bfloat16(a); x.h[1] = __float2bfloat16(b);
  x.h[2] = __float2bfloat16(c); x.h[3] = __float2bfloat16(d);
  return x.u;
}

// ---- NCHW f32 -> NHWC f32, LDS-tiled ----
__global__ void __launch_bounds__(256) k_in_tr(const float* __restrict__ xin,
                                               float* __restrict__ X) {
  __shared__ float t[64][65];
  int blk = blockIdx.x;
  int wt = blk & 3, h = (blk >> 2) & 255, n = blk >> 10;
  int w0 = wt * 64;
  int tx = threadIdx.x & 63, ty = threadIdx.x >> 6;
  const float* src = xin + ((size_t)n * 64 * 256 + h) * 256 + w0;
#pragma unroll
  for (int cc = 0; cc < 16; cc++) {
    int c = cc * 4 + ty;
    t[c][tx] = src[(size_t)c * 65536 + tx];
  }
  __syncthreads();
  float* dst = X + (size_t)(n * 65536 + h * 256 + w0) * 64;
#pragma unroll
  for (int jj = 0; jj < 16; jj++) {
    int j = jj * 4 + ty;
    dst[(size_t)j * 64 + tx] = t[tx][j];
  }
}

// ---- NHWC f32 -> NCHW f32 ----
__global__ void __launch_bounds__(256) k_out(const float* __restrict__ X,
                                             float* __restrict__ out) {
  __shared__ float t[64][65];
  int blk = blockIdx.x;
  int wt = blk & 3, h = (blk >> 2) & 255, n = blk >> 10;
  int w0 = wt * 64;
  int tx = threadIdx.x & 63, ty = threadIdx.x >> 6;
  const float* src = X + (size_t)(n * 65536 + h * 256 + w0) * 64;
#pragma unroll
  for (int jj = 0; jj < 16; jj++) {
    int j = jj * 4 + ty;
    t[tx][j] = src[(size_t)j * 64 + tx];
  }
  __syncthreads();
  float* dst = out + ((size_t)n * 64 * 256 + h) * 256 + w0;
#pragma unroll
  for (int cc = 0; cc < 16; cc++) {
    int c = cc * 4 + ty;
    dst[(size_t)c * 65536 + tx] = t[c][tx];
  }
}

// ---- fused, 4ch/thread: A = X + dw3x3(X); T = LN1(A) f32; Tb = bf16 ----
__global__ void __launch_bounds__(256) k_pcln4(const float* __restrict__ X,
                                               float* __restrict__ A, float* __restrict__ T,
                                               bf16* __restrict__ Tb,
                                               const float* __restrict__ pw,
                                               const float* __restrict__ pb,
                                               const float* __restrict__ g,
                                               const float* __restrict__ b) {
  __shared__ float w9[9][64];
  __shared__ float bb[64];
  int tid = threadIdx.x;
  for (int j = tid; j < 576; j += 256) w9[j % 9][j / 9] = pw[j];
  if (tid < 64) bb[tid] = pb[tid];
  __syncthreads();
  int gid = blockIdx.x * 256 + tid;
  int pix = gid >> 4, cq = (gid & 15) << 2;
  int w = pix & 255, h = (pix >> 8) & 255, n = pix >> 16;
  float acc[4];
  {
    const float4 b4 = *(const float4*)&bb[cq];
    acc[0] = b4.x; acc[1] = b4.y; acc[2] = b4.z; acc[3] = b4.w;
  }
#pragma unroll
  for (int ky = 0; ky < 3; ky++) {
    int hh = h + ky - 1;
    if ((unsigned)hh >= 256u) continue;
#pragma unroll
    for (int kx = 0; kx < 3; kx++) {
      int ww = w + kx - 1;
      if ((unsigned)ww >= 256u) continue;
      const float4 wv = *(const float4*)&w9[ky * 3 + kx][cq];
      float f[4];
      ld4(X + (size_t)((n << 16) | (hh << 8) | ww) * 64 + cq, f);
      acc[0] += wv.x * f[0]; acc[1] += wv.y * f[1];
      acc[2] += wv.z * f[2]; acc[3] += wv.w * f[3];
    }
  }
  float a[4];
  {
    float xc[4];
    ld4(X + (size_t)pix * 64 + cq, xc);
#pragma unroll
    for (int j = 0; j < 4; j++) a[j] = xc[j] + acc[j];
  }
  st4(A + (size_t)pix * 64 + cq, a);
  float s = a[0] + a[1] + a[2] + a[3];
#pragma unroll
  for (int off = 8; off; off >>= 1) s += __shfl_xor(s, off);
  float mean = s * (1.f / 64.f);
  float d[4], q = 0.f;
#pragma unroll
  for (int j = 0; j < 4; j++) { d[j] = a[j] - mean; q += d[j] * d[j]; }
#pragma unroll
  for (int off = 8; off; off >>= 1) q += __shfl_xor(q, off);
  float inv = rsqrtf(q * (1.f / 64.f) + 1e-6f);
  const float4 g4 = *(const float4*)&g[cq];
  const float4 b4 = *(const float4*)&b[cq];
  float y[4] = {d[0] * inv * g4.x + b4.x, d[1] * inv * g4.y + b4.y,
                d[2] * inv * g4.z + b4.z, d[3] * inv * g4.w + b4.w};
  st4(T + (size_t)pix * 64 + cq, y);
  st4(Tb + (size_t)pix * 64 + cq, y);
}

// ---- LN2, 4ch/thread -> bf16 ----
__global__ void __launch_bounds__(256) k_lnb4(const float* __restrict__ In,
                                              bf16* __restrict__ Out,
                                              const float* __restrict__ g,
                                              const float* __restrict__ b) {
  int gid = blockIdx.x * 256 + threadIdx.x;
  int pix = gid >> 4, cq = (gid & 15) << 2;
  float a[4];
  ld4(In + (size_t)pix * 64 + cq, a);
  float s = a[0] + a[1] + a[2] + a[3];
#pragma unroll
  for (int off = 8; off; off >>= 1) s += __shfl_xor(s, off);
  float mean = s * (1.f / 64.f);
  float d[4], q = 0.f;
#pragma unroll
  for (int j = 0; j < 4; j++) { d[j] = a[j] - mean; q += d[j] * d[j]; }
#pragma unroll
  for (int off = 8; off; off >>= 1) q += __shfl_xor(q, off);
  float inv = rsqrtf(q * (1.f / 64.f) + 1e-6f);
  const float4 g4 = *(const float4*)&g[cq];
  const float4 b4 = *(const float4*)&b[cq];
  float y[4] = {d[0] * inv * g4.x + b4.x, d[1] * inv * g4.y + b4.y,
                d[2] * inv * g4.z + b4.z, d[3] * inv * g4.w + b4.w};
  st4(Out + (size_t)pix * 64 + cq, y);
}

// ---- weight prep 1: WTq[128][64] (Q rows pre-scaled by 1/8), WTo, WT2; qbs ----
__global__ void k_prep1(const float* __restrict__ qkvw, const float* __restrict__ qkvb,
                        const float* __restrict__ wow, const float* __restrict__ f2w,
                        bf16* __restrict__ WTq, bf16* __restrict__ WTo,
                        bf16* __restrict__ WT2, float* __restrict__ qbs) {
  int t = blockIdx.x * 256 + threadIdx.x;
  if (t < 8192) {
    int r = t >> 6, k = t & 63;
    int src = r < 64 ? r : r + 64;  // Q cols 0..63, V cols 128..191
    float v = qkvw[k * 192 + src];
    if (r < 64) v *= 0.125f;        // fold qk scale into Q (exact: 2^-3)
    WTq[t] = __float2bfloat16(v);
  } else if (t < 12288) {
    int t2 = t - 8192;
    int r = t2 >> 6, k = t2 & 63;
    WTo[t2] = __float2bfloat16(wow[k * 64 + r]);
  } else if (t < 20480) {
    int t2 = t - 12288;
    int r = t2 >> 7, k = t2 & 127;
    WT2[t2] = __float2bfloat16(f2w[k * 64 + r]);
  }
  if (t < 64) qbs[t] = qkvb[t] * 0.125f;
}

// ---- Wc = W1a @ pw^T (f32); bc = b1a @ pw^T ----
__global__ void k_combine(const float* __restrict__ f1w, const float* __restrict__ f1b,
                          const float* __restrict__ pww, float* __restrict__ Wc,
                          float* __restrict__ bc) {
  int t = blockIdx.x * blockDim.x + threadIdx.x;
  if (t >= 8192) return;
  int o = t & 127, k = t >> 7;
  float acc = 0.f;
  for (int j = 0; j < 128; j++) acc += f1w[k * 256 + j] * pww[o * 128 + j];
  Wc[k * 128 + o] = acc;
  if (k == 0) {
    float b = 0.f;
    for (int j = 0; j < 128; j++) b += f1b[j] * pww[o * 128 + j];
    bc[o] = b;
  }
}

// ---- weight prep 2: WTf1[256][64] = [W1b^T ; Wc^T] bf16 ----
__global__ void k_prep2(const float* __restrict__ f1w, const float* __restrict__ Wc,
                        bf16* __restrict__ WTf1) {
  int t = blockIdx.x * 256 + threadIdx.x;
  if (t >= 16384) return;
  int r = t >> 6, k = t & 63;
  float v = r < 128 ? f1w[k * 256 + 128 + r] : Wc[k * 128 + (r - 128)];
  WTf1[t] = __float2bfloat16(v);
}

// ---- unified MFMA GEMM ----
template <int K, int N1, int N2, typename TO1, typename TO2, bool RES>
__global__ void __launch_bounds__(256) k_mf(const bf16* __restrict__ In,
                                            const bf16* __restrict__ WT,
                                            const float* __restrict__ b1,
                                            const float* __restrict__ b2,
                                            const float* __restrict__ Res,
                                            TO1* __restrict__ O1, TO2* __restrict__ O2) {
  constexpr int NC = N1 + N2;
  constexpr int KS = K / 32;
  constexpr int NTW = NC / 64;
  constexpr int KB = K * 2;
  constexpr int CH = NC * K / 8;
  __shared__ char lw[NC * K * 2];
  int tid = threadIdx.x;
  for (int ch = tid; ch < CH; ch += 256) {
    int r = ch / (K / 8), cg = ch % (K / 8);
    int byte = (r * KB + cg * 16) ^ ((r & 7) << 4);
    *(uint4*)(lw + byte) = *(const uint4*)((const short*)WT + ch * 8);
  }
  __syncthreads();
  int wid = tid >> 6, lane = tid & 63;
  int lr = lane & 15, lg = lane >> 4;
  int mb = blockIdx.x * 128;
#pragma unroll 2
  for (int ms = 0; ms < 8; ms++) {
    int m0 = mb + ms * 16;
    short8v a[KS];
#pragma unroll
    for (int ks = 0; ks < KS; ks++)
      a[ks] = *(const short8v*)((const short*)In + (size_t)(m0 + lr) * K + ks * 32 + lg * 8);
#pragma unroll
    for (int t = 0; t < NTW; t++) {
      int nt = wid * NTW + t;
      int col = nt * 16 + lr;
      float bv = (N2 == 0 || col < N1) ? b1[col] : b2[col - N1];
      f32x4 acc = {bv, bv, bv, bv};
#pragma unroll
      for (int ks = 0; ks < KS; ks++) {
        int byte = (col * KB + ks * 64 + lg * 16) ^ ((col & 7) << 4);
        short8v bfrag = *(const short8v*)(lw + byte);
        acc = __builtin_amdgcn_mfma_f32_16x16x32_bf16(a[ks], bfrag, acc, 0, 0, 0);
      }
      int r0 = m0 + lg * 4;
#pragma unroll
      for (int j = 0; j < 4; j++) {
        float v = acc[j];
        size_t row = r0 + j;
        if (RES) v += Res[row * N1 + col];
        if (N2 == 0 || col < N1) sto(O1, row * N1 + col, v);
        else sto(O2, row * N2 + (col - N1), v);
      }
    }
  }
}

// ---- 8x8 block means of LN1 (f32, exact routing path) ----
__global__ void k_pool8(const float* __restrict__ T, float* __restrict__ Y8) {
  int b = blockIdx.x;
  int c = threadIdx.x;
  int bx = b & 31, by = (b >> 5) & 31, n = b >> 10;
  float acc = 0.f;
  for (int r = 0; r < 8; r++)
    for (int s = 0; s < 8; s++) {
      int p = (n << 16) | ((by * 8 + r) << 8) | (bx * 8 + s);
      acc += T[(size_t)p * 64 + c];
    }
  Y8[(size_t)b * 64 + c] = acc * (1.f / 64.f);
}

__global__ void k_poolwin(const float* __restrict__ Y8, float* __restrict__ Ym) {
  int b = blockIdx.x;
  int c = threadIdx.x;
  int win = b & 63, n = b >> 6, wi = win >> 3, wj = win & 7;
  float acc = 0.f;
  for (int ti = 0; ti < 4; ti++)
    for (int tj = 0; tj < 4; tj++) {
      int y8 = (n * 32 + wi * 4 + ti) * 32 + wj * 4 + tj;
      acc += Y8[(size_t)y8 * 64 + c];
    }
  Ym[(size_t)b * 64 + c] = acc * (1.f / 16.f);
}

__global__ void k_qkwin(const float* __restrict__ Ym, const float* __restrict__ qw,
                        const float* __restrict__ qb, float* __restrict__ QW,
                        float* __restrict__ KW) {
  int t = blockIdx.x * blockDim.x + threadIdx.x;
  if (t >= 16384) return;
  int c = t & 63, row = (t >> 6) & 127, sel = t >> 13;
  const float* y = Ym + (size_t)row * 64;
  int col = sel * 64 + c;
  float acc = qb[col];
  for (int k = 0; k < 64; k++) acc += y[k] * qw[k * 192 + col];
  (sel ? KW : QW)[(size_t)row * 64 + c] = acc;
}

__global__ void k_kvp(const float* __restrict__ Y8, const float* __restrict__ qw,
                      const float* __restrict__ qb, float* __restrict__ KVP) {
  int t = blockIdx.x * blockDim.x + threadIdx.x;
  if (t >= 262144) return;
  int c2 = t & 127, tok = (t >> 7) & 15, win = (t >> 11) & 63, n = t >> 17;
  int wi = win >> 3, wj = win & 7, ti = tok >> 2, tj = tok & 3;
  int y8 = (n * 32 + wi * 4 + ti) * 32 + wj * 4 + tj;
  const float* y = Y8 + (size_t)y8 * 64;
  int col = 64 + c2;
  float acc = qb[col];
  for (int k = 0; k < 64; k++) acc += y[k] * qw[k * 192 + col];
  KVP[t] = acc;
}

// ---- routing: top-4, one block per query window, lane = candidate ----
__global__ void __launch_bounds__(64) k_route(const float* __restrict__ QW,
                                              const float* __restrict__ KW,
                                              int* __restrict__ RIDX) {
  __shared__ float kk[64][65];
  __shared__ float qq[64];
  int b = blockIdx.x;          // 128 = n*64 + qw
  int lane = threadIdx.x;      // candidate window
  int n = b >> 6;
  qq[lane] = QW[(size_t)b * 64 + lane];
  for (int r = 0; r < 64; r++) kk[r][lane] = KW[(size_t)(n * 64 + r) * 64 + lane];
  __syncthreads();
  float t = 0.f;
  for (int c = 0; c < 64; c++) t += qq[c] * kk[lane][c];
  t *= 0.125f;
  int o0 = 0, o1 = 0, o2 = 0, o3 = 0;
#pragma unroll
  for (int j = 0; j < 4; j++) {
    float v = t; int idx = lane;
#pragma unroll
    for (int off = 32; off; off >>= 1) {
      float ov = __shfl_xor(v, off);
      int oi = __shfl_xor(idx, off);
      if (ov > v || (ov == v && oi < idx)) { v = ov; idx = oi; }
    }
    if (j == 0) o0 = idx; else if (j == 1) o1 = idx;
    else if (j == 2) o2 = idx; else o3 = idx;
    if (lane == idx) t = -1e30f;
  }
  if (lane == 0) {
    int* o = RIDX + (size_t)b * 4;
    o[0] = o0; o[1] = o1; o[2] = o2; o[3] = o3;
  }
}

// ---- MFMA attention: S^T = K@Q^T (swapped), softmax lane-local, O = P@V ----
// Qb: bf16 [P][64], pre-scaled by 1/8. Writes S (f32 [P][64]).
__global__ void __launch_bounds__(256) k_attn_mf(const bf16* __restrict__ Qb,
                                                 const float* __restrict__ KVP,
                                                 const int* __restrict__ RIDX,
                                                 float* __restrict__ S) {
  __shared__ bf16 ks[64][72];      // K row-major (kv, d); stride 144B -> 2-way max
  __shared__ bf16 vt[64][72];      // V^T (d, kv)
  __shared__ bf16 pa[4][16][72];   // P per wave (q, kv)
  __shared__ float ldn[4][16];     // softmax denominators per wave
  __shared__ int idx[4];
  int blk = blockIdx.x;            // 512 = (n*64+win)*4 + part
  int part = blk & 3, bw = blk >> 2;
  int n = bw >> 6, win = bw & 63;
  int tid = threadIdx.x;
  if (tid < 4) idx[tid] = RIDX[bw * 4 + tid];
  __syncthreads();
  {  // stage K (bf16) and V^T
    int tok = tid & 63;
    const float* src = KVP + ((size_t)(n * 64 + idx[tok >> 4]) * 16 + (tok & 15)) * 128;
    for (int cq = tid >> 6; cq < 16; cq += 4) {
      int c0 = cq * 4;
      const float4 k4 = *(const float4*)&src[c0];
      *(uint2*)&ks[tok][c0] = pk4(k4.x, k4.y, k4.z, k4.w);
      const float4 v4 = *(const float4*)&src[64 + c0];
      vt[c0 + 0][tok] = __float2bfloat16(v4.x);
      vt[c0 + 1][tok] = __float2bfloat16(v4.y);
      vt[c0 + 2][tok] = __float2bfloat16(v4.z);
      vt[c0 + 3][tok] = __float2bfloat16(v4.w);
    }
  }
  __syncthreads();
  int w = tid >> 6, lane = tid & 63;
  int lr = lane & 15, lg = lane >> 4;
  int wi = win >> 3, wj = win & 7;
  for (int it = 0; it < 4; it++) {
    int qbase = part * 256 + w * 64 + it * 16;
    // Q B-fragments from global (lane holds Q[q=lr][d=ks2*32+lg*8+e])
    int q_b = qbase + lr;
    int pix_b = (n << 16) | ((wi * 32 + (q_b >> 5)) << 8) | (wj * 32 + (q_b & 31));
    short8v qf0 = *(const short8v*)((const short*)Qb + (size_t)pix_b * 64 + lg * 8);
    short8v qf1 = *(const short8v*)((const short*)Qb + (size_t)pix_b * 64 + 32 + lg * 8);
    // S^T tiles: p[mt][j] = S[kv=mt*16+lg*4+j][q=lr]
    f32x4 p[4] = {{0,0,0,0},{0,0,0,0},{0,0,0,0},{0,0,0,0}};
#pragma unroll
    for (int mt = 0; mt < 4; mt++) {
      short8v a0 = *(const short8v*)&ks[mt * 16 + lr][lg * 8];
      p[mt] = __builtin_amdgcn_mfma_f32_16x16x32_bf16(a0, qf0, p[mt], 0, 0, 0);
    }
#pragma unroll
    for (int mt = 0; mt < 4; mt++) {
      short8v a1 = *(const short8v*)&ks[mt * 16 + lr][32 + lg * 8];
      p[mt] = __builtin_amdgcn_mfma_f32_16x16x32_bf16(a1, qf1, p[mt], 0, 0, 0);
    }
    // softmax over kv: 16 local + reduce across the 4 lanes sharing q=lr
    float mx = -1e30f;
#pragma unroll
    for (int mt = 0; mt < 4; mt++)
#pragma unroll
      for (int j = 0; j < 4; j++) mx = fmaxf(mx, p[mt][j]);
    mx = fmaxf(mx, __shfl_xor(mx, 16));
    mx = fmaxf(mx, __shfl_xor(mx, 32));
    float e[4][4];
    float sum = 0.f;
#pragma unroll
    for (int mt = 0; mt < 4; mt++)
#pragma unroll
      for (int j = 0; j < 4; j++) { e[mt][j] = __expf(p[mt][j] - mx); sum += e[mt][j]; }
    sum += __shfl_xor(sum, 16);
    sum += __shfl_xor(sum, 32);
    if (lg == 0) ldn[w][lr] = sum;
    // P -> LDS (bf16), row q=lr, cols kv=mt*16+lg*4+j
#pragma unroll
    for (int mt = 0; mt < 4; mt++)
      *(uint2*)&pa[w][lr][mt * 16 + lg * 4] = pk4(e[mt][0], e[mt][1], e[mt][2], e[mt][3]);
    // PV: A = P[q][kv], B = V^T
    short8v pf0 = *(const short8v*)&pa[w][lr][lg * 8];
    short8v pf1 = *(const short8v*)&pa[w][lr][32 + lg * 8];
    f32x4 o4[4] = {{0,0,0,0},{0,0,0,0},{0,0,0,0},{0,0,0,0}};
#pragma unroll
    for (int nt = 0; nt < 4; nt++) {
      short8v v0 = *(const short8v*)&vt[nt * 16 + lr][lg * 8];
      o4[nt] = __builtin_amdgcn_mfma_f32_16x16x32_bf16(pf0, v0, o4[nt], 0, 0, 0);
    }
#pragma unroll
    for (int nt = 0; nt < 4; nt++) {
      short8v v1 = *(const short8v*)&vt[nt * 16 + lr][32 + lg * 8];
      o4[nt] = __builtin_amdgcn_mfma_f32_16x16x32_bf16(pf1, v1, o4[nt], 0, 0, 0);
    }
    // epilogue: O[q=lg*4+j][d=nt*16+lr] / l[q]
    float linv[4];
#pragma unroll
    for (int j = 0; j < 4; j++) linv[j] = 1.f / ldn[w][lg * 4 + j];
#pragma unroll
    for (int j = 0; j < 4; j++) {
      int q_o = qbase + lg * 4 + j;
      size_t pix_o = (n << 16) | ((wi * 32 + (q_o >> 5)) << 8) | (wj * 32 + (q_o & 31));
      float* op = S + pix_o * 64 + lr;
#pragma unroll
      for (int nt = 0; nt < 4; nt++) op[nt * 16] = o4[nt][j] * linv[j];
    }
  }
}

// ---- LePE: Sb = bf16(S + dw5x5(V)) ----
__global__ void __launch_bounds__(256) k_lepe4(const bf16* __restrict__ V,
                                               const float* __restrict__ S,
                                               bf16* __restrict__ Sb,
                                               const float* __restrict__ wt,
                                               const float* __restrict__ bs) {
  __shared__ float w5[25][64];
  __shared__ float bb[64];
  int tid = threadIdx.x;
  for (int j = tid; j < 1600; j += 256) w5[j % 25][j / 25] = wt[j];
  if (tid < 64) bb[tid] = bs[tid];
  __syncthreads();
  int i = blockIdx.x * 256 + tid;
  int cg = i & 15, p = i >> 4;
  int c0 = cg << 2;
  int w = p & 255, h = (p >> 8) & 255, n = p >> 16;
  float acc[4];
  {
    const float4 b4 = *(const float4*)&bb[c0];
    acc[0] = b4.x; acc[1] = b4.y; acc[2] = b4.z; acc[3] = b4.w;
  }
#pragma unroll
  for (int ky = 0; ky < 5; ky++) {
    int hh = h + ky - 2;
    if ((unsigned)hh >= 256u) continue;
#pragma unroll
    for (int kx = 0; kx < 5; kx++) {
      int ww = w + kx - 2;
      if ((unsigned)ww >= 256u) continue;
      const float4 wv = *(const float4*)&w5[ky * 5 + kx][c0];
      float f[4];
      ld4(V + (size_t)((n << 16) | (hh << 8) | ww) * 64 + c0, f);
      acc[0] += wv.x * f[0]; acc[1] += wv.y * f[1];
      acc[2] += wv.z * f[2]; acc[3] += wv.w * f[3];
    }
  }
  const float4 sv = *(const float4*)&S[(size_t)p * 64 + c0];
  float o[4] = {sv.x + acc[0], sv.y + acc[1], sv.z + acc[2], sv.w + acc[3]};
  st4(Sb + (size_t)p * 64 + c0, o);
}

// ---- GLU tail: G = gelu(dw3(PWO)+dwb) * VH ----
__global__ void __launch_bounds__(256) k_gludw4(const bf16* __restrict__ PWO,
                                                const bf16* __restrict__ VH,
                                                const float* __restrict__ wt,
                                                const float* __restrict__ bs,
                                                bf16* __restrict__ G) {
  __shared__ float wd[9][128];
  __shared__ float bb[128];
  int tid = threadIdx.x;
  for (int j = tid; j < 1152; j += 256) wd[j % 9][j / 9] = wt[j];
  if (tid < 128) bb[tid] = bs[tid];
  __syncthreads();
  int i = blockIdx.x * 256 + tid;
  int cg = i & 31, p = i >> 5;
  int c0 = cg << 2;
  int w = p & 255, h = (p >> 8) & 255, n = p >> 16;
  float acc[4];
  {
    const float4 b4 = *(const float4*)&bb[c0];
    acc[0] = b4.x; acc[1] = b4.y; acc[2] = b4.z; acc[3] = b4.w;
  }
#pragma unroll
  for (int ky = 0; ky < 3; ky++) {
    int hh = h + ky - 1;
    if ((unsigned)hh >= 256u) continue;
#pragma unroll
    for (int kx = 0; kx < 3; kx++) {
      int ww = w + kx - 1;
      if ((unsigned)ww >= 256u) continue;
      const float4 wv = *(const float4*)&wd[ky * 3 + kx][c0];
      float f[4];
      ld4(PWO + (size_t)((n << 16) | (hh << 8) | ww) * 128 + c0, f);
      acc[0] += wv.x * f[0]; acc[1] += wv.y * f[1];
      acc[2] += wv.z * f[2]; acc[3] += wv.w * f[3];
    }
  }
  float vh[4];
  ld4(VH + (size_t)p * 128 + c0, vh);
  float g[4];
#pragma unroll
  for (int j = 0; j < 4; j++) {
    float ge = 0.5f * acc[j] * (1.f + erff(acc[j] * 0.70710678118f));
    g[j] = ge * vh[j];
  }
  st4(G + (size_t)p * 128 + c0, g);
}

extern "C" void kernel_launch(void* const* d_in, const int* in_sizes, int n_in,
                              void* d_out, int out_size, void* d_ws, size_t ws_size,
                              hipStream_t stream) {
  (void)in_sizes; (void)n_in; (void)out_size; (void)ws_size;
  const float* xin = (const float*)d_in[0];
  auto Wp = [&](int i) { return (const float*)d_in[i]; };
  char* ws = (char*)d_ws;
  const size_t MB = 1u << 20;
  float* X  = (float*)(ws + 0 * MB);    // trunk f32 / Qb bf16
  float* A  = (float*)(ws + 32 * MB);   // residual f32; later A2b bf16, G bf16 @48
  float* T  = (float*)(ws + 64 * MB);   // LN1 f32 / S f32; later VH bf16
  char*  R  = ws + 96 * MB;             // Vb bf16 @96; Tb/Sb bf16 @112; PWO bf16 @96
  char*  sm = ws + 128 * MB;
  size_t off = 0;
  auto alloc = [&](size_t bytes) {
    void* p = sm + off;
    off += (bytes + 255) & ~(size_t)255;
    return p;
  };
  float* Y8   = (float*)alloc(2 * 32 * 32 * 64 * 4);
  float* Ym   = (float*)alloc(2 * 64 * 64 * 4);
  float* QW   = (float*)alloc(2 * 64 * 64 * 4);
  float* KW   = (float*)alloc(2 * 64 * 64 * 4);
  float* KVP  = (float*)alloc(2 * 64 * 16 * 128 * 4);
  int*  RIDX  = (int*)alloc(2 * 64 * 4 * 4);
  float* Wc   = (float*)alloc(64 * 128 * 4);
  float* bc   = (float*)alloc(128 * 4);
  bf16* WTq   = (bf16*)alloc(128 * 64 * 2);
  bf16* WTo   = (bf16*)alloc(64 * 64 * 2);
  bf16* WT2   = (bf16*)alloc(64 * 128 * 2);
  bf16* WTf1  = (bf16*)alloc(256 * 64 * 2);
  float* qbs  = (float*)alloc(64 * 4);
  bf16* Vb   = (bf16*)R;                 // [P][64]
  bf16* Qb   = (bf16*)X;                 // [P][64] (X trunk dead after pcln)
  bf16* Tb   = (bf16*)(ws + 112 * MB);   // [P][64]
  bf16* Sb   = Tb;                       // reuse after QKV GEMM
  bf16* PWO  = (bf16*)R;                 // [P][128] after lepe
  bf16* VH   = (bf16*)T;                 // [P][128] after pool8
  bf16* A2b  = (bf16*)A;                 // [P][64] after wo
  bf16* G    = (bf16*)(ws + 48 * MB);    // [P][128]

  k_in_tr<<<dim3(2048), dim3(256), 0, stream>>>(xin, X);
  for (int i = 0; i < 2; i++) {
    const float *posw = Wp(1) + i * 64 * 9, *posb = Wp(2) + i * 64;
    const float *l1g = Wp(3) + i * 64, *l1b = Wp(4) + i * 64;
    const float *qkvw = Wp(5) + i * 64 * 192, *qkvb = Wp(6) + i * 192;
    const float *lpw = Wp(7) + i * 64 * 25, *lpb = Wp(8) + i * 64;
    const float *wow = Wp(9) + i * 64 * 64, *wob = Wp(10) + i * 64;
    const float *l2g = Wp(11) + i * 64, *l2b = Wp(12) + i * 64;
    const float *f1w = Wp(13) + i * 64 * 256, *f1b = Wp(14) + i * 256;
    const float *pww = Wp(15) + i * 128 * 128;
    const float *dww = Wp(16) + i * 128 * 9, *dwb = Wp(17) + i * 128;
    const float *f2w = Wp(18) + i * 128 * 64, *f2b = Wp(19) + i * 64;

    k_prep1<<<dim3(80), dim3(256), 0, stream>>>(qkvw, qkvb, wow, f2w, WTq, WTo, WT2, qbs);
    k_pcln4<<<dim3(Pp / 16), dim3(256), 0, stream>>>(X, A, T, Tb, posw, posb, l1g, l1b);
    // QKV: Qb (bf16, pre-scaled) -> X region, V -> Vb (bf16)
    k_mf<64, 64, 64, bf16, bf16, false><<<dim3(Pp / 128), dim3(256), 0, stream>>>(
        Tb, WTq, qbs, qkvb + 128, nullptr, Qb, Vb);
    k_pool8<<<dim3(2048), dim3(64), 0, stream>>>(T, Y8);
    k_poolwin<<<dim3(128), dim3(64), 0, stream>>>(Y8, Ym);
    k_qkwin<<<dim3(64), dim3(256), 0, stream>>>(Ym, qkvw, qkvb, QW, KW);
    k_kvp<<<dim3(1024), dim3(256), 0, stream>>>(Y8, qkvw, qkvb, KVP);
    k_route<<<dim3(128), dim3(64), 0, stream>>>(QW, KW, RIDX);
    k_attn_mf<<<dim3(512), dim3(256), 0, stream>>>(Qb, KVP, RIDX, T);
    k_lepe4<<<dim3(Pp / 16), dim3(256), 0, stream>>>(Vb, T, Sb, lpw, lpb);
    // wo: X = Sb@wo + wob + A
    k_mf<64, 64, 0, float, float, true><<<dim3(Pp / 128), dim3(256), 0, stream>>>(
        Sb, WTo, wob, nullptr, A, X, nullptr);
    k_lnb4<<<dim3(Pp / 16), dim3(256), 0, stream>>>(X, A2b, l2g, l2b);
    k_combine<<<dim3(32), dim3(256), 0, stream>>>(f1w, f1b, pww, Wc, bc);
    k_prep2<<<dim3(64), dim3(256), 0, stream>>>(f1w, Wc, WTf1);
    // FC1: VH -> T (bf16), PWO -> R (bf16)
    k_mf<64, 128, 128, bf16, bf16, false><<<dim3(Pp / 128), dim3(256), 0, stream>>>(
        A2b, WTf1, f1b + 128, bc, nullptr, VH, PWO);
    k_gludw4<<<dim3(Pp / 8), dim3(256), 0, stream>>>(PWO, VH, dww, dwb, G);
    // fc2: X = G@fc2 + f2b + X
    k_mf<128, 64, 0, float, float, true><<<dim3(Pp / 128), dim3(256), 0, stream>>>(
        G, WT2, f2b, nullptr, X, X, nullptr);
  }
  k_out<<<dim3(2048), dim3(256), 0, stream>>>(X, (float*)d_out);
}

// Round 8
// 476.801 us; speedup vs baseline: 5.9570x; 1.1655x over previous
//
#include <hip/hip_runtime.h>
#include <hip/hip_bf16.h>

typedef __hip_bfloat16 bf16;
typedef __attribute__((ext_vector_type(8))) short short8v;
typedef __attribute__((ext_vector_type(4))) float f32x4;

static constexpr int Nn = 2, Hh = 256, Wd = 256;
static constexpr int Pp = Nn * Hh * Wd;  // 131072 pixels

// ---- scalar/vector load-store helpers ----
__device__ inline void sto(float* p, size_t i, float v) { p[i] = v; }
__device__ inline void sto(bf16* p, size_t i, float v) { p[i] = __float2bfloat16(v); }
__device__ inline void ld4(const float* p, float f[4]) {
  const float4 v = *(const float4*)p;
  f[0] = v.x; f[1] = v.y; f[2] = v.z; f[3] = v.w;
}
__device__ inline void ld4(const bf16* p, float f[4]) {
  uint2 u = *(const uint2*)p;
  f[0] = __uint_as_float(u.x << 16); f[1] = __uint_as_float(u.x & 0xffff0000u);
  f[2] = __uint_as_float(u.y << 16); f[3] = __uint_as_float(u.y & 0xffff0000u);
}
__device__ inline void st4(float* p, const float f[4]) {
  *(float4*)p = make_float4(f[0], f[1], f[2], f[3]);
}
__device__ inline void st4(bf16* p, const float f[4]) {
  union { bf16 h[4]; uint2 u; } x;
  x.h[0] = __float2bfloat16(f[0]); x.h[1] = __float2bfloat16(f[1]);
  x.h[2] = __float2bfloat16(f[2]); x.h[3] = __float2bfloat16(f[3]);
  *(uint2*)p = x.u;
}
__device__ inline uint2 pk4(float a, float b, float c, float d) {
  union { bf16 h[4]; uint2 u; } x;
  x.h[0] = __float2bfloat16(a); x.h[1] = __float2bfloat16(b);
  x.h[2] = __float2bfloat16(c); x.h[3] = __float2bfloat16(d);
  return x.u;
}

// ---- NCHW f32 -> NHWC f32, LDS-tiled ----
__global__ void __launch_bounds__(256) k_in_tr(const float* __restrict__ xin,
                                               float* __restrict__ X) {
  __shared__ float t[64][65];
  int blk = blockIdx.x;
  int wt = blk & 3, h = (blk >> 2) & 255, n = blk >> 10;
  int w0 = wt * 64;
  int tx = threadIdx.x & 63, ty = threadIdx.x >> 6;
  const float* src = xin + ((size_t)n * 64 * 256 + h) * 256 + w0;
#pragma unroll
  for (int cc = 0; cc < 16; cc++) {
    int c = cc * 4 + ty;
    t[c][tx] = src[(size_t)c * 65536 + tx];
  }
  __syncthreads();
  float* dst = X + (size_t)(n * 65536 + h * 256 + w0) * 64;
#pragma unroll
  for (int jj = 0; jj < 16; jj++) {
    int j = jj * 4 + ty;
    dst[(size_t)j * 64 + tx] = t[tx][j];
  }
}

// ---- NHWC f32 -> NCHW f32 ----
__global__ void __launch_bounds__(256) k_out(const float* __restrict__ X,
                                             float* __restrict__ out) {
  __shared__ float t[64][65];
  int blk = blockIdx.x;
  int wt = blk & 3, h = (blk >> 2) & 255, n = blk >> 10;
  int w0 = wt * 64;
  int tx = threadIdx.x & 63, ty = threadIdx.x >> 6;
  const float* src = X + (size_t)(n * 65536 + h * 256 + w0) * 64;
#pragma unroll
  for (int jj = 0; jj < 16; jj++) {
    int j = jj * 4 + ty;
    t[tx][j] = src[(size_t)j * 64 + tx];
  }
  __syncthreads();
  float* dst = out + ((size_t)n * 64 * 256 + h) * 256 + w0;
#pragma unroll
  for (int cc = 0; cc < 16; cc++) {
    int c = cc * 4 + ty;
    dst[(size_t)c * 65536 + tx] = t[c][tx];
  }
}

// ---- fused posconv+LN1: 4 px/thread, row-reuse, conflict-free staging ----
__global__ void __launch_bounds__(256) k_pcln4(const float* __restrict__ X,
                                               float* __restrict__ A, float* __restrict__ T,
                                               bf16* __restrict__ Tb,
                                               const float* __restrict__ pw,
                                               const float* __restrict__ pb,
                                               const float* __restrict__ g,
                                               const float* __restrict__ b) {
  __shared__ float w9[9][68];
  __shared__ float bb[64];
  int tid = threadIdx.x;
  for (int j = tid; j < 576; j += 256) {
    int tap = j >> 6, c = j & 63;
    w9[tap][c] = pw[c * 9 + tap];
  }
  if (tid < 64) bb[tid] = pb[tid];
  __syncthreads();
  int gid = blockIdx.x * 256 + tid;
  int cg = gid & 15, pg = gid >> 4;
  int c0 = cg << 2;
  int w0 = (pg & 63) << 2, h = (pg >> 6) & 255, n = pg >> 14;
  int pbase = (n << 16) | (h << 8) | w0;
  float acc[4][4];
  {
    const float4 b4 = *(const float4*)&bb[c0];
#pragma unroll
    for (int px = 0; px < 4; px++) {
      acc[px][0] = b4.x; acc[px][1] = b4.y; acc[px][2] = b4.z; acc[px][3] = b4.w;
    }
  }
  float xc[4][4];
#pragma unroll
  for (int ky = 0; ky < 3; ky++) {
    int hh = h + ky - 1;
    if ((unsigned)hh >= 256u) continue;
    const float* xrow = X + (size_t)((n << 16) | (hh << 8)) * 64 + c0;
    float v[6][4];
#pragma unroll
    for (int dx = 0; dx < 6; dx++) {
      int ww = w0 + dx - 1;
      if ((unsigned)ww < 256u) ld4(xrow + (size_t)ww * 64, v[dx]);
      else { v[dx][0] = 0.f; v[dx][1] = 0.f; v[dx][2] = 0.f; v[dx][3] = 0.f; }
    }
    if (ky == 1) {
#pragma unroll
      for (int px = 0; px < 4; px++)
#pragma unroll
        for (int j = 0; j < 4; j++) xc[px][j] = v[px + 1][j];
    }
#pragma unroll
    for (int kx = 0; kx < 3; kx++) {
      const float4 wv = *(const float4*)&w9[ky * 3 + kx][c0];
#pragma unroll
      for (int px = 0; px < 4; px++) {
        acc[px][0] += wv.x * v[px + kx][0]; acc[px][1] += wv.y * v[px + kx][1];
        acc[px][2] += wv.z * v[px + kx][2]; acc[px][3] += wv.w * v[px + kx][3];
      }
    }
  }
  const float4 g4 = *(const float4*)&g[c0];
  const float4 b4 = *(const float4*)&b[c0];
#pragma unroll
  for (int px = 0; px < 4; px++) {
    float a[4];
#pragma unroll
    for (int j = 0; j < 4; j++) a[j] = xc[px][j] + acc[px][j];
    st4(A + (size_t)(pbase + px) * 64 + c0, a);
    float s = a[0] + a[1] + a[2] + a[3];
#pragma unroll
    for (int off = 8; off; off >>= 1) s += __shfl_xor(s, off);
    float mean = s * (1.f / 64.f);
    float d[4], q = 0.f;
#pragma unroll
    for (int j = 0; j < 4; j++) { d[j] = a[j] - mean; q += d[j] * d[j]; }
#pragma unroll
    for (int off = 8; off; off >>= 1) q += __shfl_xor(q, off);
    float inv = rsqrtf(q * (1.f / 64.f) + 1e-6f);
    float y[4] = {d[0] * inv * g4.x + b4.x, d[1] * inv * g4.y + b4.y,
                  d[2] * inv * g4.z + b4.z, d[3] * inv * g4.w + b4.w};
    st4(T + (size_t)(pbase + px) * 64 + c0, y);
    st4(Tb + (size_t)(pbase + px) * 64 + c0, y);
  }
}

// ---- LN2, 4ch/thread -> bf16 ----
__global__ void __launch_bounds__(256) k_lnb4(const float* __restrict__ In,
                                              bf16* __restrict__ Out,
                                              const float* __restrict__ g,
                                              const float* __restrict__ b) {
  int gid = blockIdx.x * 256 + threadIdx.x;
  int pix = gid >> 4, cq = (gid & 15) << 2;
  float a[4];
  ld4(In + (size_t)pix * 64 + cq, a);
  float s = a[0] + a[1] + a[2] + a[3];
#pragma unroll
  for (int off = 8; off; off >>= 1) s += __shfl_xor(s, off);
  float mean = s * (1.f / 64.f);
  float d[4], q = 0.f;
#pragma unroll
  for (int j = 0; j < 4; j++) { d[j] = a[j] - mean; q += d[j] * d[j]; }
#pragma unroll
  for (int off = 8; off; off >>= 1) q += __shfl_xor(q, off);
  float inv = rsqrtf(q * (1.f / 64.f) + 1e-6f);
  const float4 g4 = *(const float4*)&g[cq];
  const float4 b4 = *(const float4*)&b[cq];
  float y[4] = {d[0] * inv * g4.x + b4.x, d[1] * inv * g4.y + b4.y,
                d[2] * inv * g4.z + b4.z, d[3] * inv * g4.w + b4.w};
  st4(Out + (size_t)pix * 64 + cq, y);
}

// ---- weight prep 1 ----
__global__ void k_prep1(const float* __restrict__ qkvw, const float* __restrict__ qkvb,
                        const float* __restrict__ wow, const float* __restrict__ f2w,
                        bf16* __restrict__ WTq, bf16* __restrict__ WTo,
                        bf16* __restrict__ WT2, float* __restrict__ qbs) {
  int t = blockIdx.x * 256 + threadIdx.x;
  if (t < 8192) {
    int r = t >> 6, k = t & 63;
    int src = r < 64 ? r : r + 64;
    float v = qkvw[k * 192 + src];
    if (r < 64) v *= 0.125f;
    WTq[t] = __float2bfloat16(v);
  } else if (t < 12288) {
    int t2 = t - 8192;
    int r = t2 >> 6, k = t2 & 63;
    WTo[t2] = __float2bfloat16(wow[k * 64 + r]);
  } else if (t < 20480) {
    int t2 = t - 12288;
    int r = t2 >> 7, k = t2 & 127;
    WT2[t2] = __float2bfloat16(f2w[k * 64 + r]);
  }
  if (t < 64) qbs[t] = qkvb[t] * 0.125f;
}

// ---- Wc = W1a @ pw^T (f32); bc = b1a @ pw^T ----
__global__ void k_combine(const float* __restrict__ f1w, const float* __restrict__ f1b,
                          const float* __restrict__ pww, float* __restrict__ Wc,
                          float* __restrict__ bc) {
  int t = blockIdx.x * blockDim.x + threadIdx.x;
  if (t >= 8192) return;
  int o = t & 127, k = t >> 7;
  float acc = 0.f;
  for (int j = 0; j < 128; j++) acc += f1w[k * 256 + j] * pww[o * 128 + j];
  Wc[k * 128 + o] = acc;
  if (k == 0) {
    float b = 0.f;
    for (int j = 0; j < 128; j++) b += f1b[j] * pww[o * 128 + j];
    bc[o] = b;
  }
}

// ---- weight prep 2: WTf1[256][64] = [W1b^T ; Wc^T] bf16 ----
__global__ void k_prep2(const float* __restrict__ f1w, const float* __restrict__ Wc,
                        bf16* __restrict__ WTf1) {
  int t = blockIdx.x * 256 + threadIdx.x;
  if (t >= 16384) return;
  int r = t >> 6, k = t & 63;
  float v = r < 128 ? f1w[k * 256 + 128 + r] : Wc[k * 128 + (r - 128)];
  WTf1[t] = __float2bfloat16(v);
}

// ---- unified MFMA GEMM ----
template <int K, int N1, int N2, typename TO1, typename TO2, bool RES>
__global__ void __launch_bounds__(256) k_mf(const bf16* __restrict__ In,
                                            const bf16* __restrict__ WT,
                                            const float* __restrict__ b1,
                                            const float* __restrict__ b2,
                                            const float* __restrict__ Res,
                                            TO1* __restrict__ O1, TO2* __restrict__ O2) {
  constexpr int NC = N1 + N2;
  constexpr int KS = K / 32;
  constexpr int NTW = NC / 64;
  constexpr int KB = K * 2;
  constexpr int CH = NC * K / 8;
  __shared__ char lw[NC * K * 2];
  int tid = threadIdx.x;
  for (int ch = tid; ch < CH; ch += 256) {
    int r = ch / (K / 8), cg = ch % (K / 8);
    int byte = (r * KB + cg * 16) ^ ((r & 7) << 4);
    *(uint4*)(lw + byte) = *(const uint4*)((const short*)WT + ch * 8);
  }
  __syncthreads();
  int wid = tid >> 6, lane = tid & 63;
  int lr = lane & 15, lg = lane >> 4;
  int mb = blockIdx.x * 128;
#pragma unroll 2
  for (int ms = 0; ms < 8; ms++) {
    int m0 = mb + ms * 16;
    short8v a[KS];
#pragma unroll
    for (int ks = 0; ks < KS; ks++)
      a[ks] = *(const short8v*)((const short*)In + (size_t)(m0 + lr) * K + ks * 32 + lg * 8);
#pragma unroll
    for (int t = 0; t < NTW; t++) {
      int nt = wid * NTW + t;
      int col = nt * 16 + lr;
      float bv = (N2 == 0 || col < N1) ? b1[col] : b2[col - N1];
      f32x4 acc = {bv, bv, bv, bv};
#pragma unroll
      for (int ks = 0; ks < KS; ks++) {
        int byte = (col * KB + ks * 64 + lg * 16) ^ ((col & 7) << 4);
        short8v bfrag = *(const short8v*)(lw + byte);
        acc = __builtin_amdgcn_mfma_f32_16x16x32_bf16(a[ks], bfrag, acc, 0, 0, 0);
      }
      int r0 = m0 + lg * 4;
#pragma unroll
      for (int j = 0; j < 4; j++) {
        float v = acc[j];
        size_t row = r0 + j;
        if (RES) v += Res[row * N1 + col];
        if (N2 == 0 || col < N1) sto(O1, row * N1 + col, v);
        else sto(O2, row * N2 + (col - N1), v);
      }
    }
  }
}

// ---- 8x8 block means of LN1 (f32, exact routing path) ----
__global__ void k_pool8(const float* __restrict__ T, float* __restrict__ Y8) {
  int b = blockIdx.x;
  int c = threadIdx.x;
  int bx = b & 31, by = (b >> 5) & 31, n = b >> 10;
  float acc = 0.f;
  for (int r = 0; r < 8; r++)
    for (int s = 0; s < 8; s++) {
      int p = (n << 16) | ((by * 8 + r) << 8) | (bx * 8 + s);
      acc += T[(size_t)p * 64 + c];
    }
  Y8[(size_t)b * 64 + c] = acc * (1.f / 64.f);
}

__global__ void k_poolwin(const float* __restrict__ Y8, float* __restrict__ Ym) {
  int b = blockIdx.x;
  int c = threadIdx.x;
  int win = b & 63, n = b >> 6, wi = win >> 3, wj = win & 7;
  float acc = 0.f;
  for (int ti = 0; ti < 4; ti++)
    for (int tj = 0; tj < 4; tj++) {
      int y8 = (n * 32 + wi * 4 + ti) * 32 + wj * 4 + tj;
      acc += Y8[(size_t)y8 * 64 + c];
    }
  Ym[(size_t)b * 64 + c] = acc * (1.f / 16.f);
}

__global__ void k_qkwin(const float* __restrict__ Ym, const float* __restrict__ qw,
                        const float* __restrict__ qb, float* __restrict__ QW,
                        float* __restrict__ KW) {
  int t = blockIdx.x * blockDim.x + threadIdx.x;
  if (t >= 16384) return;
  int c = t & 63, row = (t >> 6) & 127, sel = t >> 13;
  const float* y = Ym + (size_t)row * 64;
  int col = sel * 64 + c;
  float acc = qb[col];
  for (int k = 0; k < 64; k++) acc += y[k] * qw[k * 192 + col];
  (sel ? KW : QW)[(size_t)row * 64 + c] = acc;
}

__global__ void k_kvp(const float* __restrict__ Y8, const float* __restrict__ qw,
                      const float* __restrict__ qb, float* __restrict__ KVP) {
  int t = blockIdx.x * blockDim.x + threadIdx.x;
  if (t >= 262144) return;
  int c2 = t & 127, tok = (t >> 7) & 15, win = (t >> 11) & 63, n = t >> 17;
  int wi = win >> 3, wj = win & 7, ti = tok >> 2, tj = tok & 3;
  int y8 = (n * 32 + wi * 4 + ti) * 32 + wj * 4 + tj;
  const float* y = Y8 + (size_t)y8 * 64;
  int col = 64 + c2;
  float acc = qb[col];
  for (int k = 0; k < 64; k++) acc += y[k] * qw[k * 192 + col];
  KVP[t] = acc;
}

// ---- routing: top-4, one block per query window, lane = candidate ----
__global__ void __launch_bounds__(64) k_route(const float* __restrict__ QW,
                                              const float* __restrict__ KW,
                                              int* __restrict__ RIDX) {
  __shared__ float kk[64][65];
  __shared__ float qq[64];
  int b = blockIdx.x;
  int lane = threadIdx.x;
  int n = b >> 6;
  qq[lane] = QW[(size_t)b * 64 + lane];
  for (int r = 0; r < 64; r++) kk[r][lane] = KW[(size_t)(n * 64 + r) * 64 + lane];
  __syncthreads();
  float t = 0.f;
  for (int c = 0; c < 64; c++) t += qq[c] * kk[lane][c];
  t *= 0.125f;
  int o0 = 0, o1 = 0, o2 = 0, o3 = 0;
#pragma unroll
  for (int j = 0; j < 4; j++) {
    float v = t; int idx = lane;
#pragma unroll
    for (int off = 32; off; off >>= 1) {
      float ov = __shfl_xor(v, off);
      int oi = __shfl_xor(idx, off);
      if (ov > v || (ov == v && oi < idx)) { v = ov; idx = oi; }
    }
    if (j == 0) o0 = idx; else if (j == 1) o1 = idx;
    else if (j == 2) o2 = idx; else o3 = idx;
    if (lane == idx) t = -1e30f;
  }
  if (lane == 0) {
    int* o = RIDX + (size_t)b * 4;
    o[0] = o0; o[1] = o1; o[2] = o2; o[3] = o3;
  }
}

// ---- MFMA attention -> bf16 output ----
__global__ void __launch_bounds__(256) k_attn_mf(const bf16* __restrict__ Qb,
                                                 const float* __restrict__ KVP,
                                                 const int* __restrict__ RIDX,
                                                 bf16* __restrict__ Sbf) {
  __shared__ bf16 ks[64][72];
  __shared__ bf16 vt[64][72];
  __shared__ bf16 pa[4][16][72];
  __shared__ float ldn[4][16];
  __shared__ int idx[4];
  int blk = blockIdx.x;
  int part = blk & 3, bw = blk >> 2;
  int n = bw >> 6, win = bw & 63;
  int tid = threadIdx.x;
  if (tid < 4) idx[tid] = RIDX[bw * 4 + tid];
  __syncthreads();
  {
    int tok = tid & 63;
    const float* src = KVP + ((size_t)(n * 64 + idx[tok >> 4]) * 16 + (tok & 15)) * 128;
    for (int cq = tid >> 6; cq < 16; cq += 4) {
      int c0 = cq * 4;
      const float4 k4 = *(const float4*)&src[c0];
      *(uint2*)&ks[tok][c0] = pk4(k4.x, k4.y, k4.z, k4.w);
      const float4 v4 = *(const float4*)&src[64 + c0];
      vt[c0 + 0][tok] = __float2bfloat16(v4.x);
      vt[c0 + 1][tok] = __float2bfloat16(v4.y);
      vt[c0 + 2][tok] = __float2bfloat16(v4.z);
      vt[c0 + 3][tok] = __float2bfloat16(v4.w);
    }
  }
  __syncthreads();
  int w = tid >> 6, lane = tid & 63;
  int lr = lane & 15, lg = lane >> 4;
  int wi = win >> 3, wj = win & 7;
  for (int it = 0; it < 4; it++) {
    int qbase = part * 256 + w * 64 + it * 16;
    int q_b = qbase + lr;
    int pix_b = (n << 16) | ((wi * 32 + (q_b >> 5)) << 8) | (wj * 32 + (q_b & 31));
    short8v qf0 = *(const short8v*)((const short*)Qb + (size_t)pix_b * 64 + lg * 8);
    short8v qf1 = *(const short8v*)((const short*)Qb + (size_t)pix_b * 64 + 32 + lg * 8);
    f32x4 p[4] = {{0,0,0,0},{0,0,0,0},{0,0,0,0},{0,0,0,0}};
#pragma unroll
    for (int mt = 0; mt < 4; mt++) {
      short8v a0 = *(const short8v*)&ks[mt * 16 + lr][lg * 8];
      p[mt] = __builtin_amdgcn_mfma_f32_16x16x32_bf16(a0, qf0, p[mt], 0, 0, 0);
    }
#pragma unroll
    for (int mt = 0; mt < 4; mt++) {
      short8v a1 = *(const short8v*)&ks[mt * 16 + lr][32 + lg * 8];
      p[mt] = __builtin_amdgcn_mfma_f32_16x16x32_bf16(a1, qf1, p[mt], 0, 0, 0);
    }
    float mx = -1e30f;
#pragma unroll
    for (int mt = 0; mt < 4; mt++)
#pragma unroll
      for (int j = 0; j < 4; j++) mx = fmaxf(mx, p[mt][j]);
    mx = fmaxf(mx, __shfl_xor(mx, 16));
    mx = fmaxf(mx, __shfl_xor(mx, 32));
    float e[4][4];
    float sum = 0.f;
#pragma unroll
    for (int mt = 0; mt < 4; mt++)
#pragma unroll
      for (int j = 0; j < 4; j++) { e[mt][j] = __expf(p[mt][j] - mx); sum += e[mt][j]; }
    sum += __shfl_xor(sum, 16);
    sum += __shfl_xor(sum, 32);
    if (lg == 0) ldn[w][lr] = sum;
#pragma unroll
    for (int mt = 0; mt < 4; mt++)
      *(uint2*)&pa[w][lr][mt * 16 + lg * 4] = pk4(e[mt][0], e[mt][1], e[mt][2], e[mt][3]);
    short8v pf0 = *(const short8v*)&pa[w][lr][lg * 8];
    short8v pf1 = *(const short8v*)&pa[w][lr][32 + lg * 8];
    f32x4 o4[4] = {{0,0,0,0},{0,0,0,0},{0,0,0,0},{0,0,0,0}};
#pragma unroll
    for (int nt = 0; nt < 4; nt++) {
      short8v v0 = *(const short8v*)&vt[nt * 16 + lr][lg * 8];
      o4[nt] = __builtin_amdgcn_mfma_f32_16x16x32_bf16(pf0, v0, o4[nt], 0, 0, 0);
    }
#pragma unroll
    for (int nt = 0; nt < 4; nt++) {
      short8v v1 = *(const short8v*)&vt[nt * 16 + lr][32 + lg * 8];
      o4[nt] = __builtin_amdgcn_mfma_f32_16x16x32_bf16(pf1, v1, o4[nt], 0, 0, 0);
    }
    float linv[4];
#pragma unroll
    for (int j = 0; j < 4; j++) linv[j] = 1.f / ldn[w][lg * 4 + j];
#pragma unroll
    for (int j = 0; j < 4; j++) {
      int q_o = qbase + lg * 4 + j;
      size_t pix_o = (n << 16) | ((wi * 32 + (q_o >> 5)) << 8) | (wj * 32 + (q_o & 31));
      bf16* op = Sbf + pix_o * 64 + lr;
#pragma unroll
      for (int nt = 0; nt < 4; nt++) op[nt * 16] = __float2bfloat16(o4[nt][j] * linv[j]);
    }
  }
}

// ---- LePE: 4 px/thread, row-reuse; Sb = bf16(Sbf + dw5x5(V)) ----
__global__ void __launch_bounds__(256) k_lepe4(const bf16* __restrict__ V,
                                               const bf16* __restrict__ Sbf,
                                               bf16* __restrict__ Sb,
                                               const float* __restrict__ wt,
                                               const float* __restrict__ bs) {
  __shared__ float w5[25][68];
  __shared__ float bb[64];
  int tid = threadIdx.x;
  for (int j = tid; j < 1600; j += 256) {
    int tap = j >> 6, c = j & 63;
    w5[tap][c] = wt[c * 25 + tap];
  }
  if (tid < 64) bb[tid] = bs[tid];
  __syncthreads();
  int gid = blockIdx.x * 256 + tid;
  int cg = gid & 15, pg = gid >> 4;
  int c0 = cg << 2;
  int w0 = (pg & 63) << 2, h = (pg >> 6) & 255, n = pg >> 14;
  int pbase = (n << 16) | (h << 8) | w0;
  float acc[4][4];
  {
    const float4 b4 = *(const float4*)&bb[c0];
#pragma unroll
    for (int px = 0; px < 4; px++) {
      acc[px][0] = b4.x; acc[px][1] = b4.y; acc[px][2] = b4.z; acc[px][3] = b4.w;
    }
  }
#pragma unroll
  for (int ky = 0; ky < 5; ky++) {
    int hh = h + ky - 2;
    if ((unsigned)hh >= 256u) continue;
    const bf16* vrow = V + (size_t)((n << 16) | (hh << 8)) * 64 + c0;
    float v[8][4];
#pragma unroll
    for (int dx = 0; dx < 8; dx++) {
      int ww = w0 + dx - 2;
      if ((unsigned)ww < 256u) ld4(vrow + (size_t)ww * 64, v[dx]);
      else { v[dx][0] = 0.f; v[dx][1] = 0.f; v[dx][2] = 0.f; v[dx][3] = 0.f; }
    }
#pragma unroll
    for (int kx = 0; kx < 5; kx++) {
      const float4 wv = *(const float4*)&w5[ky * 5 + kx][c0];
#pragma unroll
      for (int px = 0; px < 4; px++) {
        acc[px][0] += wv.x * v[px + kx][0]; acc[px][1] += wv.y * v[px + kx][1];
        acc[px][2] += wv.z * v[px + kx][2]; acc[px][3] += wv.w * v[px + kx][3];
      }
    }
  }
#pragma unroll
  for (int px = 0; px < 4; px++) {
    float s4[4];
    ld4(Sbf + (size_t)(pbase + px) * 64 + c0, s4);
    float o[4] = {s4[0] + acc[px][0], s4[1] + acc[px][1],
                  s4[2] + acc[px][2], s4[3] + acc[px][3]};
    st4(Sb + (size_t)(pbase + px) * 64 + c0, o);
  }
}

// ---- GLU tail: 4 px/thread; G = gelu(dw3(PWO)+dwb) * VH ----
__global__ void __launch_bounds__(256) k_gludw4(const bf16* __restrict__ PWO,
                                                const bf16* __restrict__ VH,
                                                const float* __restrict__ wt,
                                                const float* __restrict__ bs,
                                                bf16* __restrict__ G) {
  __shared__ float wd[9][132];
  __shared__ float bb[128];
  int tid = threadIdx.x;
  for (int j = tid; j < 1152; j += 256) {
    int tap = j >> 7, c = j & 127;
    wd[tap][c] = wt[c * 9 + tap];
  }
  if (tid < 128) bb[tid] = bs[tid];
  __syncthreads();
  int gid = blockIdx.x * 256 + tid;
  int cg = gid & 31, pg = gid >> 5;
  int c0 = cg << 2;
  int w0 = (pg & 63) << 2, h = (pg >> 6) & 255, n = pg >> 14;
  int pbase = (n << 16) | (h << 8) | w0;
  float acc[4][4];
  {
    const float4 b4 = *(const float4*)&bb[c0];
#pragma unroll
    for (int px = 0; px < 4; px++) {
      acc[px][0] = b4.x; acc[px][1] = b4.y; acc[px][2] = b4.z; acc[px][3] = b4.w;
    }
  }
#pragma unroll
  for (int ky = 0; ky < 3; ky++) {
    int hh = h + ky - 1;
    if ((unsigned)hh >= 256u) continue;
    const bf16* prow = PWO + (size_t)((n << 16) | (hh << 8)) * 128 + c0;
    float v[6][4];
#pragma unroll
    for (int dx = 0; dx < 6; dx++) {
      int ww = w0 + dx - 1;
      if ((unsigned)ww < 256u) ld4(prow + (size_t)ww * 128, v[dx]);
      else { v[dx][0] = 0.f; v[dx][1] = 0.f; v[dx][2] = 0.f; v[dx][3] = 0.f; }
    }
#pragma unroll
    for (int kx = 0; kx < 3; kx++) {
      const float4 wv = *(const float4*)&wd[ky * 3 + kx][c0];
#pragma unroll
      for (int px = 0; px < 4; px++) {
        acc[px][0] += wv.x * v[px + kx][0]; acc[px][1] += wv.y * v[px + kx][1];
        acc[px][2] += wv.z * v[px + kx][2]; acc[px][3] += wv.w * v[px + kx][3];
      }
    }
  }
#pragma unroll
  for (int px = 0; px < 4; px++) {
    float vh[4];
    ld4(VH + (size_t)(pbase + px) * 128 + c0, vh);
    float o[4];
#pragma unroll
    for (int j = 0; j < 4; j++) {
      float x = acc[px][j];
      float ge = 0.5f * x * (1.f + erff(x * 0.70710678118f));
      o[j] = ge * vh[j];
    }
    st4(G + (size_t)(pbase + px) * 128 + c0, o);
  }
}

extern "C" void kernel_launch(void* const* d_in, const int* in_sizes, int n_in,
                              void* d_out, int out_size, void* d_ws, size_t ws_size,
                              hipStream_t stream) {
  (void)in_sizes; (void)n_in; (void)out_size; (void)ws_size;
  const float* xin = (const float*)d_in[0];
  auto Wp = [&](int i) { return (const float*)d_in[i]; };
  char* ws = (char*)d_ws;
  const size_t MB = 1u << 20;
  float* X  = (float*)(ws + 0 * MB);    // trunk f32 / Qb bf16
  float* A  = (float*)(ws + 32 * MB);   // residual f32; later A2b bf16, G bf16 @48
  float* T  = (float*)(ws + 64 * MB);   // LN1 f32; Sbf bf16; later VH bf16
  char*  R  = ws + 96 * MB;             // Vb bf16 @96; Tb/Sb bf16 @112; PWO bf16 @96
  char*  sm = ws + 128 * MB;
  size_t off = 0;
  auto alloc = [&](size_t bytes) {
    void* p = sm + off;
    off += (bytes + 255) & ~(size_t)255;
    return p;
  };
  float* Y8   = (float*)alloc(2 * 32 * 32 * 64 * 4);
  float* Ym   = (float*)alloc(2 * 64 * 64 * 4);
  float* QW   = (float*)alloc(2 * 64 * 64 * 4);
  float* KW   = (float*)alloc(2 * 64 * 64 * 4);
  float* KVP  = (float*)alloc(2 * 64 * 16 * 128 * 4);
  int*  RIDX  = (int*)alloc(2 * 64 * 4 * 4);
  float* Wc   = (float*)alloc(64 * 128 * 4);
  float* bc   = (float*)alloc(128 * 4);
  bf16* WTq   = (bf16*)alloc(128 * 64 * 2);
  bf16* WTo   = (bf16*)alloc(64 * 64 * 2);
  bf16* WT2   = (bf16*)alloc(64 * 128 * 2);
  bf16* WTf1  = (bf16*)alloc(256 * 64 * 2);
  float* qbs  = (float*)alloc(64 * 4);
  bf16* Vb   = (bf16*)R;                 // [P][64]
  bf16* Qb   = (bf16*)X;                 // [P][64]
  bf16* Tb   = (bf16*)(ws + 112 * MB);   // [P][64]
  bf16* Sbf  = (bf16*)T;                 // [P][64] attn out (T f32 dead by then)
  bf16* Sb   = Tb;                       // [P][64] lepe out
  bf16* PWO  = (bf16*)R;                 // [P][128]
  bf16* VH   = (bf16*)T;                 // [P][128] after attn+lepe consumed Sbf? (FC1 after wo)
  bf16* A2b  = (bf16*)A;                 // [P][64]
  bf16* G    = (bf16*)(ws + 48 * MB);    // [P][128]

  k_in_tr<<<dim3(2048), dim3(256), 0, stream>>>(xin, X);
  for (int i = 0; i < 2; i++) {
    const float *posw = Wp(1) + i * 64 * 9, *posb = Wp(2) + i * 64;
    const float *l1g = Wp(3) + i * 64, *l1b = Wp(4) + i * 64;
    const float *qkvw = Wp(5) + i * 64 * 192, *qkvb = Wp(6) + i * 192;
    const float *lpw = Wp(7) + i * 64 * 25, *lpb = Wp(8) + i * 64;
    const float *wow = Wp(9) + i * 64 * 64, *wob = Wp(10) + i * 64;
    const float *l2g = Wp(11) + i * 64, *l2b = Wp(12) + i * 64;
    const float *f1w = Wp(13) + i * 64 * 256, *f1b = Wp(14) + i * 256;
    const float *pww = Wp(15) + i * 128 * 128;
    const float *dww = Wp(16) + i * 128 * 9, *dwb = Wp(17) + i * 128;
    const float *f2w = Wp(18) + i * 128 * 64, *f2b = Wp(19) + i * 64;

    k_prep1<<<dim3(80), dim3(256), 0, stream>>>(qkvw, qkvb, wow, f2w, WTq, WTo, WT2, qbs);
    k_pcln4<<<dim3(2048), dim3(256), 0, stream>>>(X, A, T, Tb, posw, posb, l1g, l1b);
    k_mf<64, 64, 64, bf16, bf16, false><<<dim3(Pp / 128), dim3(256), 0, stream>>>(
        Tb, WTq, qbs, qkvb + 128, nullptr, Qb, Vb);
    k_pool8<<<dim3(2048), dim3(64), 0, stream>>>(T, Y8);
    k_poolwin<<<dim3(128), dim3(64), 0, stream>>>(Y8, Ym);
    k_qkwin<<<dim3(64), dim3(256), 0, stream>>>(Ym, qkvw, qkvb, QW, KW);
    k_kvp<<<dim3(1024), dim3(256), 0, stream>>>(Y8, qkvw, qkvb, KVP);
    k_route<<<dim3(128), dim3(64), 0, stream>>>(QW, KW, RIDX);
    k_attn_mf<<<dim3(512), dim3(256), 0, stream>>>(Qb, KVP, RIDX, Sbf);
    k_lepe4<<<dim3(2048), dim3(256), 0, stream>>>(Vb, Sbf, Sb, lpw, lpb);
    k_mf<64, 64, 0, float, float, true><<<dim3(Pp / 128), dim3(256), 0, stream>>>(
        Sb, WTo, wob, nullptr, A, X, nullptr);
    k_lnb4<<<dim3(Pp / 16), dim3(256), 0, stream>>>(X, A2b, l2g, l2b);
    k_combine<<<dim3(32), dim3(256), 0, stream>>>(f1w, f1b, pww, Wc, bc);
    k_prep2<<<dim3(64), dim3(256), 0, stream>>>(f1w, Wc, WTf1);
    k_mf<64, 128, 128, bf16, bf16, false><<<dim3(Pp / 128), dim3(256), 0, stream>>>(
        A2b, WTf1, f1b + 128, bc, nullptr, VH, PWO);
    k_gludw4<<<dim3(4096), dim3(256), 0, stream>>>(PWO, VH, dww, dwb, G);
    k_mf<128, 64, 0, float, float, true><<<dim3(Pp / 128), dim3(256), 0, stream>>>(
        G, WT2, f2b, nullptr, X, X, nullptr);
  }
  k_out<<<dim3(2048), dim3(256), 0, stream>>>(X, (float*)d_out);
}

// Round 9
// 448.736 us; speedup vs baseline: 6.3296x; 1.0625x over previous
//
#include <hip/hip_runtime.h>
#include <hip/hip_bf16.h>

typedef __hip_bfloat16 bf16;
typedef __attribute__((ext_vector_type(8))) short short8v;
typedef __attribute__((ext_vector_type(4))) float f32x4;

static constexpr int Nn = 2, Hh = 256, Wd = 256;
static constexpr int Pp = Nn * Hh * Wd;  // 131072 pixels

// ---- scalar/vector load-store helpers ----
__device__ inline void sto(float* p, size_t i, float v) { p[i] = v; }
__device__ inline void sto(bf16* p, size_t i, float v) { p[i] = __float2bfloat16(v); }
__device__ inline void ld4(const float* p, float f[4]) {
  const float4 v = *(const float4*)p;
  f[0] = v.x; f[1] = v.y; f[2] = v.z; f[3] = v.w;
}
__device__ inline void ld4(const bf16* p, float f[4]) {
  uint2 u = *(const uint2*)p;
  f[0] = __uint_as_float(u.x << 16); f[1] = __uint_as_float(u.x & 0xffff0000u);
  f[2] = __uint_as_float(u.y << 16); f[3] = __uint_as_float(u.y & 0xffff0000u);
}
__device__ inline void st4(float* p, const float f[4]) {
  *(float4*)p = make_float4(f[0], f[1], f[2], f[3]);
}
__device__ inline void st4(bf16* p, const float f[4]) {
  union { bf16 h[4]; uint2 u; } x;
  x.h[0] = __float2bfloat16(f[0]); x.h[1] = __float2bfloat16(f[1]);
  x.h[2] = __float2bfloat16(f[2]); x.h[3] = __float2bfloat16(f[3]);
  *(uint2*)p = x.u;
}
__device__ inline uint2 pk4(float a, float b, float c, float d) {
  union { bf16 h[4]; uint2 u; } x;
  x.h[0] = __float2bfloat16(a); x.h[1] = __float2bfloat16(b);
  x.h[2] = __float2bfloat16(c); x.h[3] = __float2bfloat16(d);
  return x.u;
}

// ---- NCHW f32 -> NHWC f32, LDS-tiled ----
__global__ void __launch_bounds__(256) k_in_tr(const float* __restrict__ xin,
                                               float* __restrict__ X) {
  __shared__ float t[64][65];
  int blk = blockIdx.x;
  int wt = blk & 3, h = (blk >> 2) & 255, n = blk >> 10;
  int w0 = wt * 64;
  int tx = threadIdx.x & 63, ty = threadIdx.x >> 6;
  const float* src = xin + ((size_t)n * 64 * 256 + h) * 256 + w0;
#pragma unroll
  for (int cc = 0; cc < 16; cc++) {
    int c = cc * 4 + ty;
    t[c][tx] = src[(size_t)c * 65536 + tx];
  }
  __syncthreads();
  float* dst = X + (size_t)(n * 65536 + h * 256 + w0) * 64;
#pragma unroll
  for (int jj = 0; jj < 16; jj++) {
    int j = jj * 4 + ty;
    dst[(size_t)j * 64 + tx] = t[tx][j];
  }
}

// ---- NHWC f32 -> NCHW f32 ----
__global__ void __launch_bounds__(256) k_out(const float* __restrict__ X,
                                             float* __restrict__ out) {
  __shared__ float t[64][65];
  int blk = blockIdx.x;
  int wt = blk & 3, h = (blk >> 2) & 255, n = blk >> 10;
  int w0 = wt * 64;
  int tx = threadIdx.x & 63, ty = threadIdx.x >> 6;
  const float* src = X + (size_t)(n * 65536 + h * 256 + w0) * 64;
#pragma unroll
  for (int jj = 0; jj < 16; jj++) {
    int j = jj * 4 + ty;
    t[tx][j] = src[(size_t)j * 64 + tx];
  }
  __syncthreads();
  float* dst = out + ((size_t)n * 64 * 256 + h) * 256 + w0;
#pragma unroll
  for (int cc = 0; cc < 16; cc++) {
    int c = cc * 4 + ty;
    dst[(size_t)c * 65536 + tx] = t[c][tx];
  }
}

// ---- fused posconv+LN1: 4 px/thread, row-reuse ----
__global__ void __launch_bounds__(256) k_pcln4(const float* __restrict__ X,
                                               float* __restrict__ A, float* __restrict__ T,
                                               bf16* __restrict__ Tb,
                                               const float* __restrict__ pw,
                                               const float* __restrict__ pb,
                                               const float* __restrict__ g,
                                               const float* __restrict__ b) {
  __shared__ float w9[9][68];
  __shared__ float bb[64];
  int tid = threadIdx.x;
  for (int j = tid; j < 576; j += 256) {
    int tap = j >> 6, c = j & 63;
    w9[tap][c] = pw[c * 9 + tap];
  }
  if (tid < 64) bb[tid] = pb[tid];
  __syncthreads();
  int gid = blockIdx.x * 256 + tid;
  int cg = gid & 15, pg = gid >> 4;
  int c0 = cg << 2;
  int w0 = (pg & 63) << 2, h = (pg >> 6) & 255, n = pg >> 14;
  int pbase = (n << 16) | (h << 8) | w0;
  float acc[4][4];
  {
    const float4 b4 = *(const float4*)&bb[c0];
#pragma unroll
    for (int px = 0; px < 4; px++) {
      acc[px][0] = b4.x; acc[px][1] = b4.y; acc[px][2] = b4.z; acc[px][3] = b4.w;
    }
  }
  float xc[4][4];
#pragma unroll
  for (int ky = 0; ky < 3; ky++) {
    int hh = h + ky - 1;
    if ((unsigned)hh >= 256u) continue;
    const float* xrow = X + (size_t)((n << 16) | (hh << 8)) * 64 + c0;
    float v[6][4];
#pragma unroll
    for (int dx = 0; dx < 6; dx++) {
      int ww = w0 + dx - 1;
      if ((unsigned)ww < 256u) ld4(xrow + (size_t)ww * 64, v[dx]);
      else { v[dx][0] = 0.f; v[dx][1] = 0.f; v[dx][2] = 0.f; v[dx][3] = 0.f; }
    }
    if (ky == 1) {
#pragma unroll
      for (int px = 0; px < 4; px++)
#pragma unroll
        for (int j = 0; j < 4; j++) xc[px][j] = v[px + 1][j];
    }
#pragma unroll
    for (int kx = 0; kx < 3; kx++) {
      const float4 wv = *(const float4*)&w9[ky * 3 + kx][c0];
#pragma unroll
      for (int px = 0; px < 4; px++) {
        acc[px][0] += wv.x * v[px + kx][0]; acc[px][1] += wv.y * v[px + kx][1];
        acc[px][2] += wv.z * v[px + kx][2]; acc[px][3] += wv.w * v[px + kx][3];
      }
    }
  }
  const float4 g4 = *(const float4*)&g[c0];
  const float4 b4 = *(const float4*)&b[c0];
#pragma unroll
  for (int px = 0; px < 4; px++) {
    float a[4];
#pragma unroll
    for (int j = 0; j < 4; j++) a[j] = xc[px][j] + acc[px][j];
    st4(A + (size_t)(pbase + px) * 64 + c0, a);
    float s = a[0] + a[1] + a[2] + a[3];
#pragma unroll
    for (int off = 8; off; off >>= 1) s += __shfl_xor(s, off);
    float mean = s * (1.f / 64.f);
    float d[4], q = 0.f;
#pragma unroll
    for (int j = 0; j < 4; j++) { d[j] = a[j] - mean; q += d[j] * d[j]; }
#pragma unroll
    for (int off = 8; off; off >>= 1) q += __shfl_xor(q, off);
    float inv = rsqrtf(q * (1.f / 64.f) + 1e-6f);
    float y[4] = {d[0] * inv * g4.x + b4.x, d[1] * inv * g4.y + b4.y,
                  d[2] * inv * g4.z + b4.z, d[3] * inv * g4.w + b4.w};
    st4(T + (size_t)(pbase + px) * 64 + c0, y);
    st4(Tb + (size_t)(pbase + px) * 64 + c0, y);
  }
}

// ---- merged weight prep: prep1 + (combine->WTf1 fused) + prep2 ----
__global__ void k_prep(const float* __restrict__ qkvw, const float* __restrict__ qkvb,
                       const float* __restrict__ wow, const float* __restrict__ f2w,
                       const float* __restrict__ f1w, const float* __restrict__ f1b,
                       const float* __restrict__ pww,
                       bf16* __restrict__ WTq, bf16* __restrict__ WTo,
                       bf16* __restrict__ WT2, bf16* __restrict__ WTf1,
                       float* __restrict__ qbs, float* __restrict__ bc) {
  int t = blockIdx.x * 256 + threadIdx.x;
  if (t < 8192) {
    int r = t >> 6, k = t & 63;
    int src = r < 64 ? r : r + 64;  // Q cols 0..63, V cols 128..191
    float v = qkvw[k * 192 + src];
    if (r < 64) v *= 0.125f;        // fold qk scale (exact 2^-3)
    WTq[t] = __float2bfloat16(v);
  } else if (t < 12288) {
    int t2 = t - 8192;
    int r = t2 >> 6, k = t2 & 63;
    WTo[t2] = __float2bfloat16(wow[k * 64 + r]);
  } else if (t < 20480) {
    int t2 = t - 12288;
    int r = t2 >> 7, k = t2 & 127;
    WT2[t2] = __float2bfloat16(f2w[k * 64 + r]);
  } else if (t < 28672) {
    int t2 = t - 20480;                    // WTf1 rows 0..127 = W1b^T
    int r = t2 >> 6, k = t2 & 63;
    WTf1[t2] = __float2bfloat16(f1w[k * 256 + 128 + r]);
  } else if (t < 36864) {                  // WTf1 rows 128..255 = (W1a@pw^T)^T
    int t2 = t - 28672;
    int o = t2 & 127, k = t2 >> 7;
    float acc = 0.f;
    for (int j = 0; j < 128; j++) acc += f1w[k * 256 + j] * pww[o * 128 + j];
    WTf1[(128 + o) * 64 + k] = __float2bfloat16(acc);
  } else if (t < 36992) {                  // bc = b1a @ pw^T
    int o = t - 36864;
    float bv = 0.f;
    for (int j = 0; j < 128; j++) bv += f1b[j] * pww[o * 128 + j];
    bc[o] = bv;
  }
  if (t < 64) qbs[t] = qkvb[t] * 0.125f;
}

// ---- unified MFMA GEMM ----
template <int K, int N1, int N2, typename TO1, typename TO2, bool RES>
__global__ void __launch_bounds__(256) k_mf(const bf16* __restrict__ In,
                                            const bf16* __restrict__ WT,
                                            const float* __restrict__ b1,
                                            const float* __restrict__ b2,
                                            const float* __restrict__ Res,
                                            TO1* __restrict__ O1, TO2* __restrict__ O2) {
  constexpr int NC = N1 + N2;
  constexpr int KS = K / 32;
  constexpr int NTW = NC / 64;
  constexpr int KB = K * 2;
  constexpr int CH = NC * K / 8;
  __shared__ char lw[NC * K * 2];
  int tid = threadIdx.x;
  for (int ch = tid; ch < CH; ch += 256) {
    int r = ch / (K / 8), cg = ch % (K / 8);
    int byte = (r * KB + cg * 16) ^ ((r & 7) << 4);
    *(uint4*)(lw + byte) = *(const uint4*)((const short*)WT + ch * 8);
  }
  __syncthreads();
  int wid = tid >> 6, lane = tid & 63;
  int lr = lane & 15, lg = lane >> 4;
  int mb = blockIdx.x * 128;
#pragma unroll 2
  for (int ms = 0; ms < 8; ms++) {
    int m0 = mb + ms * 16;
    short8v a[KS];
#pragma unroll
    for (int ks = 0; ks < KS; ks++)
      a[ks] = *(const short8v*)((const short*)In + (size_t)(m0 + lr) * K + ks * 32 + lg * 8);
#pragma unroll
    for (int t = 0; t < NTW; t++) {
      int nt = wid * NTW + t;
      int col = nt * 16 + lr;
      float bv = (N2 == 0 || col < N1) ? b1[col] : b2[col - N1];
      f32x4 acc = {bv, bv, bv, bv};
#pragma unroll
      for (int ks = 0; ks < KS; ks++) {
        int byte = (col * KB + ks * 64 + lg * 16) ^ ((col & 7) << 4);
        short8v bfrag = *(const short8v*)(lw + byte);
        acc = __builtin_amdgcn_mfma_f32_16x16x32_bf16(a[ks], bfrag, acc, 0, 0, 0);
      }
      int r0 = m0 + lg * 4;
#pragma unroll
      for (int j = 0; j < 4; j++) {
        float v = acc[j];
        size_t row = r0 + j;
        if (RES) v += Res[row * N1 + col];
        if (N2 == 0 || col < N1) sto(O1, row * N1 + col, v);
        else sto(O2, row * N2 + (col - N1), v);
      }
    }
  }
}

// ---- wo GEMM fused with LN2: X = Sb@wo + wob + Res;  A2b = bf16(LN2(X)) ----
__global__ void __launch_bounds__(256) k_mf_wo_ln(const bf16* __restrict__ In,
                                                  const bf16* __restrict__ WT,
                                                  const float* __restrict__ bias,
                                                  const float* __restrict__ Res,
                                                  float* __restrict__ Xo,
                                                  bf16* __restrict__ A2b,
                                                  const float* __restrict__ g,
                                                  const float* __restrict__ b) {
  __shared__ char lw[64 * 64 * 2];
  __shared__ float xs[16][68];
  int tid = threadIdx.x;
  for (int ch = tid; ch < 512; ch += 256) {
    int r = ch >> 3, cg = ch & 7;
    int byte = (r * 128 + cg * 16) ^ ((r & 7) << 4);
    *(uint4*)(lw + byte) = *(const uint4*)((const short*)WT + ch * 8);
  }
  __syncthreads();
  int wid = tid >> 6, lane = tid & 63;
  int lr = lane & 15, lg = lane >> 4;
  int col = wid * 16 + lr;
  int mb = blockIdx.x * 128;
  int row2 = tid >> 4, cq = (tid & 15) << 2;  // LN-phase mapping
  const float4 g4 = *(const float4*)&g[cq];
  const float4 b4 = *(const float4*)&b[cq];
  float bv = bias[col];
  for (int ms = 0; ms < 8; ms++) {
    int m0 = mb + ms * 16;
    short8v a0 = *(const short8v*)((const short*)In + (size_t)(m0 + lr) * 64 + lg * 8);
    short8v a1 = *(const short8v*)((const short*)In + (size_t)(m0 + lr) * 64 + 32 + lg * 8);
    f32x4 acc = {bv, bv, bv, bv};
    {
      int byte = (col * 128 + lg * 16) ^ ((col & 7) << 4);
      acc = __builtin_amdgcn_mfma_f32_16x16x32_bf16(a0, *(const short8v*)(lw + byte), acc, 0, 0, 0);
      byte = (col * 128 + 64 + lg * 16) ^ ((col & 7) << 4);
      acc = __builtin_amdgcn_mfma_f32_16x16x32_bf16(a1, *(const short8v*)(lw + byte), acc, 0, 0, 0);
    }
    int r0 = m0 + lg * 4;
#pragma unroll
    for (int j = 0; j < 4; j++) {
      float v = acc[j] + Res[(size_t)(r0 + j) * 64 + col];
      Xo[(size_t)(r0 + j) * 64 + col] = v;
      xs[lg * 4 + j][col] = v;
    }
    __syncthreads();
    {
      float a4[4] = {xs[row2][cq], xs[row2][cq + 1], xs[row2][cq + 2], xs[row2][cq + 3]};
      float s = a4[0] + a4[1] + a4[2] + a4[3];
#pragma unroll
      for (int off = 8; off; off >>= 1) s += __shfl_xor(s, off);
      float mean = s * (1.f / 64.f);
      float d[4], q = 0.f;
#pragma unroll
      for (int j = 0; j < 4; j++) { d[j] = a4[j] - mean; q += d[j] * d[j]; }
#pragma unroll
      for (int off = 8; off; off >>= 1) q += __shfl_xor(q, off);
      float inv = rsqrtf(q * (1.f / 64.f) + 1e-6f);
      float y[4] = {d[0] * inv * g4.x + b4.x, d[1] * inv * g4.y + b4.y,
                    d[2] * inv * g4.z + b4.z, d[3] * inv * g4.w + b4.w};
      st4(A2b + (size_t)(m0 + row2) * 64 + cq, y);
    }
    __syncthreads();
  }
}

// ---- 8x8 block means of LN1 (f32, exact routing path) ----
__global__ void k_pool8(const float* __restrict__ T, float* __restrict__ Y8) {
  int b = blockIdx.x;
  int c = threadIdx.x;
  int bx = b & 31, by = (b >> 5) & 31, n = b >> 10;
  float acc = 0.f;
  for (int r = 0; r < 8; r++)
    for (int s = 0; s < 8; s++) {
      int p = (n << 16) | ((by * 8 + r) << 8) | (bx * 8 + s);
      acc += T[(size_t)p * 64 + c];
    }
  Y8[(size_t)b * 64 + c] = acc * (1.f / 64.f);
}

// ---- fused window-mean + q/k projection (was poolwin + qkwin) ----
__global__ void __launch_bounds__(256) k_qkwin2(const float* __restrict__ Y8,
                                                const float* __restrict__ qw,
                                                const float* __restrict__ qb,
                                                float* __restrict__ QW,
                                                float* __restrict__ KW) {
  __shared__ float ym[4][68];
  int blk = blockIdx.x;       // 64: blk<32 -> sel 0 rows blk*4.., else sel 1
  int sel = blk >> 5;
  int r0 = (blk & 31) * 4;
  int tid = threadIdx.x;
  {
    int rl = tid >> 6, c = tid & 63;
    int row = r0 + rl;
    int n = row >> 6, win = row & 63;
    int wi = win >> 3, wj = win & 7;
    float acc = 0.f;
    for (int ti = 0; ti < 4; ti++)
      for (int tj = 0; tj < 4; tj++) {
        int y8 = (n * 32 + wi * 4 + ti) * 32 + wj * 4 + tj;
        acc += Y8[(size_t)y8 * 64 + c];
      }
    ym[rl][c] = acc * (1.f / 16.f);
  }
  __syncthreads();
  int rl = tid >> 6, c = tid & 63;
  int row = r0 + rl;
  int colg = sel * 64 + c;
  float acc = qb[colg];
  for (int k = 0; k < 64; k++) acc += ym[rl][k] * qw[k * 192 + colg];
  (sel ? KW : QW)[(size_t)row * 64 + c] = acc;
}

__global__ void k_kvp(const float* __restrict__ Y8, const float* __restrict__ qw,
                      const float* __restrict__ qb, float* __restrict__ KVP) {
  int t = blockIdx.x * blockDim.x + threadIdx.x;
  if (t >= 262144) return;
  int c2 = t & 127, tok = (t >> 7) & 15, win = (t >> 11) & 63, n = t >> 17;
  int wi = win >> 3, wj = win & 7, ti = tok >> 2, tj = tok & 3;
  int y8 = (n * 32 + wi * 4 + ti) * 32 + wj * 4 + tj;
  const float* y = Y8 + (size_t)y8 * 64;
  int col = 64 + c2;
  float acc = qb[col];
  for (int k = 0; k < 64; k++) acc += y[k] * qw[k * 192 + col];
  KVP[t] = acc;
}

// ---- routing: top-4, one block per query window, lane = candidate ----
__global__ void __launch_bounds__(64) k_route(const float* __restrict__ QW,
                                              const float* __restrict__ KW,
                                              int* __restrict__ RIDX) {
  __shared__ float kk[64][65];
  __shared__ float qq[64];
  int b = blockIdx.x;
  int lane = threadIdx.x;
  int n = b >> 6;
  qq[lane] = QW[(size_t)b * 64 + lane];
  for (int r = 0; r < 64; r++) kk[r][lane] = KW[(size_t)(n * 64 + r) * 64 + lane];
  __syncthreads();
  float t = 0.f;
  for (int c = 0; c < 64; c++) t += qq[c] * kk[lane][c];
  t *= 0.125f;
  int o0 = 0, o1 = 0, o2 = 0, o3 = 0;
#pragma unroll
  for (int j = 0; j < 4; j++) {
    float v = t; int idx = lane;
#pragma unroll
    for (int off = 32; off; off >>= 1) {
      float ov = __shfl_xor(v, off);
      int oi = __shfl_xor(idx, off);
      if (ov > v || (ov == v && oi < idx)) { v = ov; idx = oi; }
    }
    if (j == 0) o0 = idx; else if (j == 1) o1 = idx;
    else if (j == 2) o2 = idx; else o3 = idx;
    if (lane == idx) t = -1e30f;
  }
  if (lane == 0) {
    int* o = RIDX + (size_t)b * 4;
    o[0] = o0; o[1] = o1; o[2] = o2; o[3] = o3;
  }
}

// ---- MFMA attention -> bf16 output ----
__global__ void __launch_bounds__(256) k_attn_mf(const bf16* __restrict__ Qb,
                                                 const float* __restrict__ KVP,
                                                 const int* __restrict__ RIDX,
                                                 bf16* __restrict__ Sbf) {
  __shared__ bf16 ks[64][72];
  __shared__ bf16 vt[64][72];
  __shared__ bf16 pa[4][16][72];
  __shared__ float ldn[4][16];
  __shared__ int idx[4];
  int blk = blockIdx.x;
  int part = blk & 3, bw = blk >> 2;
  int n = bw >> 6, win = bw & 63;
  int tid = threadIdx.x;
  if (tid < 4) idx[tid] = RIDX[bw * 4 + tid];
  __syncthreads();
  {
    int tok = tid & 63;
    const float* src = KVP + ((size_t)(n * 64 + idx[tok >> 4]) * 16 + (tok & 15)) * 128;
    for (int cq = tid >> 6; cq < 16; cq += 4) {
      int c0 = cq * 4;
      const float4 k4 = *(const float4*)&src[c0];
      *(uint2*)&ks[tok][c0] = pk4(k4.x, k4.y, k4.z, k4.w);
      const float4 v4 = *(const float4*)&src[64 + c0];
      vt[c0 + 0][tok] = __float2bfloat16(v4.x);
      vt[c0 + 1][tok] = __float2bfloat16(v4.y);
      vt[c0 + 2][tok] = __float2bfloat16(v4.z);
      vt[c0 + 3][tok] = __float2bfloat16(v4.w);
    }
  }
  __syncthreads();
  int w = tid >> 6, lane = tid & 63;
  int lr = lane & 15, lg = lane >> 4;
  int wi = win >> 3, wj = win & 7;
  for (int it = 0; it < 4; it++) {
    int qbase = part * 256 + w * 64 + it * 16;
    int q_b = qbase + lr;
    int pix_b = (n << 16) | ((wi * 32 + (q_b >> 5)) << 8) | (wj * 32 + (q_b & 31));
    short8v qf0 = *(const short8v*)((const short*)Qb + (size_t)pix_b * 64 + lg * 8);
    short8v qf1 = *(const short8v*)((const short*)Qb + (size_t)pix_b * 64 + 32 + lg * 8);
    f32x4 p[4] = {{0,0,0,0},{0,0,0,0},{0,0,0,0},{0,0,0,0}};
#pragma unroll
    for (int mt = 0; mt < 4; mt++) {
      short8v a0 = *(const short8v*)&ks[mt * 16 + lr][lg * 8];
      p[mt] = __builtin_amdgcn_mfma_f32_16x16x32_bf16(a0, qf0, p[mt], 0, 0, 0);
    }
#pragma unroll
    for (int mt = 0; mt < 4; mt++) {
      short8v a1 = *(const short8v*)&ks[mt * 16 + lr][32 + lg * 8];
      p[mt] = __builtin_amdgcn_mfma_f32_16x16x32_bf16(a1, qf1, p[mt], 0, 0, 0);
    }
    float mx = -1e30f;
#pragma unroll
    for (int mt = 0; mt < 4; mt++)
#pragma unroll
      for (int j = 0; j < 4; j++) mx = fmaxf(mx, p[mt][j]);
    mx = fmaxf(mx, __shfl_xor(mx, 16));
    mx = fmaxf(mx, __shfl_xor(mx, 32));
    float e[4][4];
    float sum = 0.f;
#pragma unroll
    for (int mt = 0; mt < 4; mt++)
#pragma unroll
      for (int j = 0; j < 4; j++) { e[mt][j] = __expf(p[mt][j] - mx); sum += e[mt][j]; }
    sum += __shfl_xor(sum, 16);
    sum += __shfl_xor(sum, 32);
    if (lg == 0) ldn[w][lr] = sum;
#pragma unroll
    for (int mt = 0; mt < 4; mt++)
      *(uint2*)&pa[w][lr][mt * 16 + lg * 4] = pk4(e[mt][0], e[mt][1], e[mt][2], e[mt][3]);
    short8v pf0 = *(const short8v*)&pa[w][lr][lg * 8];
    short8v pf1 = *(const short8v*)&pa[w][lr][32 + lg * 8];
    f32x4 o4[4] = {{0,0,0,0},{0,0,0,0},{0,0,0,0},{0,0,0,0}};
#pragma unroll
    for (int nt = 0; nt < 4; nt++) {
      short8v v0 = *(const short8v*)&vt[nt * 16 + lr][lg * 8];
      o4[nt] = __builtin_amdgcn_mfma_f32_16x16x32_bf16(pf0, v0, o4[nt], 0, 0, 0);
    }
#pragma unroll
    for (int nt = 0; nt < 4; nt++) {
      short8v v1 = *(const short8v*)&vt[nt * 16 + lr][32 + lg * 8];
      o4[nt] = __builtin_amdgcn_mfma_f32_16x16x32_bf16(pf1, v1, o4[nt], 0, 0, 0);
    }
    float linv[4];
#pragma unroll
    for (int j = 0; j < 4; j++) linv[j] = 1.f / ldn[w][lg * 4 + j];
#pragma unroll
    for (int j = 0; j < 4; j++) {
      int q_o = qbase + lg * 4 + j;
      size_t pix_o = (n << 16) | ((wi * 32 + (q_o >> 5)) << 8) | (wj * 32 + (q_o & 31));
      bf16* op = Sbf + pix_o * 64 + lr;
#pragma unroll
      for (int nt = 0; nt < 4; nt++) op[nt * 16] = __float2bfloat16(o4[nt][j] * linv[j]);
    }
  }
}

// ---- LePE: 4 px/thread, row-reuse; Sb = bf16(Sbf + dw5x5(V)) ----
__global__ void __launch_bounds__(256) k_lepe4(const bf16* __restrict__ V,
                                               const bf16* __restrict__ Sbf,
                                               bf16* __restrict__ Sb,
                                               const float* __restrict__ wt,
                                               const float* __restrict__ bs) {
  __shared__ float w5[25][68];
  __shared__ float bb[64];
  int tid = threadIdx.x;
  for (int j = tid; j < 1600; j += 256) {
    int tap = j >> 6, c = j & 63;
    w5[tap][c] = wt[c * 25 + tap];
  }
  if (tid < 64) bb[tid] = bs[tid];
  __syncthreads();
  int gid = blockIdx.x * 256 + tid;
  int cg = gid & 15, pg = gid >> 4;
  int c0 = cg << 2;
  int w0 = (pg & 63) << 2, h = (pg >> 6) & 255, n = pg >> 14;
  int pbase = (n << 16) | (h << 8) | w0;
  float acc[4][4];
  {
    const float4 b4 = *(const float4*)&bb[c0];
#pragma unroll
    for (int px = 0; px < 4; px++) {
      acc[px][0] = b4.x; acc[px][1] = b4.y; acc[px][2] = b4.z; acc[px][3] = b4.w;
    }
  }
#pragma unroll
  for (int ky = 0; ky < 5; ky++) {
    int hh = h + ky - 2;
    if ((unsigned)hh >= 256u) continue;
    const bf16* vrow = V + (size_t)((n << 16) | (hh << 8)) * 64 + c0;
    float v[8][4];
#pragma unroll
    for (int dx = 0; dx < 8; dx++) {
      int ww = w0 + dx - 2;
      if ((unsigned)ww < 256u) ld4(vrow + (size_t)ww * 64, v[dx]);
      else { v[dx][0] = 0.f; v[dx][1] = 0.f; v[dx][2] = 0.f; v[dx][3] = 0.f; }
    }
#pragma unroll
    for (int kx = 0; kx < 5; kx++) {
      const float4 wv = *(const float4*)&w5[ky * 5 + kx][c0];
#pragma unroll
      for (int px = 0; px < 4; px++) {
        acc[px][0] += wv.x * v[px + kx][0]; acc[px][1] += wv.y * v[px + kx][1];
        acc[px][2] += wv.z * v[px + kx][2]; acc[px][3] += wv.w * v[px + kx][3];
      }
    }
  }
#pragma unroll
  for (int px = 0; px < 4; px++) {
    float s4[4];
    ld4(Sbf + (size_t)(pbase + px) * 64 + c0, s4);
    float o[4] = {s4[0] + acc[px][0], s4[1] + acc[px][1],
                  s4[2] + acc[px][2], s4[3] + acc[px][3]};
    st4(Sb + (size_t)(pbase + px) * 64 + c0, o);
  }
}

// ---- GLU tail: 4 px/thread; G = gelu(dw3(PWO)+dwb) * VH ----
__global__ void __launch_bounds__(256) k_gludw4(const bf16* __restrict__ PWO,
                                                const bf16* __restrict__ VH,
                                                const float* __restrict__ wt,
                                                const float* __restrict__ bs,
                                                bf16* __restrict__ G) {
  __shared__ float wd[9][132];
  __shared__ float bb[128];
  int tid = threadIdx.x;
  for (int j = tid; j < 1152; j += 256) {
    int tap = j >> 7, c = j & 127;
    wd[tap][c] = wt[c * 9 + tap];
  }
  if (tid < 128) bb[tid] = bs[tid];
  __syncthreads();
  int gid = blockIdx.x * 256 + tid;
  int cg = gid & 31, pg = gid >> 5;
  int c0 = cg << 2;
  int w0 = (pg & 63) << 2, h = (pg >> 6) & 255, n = pg >> 14;
  int pbase = (n << 16) | (h << 8) | w0;
  float acc[4][4];
  {
    const float4 b4 = *(const float4*)&bb[c0];
#pragma unroll
    for (int px = 0; px < 4; px++) {
      acc[px][0] = b4.x; acc[px][1] = b4.y; acc[px][2] = b4.z; acc[px][3] = b4.w;
    }
  }
#pragma unroll
  for (int ky = 0; ky < 3; ky++) {
    int hh = h + ky - 1;
    if ((unsigned)hh >= 256u) continue;
    const bf16* prow = PWO + (size_t)((n << 16) | (hh << 8)) * 128 + c0;
    float v[6][4];
#pragma unroll
    for (int dx = 0; dx < 6; dx++) {
      int ww = w0 + dx - 1;
      if ((unsigned)ww < 256u) ld4(prow + (size_t)ww * 128, v[dx]);
      else { v[dx][0] = 0.f; v[dx][1] = 0.f; v[dx][2] = 0.f; v[dx][3] = 0.f; }
    }
#pragma unroll
    for (int kx = 0; kx < 3; kx++) {
      const float4 wv = *(const float4*)&wd[ky * 3 + kx][c0];
#pragma unroll
      for (int px = 0; px < 4; px++) {
        acc[px][0] += wv.x * v[px + kx][0]; acc[px][1] += wv.y * v[px + kx][1];
        acc[px][2] += wv.z * v[px + kx][2]; acc[px][3] += wv.w * v[px + kx][3];
      }
    }
  }
#pragma unroll
  for (int px = 0; px < 4; px++) {
    float vh[4];
    ld4(VH + (size_t)(pbase + px) * 128 + c0, vh);
    float o[4];
#pragma unroll
    for (int j = 0; j < 4; j++) {
      float x = acc[px][j];
      float ge = 0.5f * x * (1.f + erff(x * 0.70710678118f));
      o[j] = ge * vh[j];
    }
    st4(G + (size_t)(pbase + px) * 128 + c0, o);
  }
}

extern "C" void kernel_launch(void* const* d_in, const int* in_sizes, int n_in,
                              void* d_out, int out_size, void* d_ws, size_t ws_size,
                              hipStream_t stream) {
  (void)in_sizes; (void)n_in; (void)out_size; (void)ws_size;
  const float* xin = (const float*)d_in[0];
  auto Wp = [&](int i) { return (const float*)d_in[i]; };
  char* ws = (char*)d_ws;
  const size_t MB = 1u << 20;
  // lifetime-checked layout (fixes round7/8 G/VH overlap race):
  // 0..32   : X trunk f32  | Qb bf16 (after pcln)
  // 32..64  : A res f32    | VH bf16 (after wo)
  // 64..96  : T LN1 f32    | Sbf bf16 (attn out) | PWO bf16 (after lepe)
  // 96..112 : Vb bf16      | A2b bf16 (after lepe) | G low half (after FC1)
  // 112..128: Tb bf16 / Sb bf16 | G high half (after wo)
  // 128+    : smalls
  float* X  = (float*)(ws + 0 * MB);
  float* A  = (float*)(ws + 32 * MB);
  float* T  = (float*)(ws + 64 * MB);
  char*  sm = ws + 128 * MB;
  size_t off = 0;
  auto alloc = [&](size_t bytes) {
    void* p = sm + off;
    off += (bytes + 255) & ~(size_t)255;
    return p;
  };
  float* Y8   = (float*)alloc(2 * 32 * 32 * 64 * 4);
  float* QW   = (float*)alloc(2 * 64 * 64 * 4);
  float* KW   = (float*)alloc(2 * 64 * 64 * 4);
  float* KVP  = (float*)alloc(2 * 64 * 16 * 128 * 4);
  int*  RIDX  = (int*)alloc(2 * 64 * 4 * 4);
  float* bc   = (float*)alloc(128 * 4);
  bf16* WTq   = (bf16*)alloc(128 * 64 * 2);
  bf16* WTo   = (bf16*)alloc(64 * 64 * 2);
  bf16* WT2   = (bf16*)alloc(64 * 128 * 2);
  bf16* WTf1  = (bf16*)alloc(256 * 64 * 2);
  float* qbs  = (float*)alloc(64 * 4);
  bf16* Qb   = (bf16*)X;                 // [P][64]
  bf16* Vb   = (bf16*)(ws + 96 * MB);    // [P][64]
  bf16* Tb   = (bf16*)(ws + 112 * MB);   // [P][64]
  bf16* Sbf  = (bf16*)T;                 // [P][64]
  bf16* Sb   = Tb;                       // [P][64]
  bf16* A2b  = (bf16*)(ws + 96 * MB);    // [P][64] (Vb dead)
  bf16* VH   = (bf16*)A;                 // [P][128] (A dead after wo)
  bf16* PWO  = (bf16*)T;                 // [P][128] (T/Sbf dead)
  bf16* G    = (bf16*)(ws + 96 * MB);    // [P][128] (A2b+Sb dead)

  k_in_tr<<<dim3(2048), dim3(256), 0, stream>>>(xin, X);
  for (int i = 0; i < 2; i++) {
    const float *posw = Wp(1) + i * 64 * 9, *posb = Wp(2) + i * 64;
    const float *l1g = Wp(3) + i * 64, *l1b = Wp(4) + i * 64;
    const float *qkvw = Wp(5) + i * 64 * 192, *qkvb = Wp(6) + i * 192;
    const float *lpw = Wp(7) + i * 64 * 25, *lpb = Wp(8) + i * 64;
    const float *wow = Wp(9) + i * 64 * 64, *wob = Wp(10) + i * 64;
    const float *l2g = Wp(11) + i * 64, *l2b = Wp(12) + i * 64;
    const float *f1w = Wp(13) + i * 64 * 256, *f1b = Wp(14) + i * 256;
    const float *pww = Wp(15) + i * 128 * 128;
    const float *dww = Wp(16) + i * 128 * 9, *dwb = Wp(17) + i * 128;
    const float *f2w = Wp(18) + i * 128 * 64, *f2b = Wp(19) + i * 64;

    k_prep<<<dim3(145), dim3(256), 0, stream>>>(qkvw, qkvb, wow, f2w, f1w, f1b, pww,
                                                WTq, WTo, WT2, WTf1, qbs, bc);
    k_pcln4<<<dim3(2048), dim3(256), 0, stream>>>(X, A, T, Tb, posw, posb, l1g, l1b);
    k_mf<64, 64, 64, bf16, bf16, false><<<dim3(Pp / 128), dim3(256), 0, stream>>>(
        Tb, WTq, qbs, qkvb + 128, nullptr, Qb, Vb);
    k_pool8<<<dim3(2048), dim3(64), 0, stream>>>(T, Y8);
    k_qkwin2<<<dim3(64), dim3(256), 0, stream>>>(Y8, qkvw, qkvb, QW, KW);
    k_kvp<<<dim3(1024), dim3(256), 0, stream>>>(Y8, qkvw, qkvb, KVP);
    k_route<<<dim3(128), dim3(64), 0, stream>>>(QW, KW, RIDX);
    k_attn_mf<<<dim3(512), dim3(256), 0, stream>>>(Qb, KVP, RIDX, Sbf);
    k_lepe4<<<dim3(2048), dim3(256), 0, stream>>>(Vb, Sbf, Sb, lpw, lpb);
    k_mf_wo_ln<<<dim3(Pp / 128), dim3(256), 0, stream>>>(
        Sb, WTo, wob, A, X, A2b, l2g, l2b);
    k_mf<64, 128, 128, bf16, bf16, false><<<dim3(Pp / 128), dim3(256), 0, stream>>>(
        A2b, WTf1, f1b + 128, bc, nullptr, VH, PWO);
    k_gludw4<<<dim3(4096), dim3(256), 0, stream>>>(PWO, VH, dww, dwb, G);
    k_mf<128, 64, 0, float, float, true><<<dim3(Pp / 128), dim3(256), 0, stream>>>(
        G, WT2, f2b, nullptr, X, X, nullptr);
  }
  k_out<<<dim3(2048), dim3(256), 0, stream>>>(X, (float*)d_out);
}

// Round 11
// 441.400 us; speedup vs baseline: 6.4348x; 1.0166x over previous
//
#include <hip/hip_runtime.h>
#include <hip/hip_bf16.h>

typedef __hip_bfloat16 bf16;
typedef __attribute__((ext_vector_type(8))) short short8v;
typedef __attribute__((ext_vector_type(4))) float f32x4;

static constexpr int Nn = 2, Hh = 256, Wd = 256;
static constexpr int Pp = Nn * Hh * Wd;  // 131072 pixels

__device__ inline void ld4(const float* p, float f[4]) {
  const float4 v = *(const float4*)p;
  f[0] = v.x; f[1] = v.y; f[2] = v.z; f[3] = v.w;
}
__device__ inline void ld4(const bf16* p, float f[4]) {
  uint2 u = *(const uint2*)p;
  f[0] = __uint_as_float(u.x << 16); f[1] = __uint_as_float(u.x & 0xffff0000u);
  f[2] = __uint_as_float(u.y << 16); f[3] = __uint_as_float(u.y & 0xffff0000u);
}
__device__ inline void st4(float* p, const float f[4]) {
  *(float4*)p = make_float4(f[0], f[1], f[2], f[3]);
}
__device__ inline void st4(bf16* p, const float f[4]) {
  union { bf16 h[4]; uint2 u; } x;
  x.h[0] = __float2bfloat16(f[0]); x.h[1] = __float2bfloat16(f[1]);
  x.h[2] = __float2bfloat16(f[2]); x.h[3] = __float2bfloat16(f[3]);
  *(uint2*)p = x.u;
}
__device__ inline uint2 pk4(float a, float b, float c, float d) {
  union { bf16 h[4]; uint2 u; } x;
  x.h[0] = __float2bfloat16(a); x.h[1] = __float2bfloat16(b);
  x.h[2] = __float2bfloat16(c); x.h[3] = __float2bfloat16(d);
  return x.u;
}

// ---- NCHW f32 -> NHWC f32, LDS-tiled ----
__global__ void __launch_bounds__(256) k_in_tr(const float* __restrict__ xin,
                                               float* __restrict__ X) {
  __shared__ float t[64][65];
  int blk = blockIdx.x;
  int wt = blk & 3, h = (blk >> 2) & 255, n = blk >> 10;
  int w0 = wt * 64;
  int tx = threadIdx.x & 63, ty = threadIdx.x >> 6;
  const float* src = xin + ((size_t)n * 64 * 256 + h) * 256 + w0;
#pragma unroll
  for (int cc = 0; cc < 16; cc++) {
    int c = cc * 4 + ty;
    t[c][tx] = src[(size_t)c * 65536 + tx];
  }
  __syncthreads();
  float* dst = X + (size_t)(n * 65536 + h * 256 + w0) * 64;
#pragma unroll
  for (int jj = 0; jj < 16; jj++) {
    int j = jj * 4 + ty;
    dst[(size_t)j * 64 + tx] = t[tx][j];
  }
}

// ---- NHWC f32 -> NCHW f32 ----
__global__ void __launch_bounds__(256) k_out(const float* __restrict__ X,
                                             float* __restrict__ out) {
  __shared__ float t[64][65];
  int blk = blockIdx.x;
  int wt = blk & 3, h = (blk >> 2) & 255, n = blk >> 10;
  int w0 = wt * 64;
  int tx = threadIdx.x & 63, ty = threadIdx.x >> 6;
  const float* src = X + (size_t)(n * 65536 + h * 256 + w0) * 64;
#pragma unroll
  for (int jj = 0; jj < 16; jj++) {
    int j = jj * 4 + ty;
    t[tx][j] = src[(size_t)j * 64 + tx];
  }
  __syncthreads();
  float* dst = out + ((size_t)n * 64 * 256 + h) * 256 + w0;
#pragma unroll
  for (int cc = 0; cc < 16; cc++) {
    int c = cc * 4 + ty;
    dst[(size_t)c * 65536 + tx] = t[c][tx];
  }
}

// ---- fused posconv + LN1 + QKV MFMA GEMM ----
// Block: 64 consecutive w-pixels of one row. Writes A,T (f32), Qb,Vb (bf16).
__global__ void __launch_bounds__(256) k_pcln_qkv(const float* __restrict__ X,
                                                  float* __restrict__ A,
                                                  float* __restrict__ T,
                                                  const float* __restrict__ pw,
                                                  const float* __restrict__ pb,
                                                  const float* __restrict__ g,
                                                  const float* __restrict__ b,
                                                  const bf16* __restrict__ WTq,
                                                  const float* __restrict__ qbs,
                                                  const float* __restrict__ vbias,
                                                  bf16* __restrict__ Qb,
                                                  bf16* __restrict__ Vb) {
  __shared__ float w9[9][68];
  __shared__ float bb[64];
  __shared__ bf16 yt[64][72];
  __shared__ char lw[128 * 64 * 2];
  int tid = threadIdx.x;
  for (int j = tid; j < 576; j += 256) {
    int tap = j >> 6, c = j & 63;
    w9[tap][c] = pw[c * 9 + tap];
  }
  if (tid < 64) bb[tid] = pb[tid];
  for (int ch = tid; ch < 1024; ch += 256) {
    int r = ch >> 3, cg = ch & 7;
    int byte = (r * 128 + cg * 16) ^ ((r & 7) << 4);
    *(uint4*)(lw + byte) = *(const uint4*)((const short*)WTq + ch * 8);
  }
  __syncthreads();
  int blk = blockIdx.x;
  int gid = blk * 256 + tid;
  int cg = gid & 15, pg = gid >> 4;
  int c0 = cg << 2;
  int w0 = (pg & 63) << 2, h = (pg >> 6) & 255, n = pg >> 14;
  int pbase = (n << 16) | (h << 8) | w0;
  int pl0 = (tid >> 4) << 2;  // local pixel base (0..60)
  float acc[4][4];
  {
    const float4 b4 = *(const float4*)&bb[c0];
#pragma unroll
    for (int px = 0; px < 4; px++) {
      acc[px][0] = b4.x; acc[px][1] = b4.y; acc[px][2] = b4.z; acc[px][3] = b4.w;
    }
  }
  float xc[4][4];
#pragma unroll
  for (int ky = 0; ky < 3; ky++) {
    int hh = h + ky - 1;
    if ((unsigned)hh >= 256u) continue;
    const float* xrow = X + (size_t)((n << 16) | (hh << 8)) * 64 + c0;
    float v[6][4];
#pragma unroll
    for (int dx = 0; dx < 6; dx++) {
      int ww = w0 + dx - 1;
      if ((unsigned)ww < 256u) ld4(xrow + (size_t)ww * 64, v[dx]);
      else { v[dx][0] = 0.f; v[dx][1] = 0.f; v[dx][2] = 0.f; v[dx][3] = 0.f; }
    }
    if (ky == 1) {
#pragma unroll
      for (int px = 0; px < 4; px++)
#pragma unroll
        for (int j = 0; j < 4; j++) xc[px][j] = v[px + 1][j];
    }
#pragma unroll
    for (int kx = 0; kx < 3; kx++) {
      const float4 wv = *(const float4*)&w9[ky * 3 + kx][c0];
#pragma unroll
      for (int px = 0; px < 4; px++) {
        acc[px][0] += wv.x * v[px + kx][0]; acc[px][1] += wv.y * v[px + kx][1];
        acc[px][2] += wv.z * v[px + kx][2]; acc[px][3] += wv.w * v[px + kx][3];
      }
    }
  }
  const float4 g4 = *(const float4*)&g[c0];
  const float4 b4 = *(const float4*)&b[c0];
#pragma unroll
  for (int px = 0; px < 4; px++) {
    float a[4];
#pragma unroll
    for (int j = 0; j < 4; j++) a[j] = xc[px][j] + acc[px][j];
    st4(A + (size_t)(pbase + px) * 64 + c0, a);
    float s = a[0] + a[1] + a[2] + a[3];
#pragma unroll
    for (int off = 8; off; off >>= 1) s += __shfl_xor(s, off);
    float mean = s * (1.f / 64.f);
    float d[4], q = 0.f;
#pragma unroll
    for (int j = 0; j < 4; j++) { d[j] = a[j] - mean; q += d[j] * d[j]; }
#pragma unroll
    for (int off = 8; off; off >>= 1) q += __shfl_xor(q, off);
    float inv = rsqrtf(q * (1.f / 64.f) + 1e-6f);
    float y[4] = {d[0] * inv * g4.x + b4.x, d[1] * inv * g4.y + b4.y,
                  d[2] * inv * g4.z + b4.z, d[3] * inv * g4.w + b4.w};
    st4(T + (size_t)(pbase + px) * 64 + c0, y);
    st4(&yt[pl0 + px][c0], y);
  }
  __syncthreads();
  // QKV MFMA: 4 waves, wave = one 16-px m-tile; NC=128 (Q 0..63, V 64..127)
  // NOTE: tile base is block-uniform blk*64 (round-10 bug: used per-thread pbase)
  int wid = tid >> 6, lane = tid & 63;
  int lr = lane & 15, lg = lane >> 4;
  size_t mbase = (size_t)blk * 64;
  short8v a0 = *(const short8v*)&yt[wid * 16 + lr][lg * 8];
  short8v a1 = *(const short8v*)&yt[wid * 16 + lr][32 + lg * 8];
#pragma unroll
  for (int nt = 0; nt < 8; nt++) {
    int col = nt * 16 + lr;
    float bv = col < 64 ? qbs[col] : vbias[col - 64];
    f32x4 acc4 = {bv, bv, bv, bv};
    int byte = (col * 128 + lg * 16) ^ ((col & 7) << 4);
    acc4 = __builtin_amdgcn_mfma_f32_16x16x32_bf16(a0, *(const short8v*)(lw + byte), acc4, 0, 0, 0);
    byte = (col * 128 + 64 + lg * 16) ^ ((col & 7) << 4);
    acc4 = __builtin_amdgcn_mfma_f32_16x16x32_bf16(a1, *(const short8v*)(lw + byte), acc4, 0, 0, 0);
#pragma unroll
    for (int j = 0; j < 4; j++) {
      size_t pix = mbase + wid * 16 + lg * 4 + j;
      if (col < 64) Qb[pix * 64 + col] = __float2bfloat16(acc4[j]);
      else          Vb[pix * 64 + (col - 64)] = __float2bfloat16(acc4[j]);
    }
  }
}

// ---- merged weight prep ----
__global__ void k_prep(const float* __restrict__ qkvw, const float* __restrict__ qkvb,
                       const float* __restrict__ wow, const float* __restrict__ f2w,
                       const float* __restrict__ f1w, const float* __restrict__ f1b,
                       const float* __restrict__ pww,
                       bf16* __restrict__ WTq, bf16* __restrict__ WTo,
                       bf16* __restrict__ WT2, bf16* __restrict__ WTf1,
                       float* __restrict__ qbs, float* __restrict__ bc) {
  int t = blockIdx.x * 256 + threadIdx.x;
  if (t < 8192) {
    int r = t >> 6, k = t & 63;
    int src = r < 64 ? r : r + 64;
    float v = qkvw[k * 192 + src];
    if (r < 64) v *= 0.125f;
    WTq[t] = __float2bfloat16(v);
  } else if (t < 12288) {
    int t2 = t - 8192;
    int r = t2 >> 6, k = t2 & 63;
    WTo[t2] = __float2bfloat16(wow[k * 64 + r]);
  } else if (t < 20480) {
    int t2 = t - 12288;
    int r = t2 >> 7, k = t2 & 127;
    WT2[t2] = __float2bfloat16(f2w[k * 64 + r]);
  } else if (t < 28672) {
    int t2 = t - 20480;                    // WTf1 rows 0..127 = W1b^T
    int r = t2 >> 6, k = t2 & 63;
    WTf1[t2] = __float2bfloat16(f1w[k * 256 + 128 + r]);
  } else if (t < 36864) {                  // WTf1 rows 128..255 = (W1a@pw^T)^T
    int t2 = t - 28672;
    int o = t2 & 127, k = t2 >> 7;
    float acc = 0.f;
    for (int j = 0; j < 128; j++) acc += f1w[k * 256 + j] * pww[o * 128 + j];
    WTf1[(128 + o) * 64 + k] = __float2bfloat16(acc);
  } else if (t < 36992) {                  // bc = b1a @ pw^T
    int o = t - 36864;
    float bv = 0.f;
    for (int j = 0; j < 128; j++) bv += f1b[j] * pww[o * 128 + j];
    bc[o] = bv;
  }
  if (t < 64) qbs[t] = qkvb[t] * 0.125f;
}

// ---- fused wo GEMM + res + LN2 + FC1 GEMM ----
__global__ void __launch_bounds__(256) k_wo_ln_fc1(const bf16* __restrict__ In,
                                                   const bf16* __restrict__ WTo,
                                                   const float* __restrict__ wob,
                                                   const float* __restrict__ Res,
                                                   float* __restrict__ Xo,
                                                   const float* __restrict__ g,
                                                   const float* __restrict__ b,
                                                   const bf16* __restrict__ WTf1,
                                                   const float* __restrict__ b1,
                                                   const float* __restrict__ b2,
                                                   bf16* __restrict__ VH,
                                                   bf16* __restrict__ PWO) {
  __shared__ char lwo[64 * 64 * 2];
  __shared__ char lf1[256 * 64 * 2];
  __shared__ float xs[16][68];
  __shared__ bf16 a2t[16][72];
  int tid = threadIdx.x;
  for (int ch = tid; ch < 512; ch += 256) {
    int r = ch >> 3, cg = ch & 7;
    int byte = (r * 128 + cg * 16) ^ ((r & 7) << 4);
    *(uint4*)(lwo + byte) = *(const uint4*)((const short*)WTo + ch * 8);
  }
  for (int ch = tid; ch < 2048; ch += 256) {
    int r = ch >> 3, cg = ch & 7;
    int byte = (r * 128 + cg * 16) ^ ((r & 7) << 4);
    *(uint4*)(lf1 + byte) = *(const uint4*)((const short*)WTf1 + ch * 8);
  }
  __syncthreads();
  int wid = tid >> 6, lane = tid & 63;
  int lr = lane & 15, lg = lane >> 4;
  int col_o = wid * 16 + lr;
  int mb = blockIdx.x * 128;
  int row2 = tid >> 4, cq = (tid & 15) << 2;
  const float4 g4 = *(const float4*)&g[cq];
  const float4 b4 = *(const float4*)&b[cq];
  float bvo = wob[col_o];
  for (int ms = 0; ms < 8; ms++) {
    int m0 = mb + ms * 16;
    // phase 1: wo GEMM + residual
    {
      short8v a0 = *(const short8v*)((const short*)In + (size_t)(m0 + lr) * 64 + lg * 8);
      short8v a1 = *(const short8v*)((const short*)In + (size_t)(m0 + lr) * 64 + 32 + lg * 8);
      f32x4 acc = {bvo, bvo, bvo, bvo};
      int byte = (col_o * 128 + lg * 16) ^ ((col_o & 7) << 4);
      acc = __builtin_amdgcn_mfma_f32_16x16x32_bf16(a0, *(const short8v*)(lwo + byte), acc, 0, 0, 0);
      byte = (col_o * 128 + 64 + lg * 16) ^ ((col_o & 7) << 4);
      acc = __builtin_amdgcn_mfma_f32_16x16x32_bf16(a1, *(const short8v*)(lwo + byte), acc, 0, 0, 0);
#pragma unroll
      for (int j = 0; j < 4; j++) {
        float v = acc[j] + Res[(size_t)(m0 + lg * 4 + j) * 64 + col_o];
        Xo[(size_t)(m0 + lg * 4 + j) * 64 + col_o] = v;
        xs[lg * 4 + j][col_o] = v;
      }
    }
    __syncthreads();
    // phase 2: LN2 -> a2t
    {
      float a4[4] = {xs[row2][cq], xs[row2][cq + 1], xs[row2][cq + 2], xs[row2][cq + 3]};
      float s = a4[0] + a4[1] + a4[2] + a4[3];
#pragma unroll
      for (int off = 8; off; off >>= 1) s += __shfl_xor(s, off);
      float mean = s * (1.f / 64.f);
      float d[4], q = 0.f;
#pragma unroll
      for (int j = 0; j < 4; j++) { d[j] = a4[j] - mean; q += d[j] * d[j]; }
#pragma unroll
      for (int off = 8; off; off >>= 1) q += __shfl_xor(q, off);
      float inv = rsqrtf(q * (1.f / 64.f) + 1e-6f);
      float y[4] = {d[0] * inv * g4.x + b4.x, d[1] * inv * g4.y + b4.y,
                    d[2] * inv * g4.z + b4.z, d[3] * inv * g4.w + b4.w};
      st4(&a2t[row2][cq], y);
    }
    __syncthreads();
    // phase 3: FC1 GEMM (NC=256: VH 0..127, PWO 128..255)
    {
      short8v f0 = *(const short8v*)&a2t[lr][lg * 8];
      short8v f1 = *(const short8v*)&a2t[lr][32 + lg * 8];
#pragma unroll
      for (int t = 0; t < 4; t++) {
        int nt = wid * 4 + t;
        int col = nt * 16 + lr;
        float bv = col < 128 ? b1[col] : b2[col - 128];
        f32x4 acc = {bv, bv, bv, bv};
        int byte = (col * 128 + lg * 16) ^ ((col & 7) << 4);
        acc = __builtin_amdgcn_mfma_f32_16x16x32_bf16(f0, *(const short8v*)(lf1 + byte), acc, 0, 0, 0);
        byte = (col * 128 + 64 + lg * 16) ^ ((col & 7) << 4);
        acc = __builtin_amdgcn_mfma_f32_16x16x32_bf16(f1, *(const short8v*)(lf1 + byte), acc, 0, 0, 0);
#pragma unroll
        for (int j = 0; j < 4; j++) {
          size_t pix = m0 + lg * 4 + j;
          if (col < 128) VH[pix * 128 + col] = __float2bfloat16(acc[j]);
          else           PWO[pix * 128 + (col - 128)] = __float2bfloat16(acc[j]);
        }
      }
    }
    __syncthreads();
  }
}

// ---- fused GLU-dw + gelu*VH + fc2 GEMM + residual ----
__global__ void __launch_bounds__(256) k_glu_fc2(const bf16* __restrict__ PWO,
                                                 const bf16* __restrict__ VH,
                                                 const float* __restrict__ wt,
                                                 const float* __restrict__ bs,
                                                 const bf16* __restrict__ WT2,
                                                 const float* __restrict__ f2b,
                                                 float* __restrict__ X) {
  __shared__ float wd[9][132];
  __shared__ float bb[128];
  __shared__ bf16 gt[128][136];
  __shared__ char lw2[64 * 128 * 2];
  int tid = threadIdx.x;
  for (int j = tid; j < 1152; j += 256) {
    int tap = j >> 7, c = j & 127;
    wd[tap][c] = wt[c * 9 + tap];
  }
  if (tid < 128) bb[tid] = bs[tid];
  for (int ch = tid; ch < 1024; ch += 256) {
    int r = ch >> 4, cg = ch & 15;
    int byte = (r * 256 + cg * 16) ^ ((r & 7) << 4);
    *(uint4*)(lw2 + byte) = *(const uint4*)((const short*)WT2 + ch * 8);
  }
  __syncthreads();
  int blk = blockIdx.x;            // 1024 = (n*256 + h)*2 + half
  int w0 = (blk & 1) * 128, h = (blk >> 1) & 255, n = blk >> 9;
  int pbase = (n << 16) | (h << 8) | w0;
  int cg = tid & 31, c0 = cg << 2;
  int pg = tid >> 5;               // 0..7
  const float4 bb4 = *(const float4*)&bb[c0];
#pragma unroll
  for (int pass = 0; pass < 4; pass++) {
    int wb = w0 + pass * 32 + pg * 4;  // this thread's 4-px base
    float acc[4][4];
#pragma unroll
    for (int px = 0; px < 4; px++) {
      acc[px][0] = bb4.x; acc[px][1] = bb4.y; acc[px][2] = bb4.z; acc[px][3] = bb4.w;
    }
#pragma unroll
    for (int ky = 0; ky < 3; ky++) {
      int hh = h + ky - 1;
      if ((unsigned)hh >= 256u) continue;
      const bf16* prow = PWO + (size_t)((n << 16) | (hh << 8)) * 128 + c0;
      float v[6][4];
#pragma unroll
      for (int dx = 0; dx < 6; dx++) {
        int ww = wb + dx - 1;
        if ((unsigned)ww < 256u) ld4(prow + (size_t)ww * 128, v[dx]);
        else { v[dx][0] = 0.f; v[dx][1] = 0.f; v[dx][2] = 0.f; v[dx][3] = 0.f; }
      }
#pragma unroll
      for (int kx = 0; kx < 3; kx++) {
        const float4 wv = *(const float4*)&wd[ky * 3 + kx][c0];
#pragma unroll
        for (int px = 0; px < 4; px++) {
          acc[px][0] += wv.x * v[px + kx][0]; acc[px][1] += wv.y * v[px + kx][1];
          acc[px][2] += wv.z * v[px + kx][2]; acc[px][3] += wv.w * v[px + kx][3];
        }
      }
    }
#pragma unroll
    for (int px = 0; px < 4; px++) {
      int pl = pass * 32 + pg * 4 + px;
      float vh[4];
      ld4(VH + (size_t)(pbase + pl) * 128 + c0, vh);
      float o[4];
#pragma unroll
      for (int j = 0; j < 4; j++) {
        float x = acc[px][j];
        float ge = 0.5f * x * (1.f + erff(x * 0.70710678118f));
        o[j] = ge * vh[j];
      }
      st4(&gt[pl][c0], o);
    }
  }
  __syncthreads();
  // fc2: K=128, N=64; 8 m-tiles, wave handles m-tiles {wid, wid+4}
  int wid = tid >> 6, lane = tid & 63;
  int lr = lane & 15, lg = lane >> 4;
#pragma unroll
  for (int mi = 0; mi < 2; mi++) {
    int mt = wid + mi * 4;
    int m0 = mt * 16;
    short8v a[4];
#pragma unroll
    for (int ks = 0; ks < 4; ks++)
      a[ks] = *(const short8v*)&gt[m0 + lr][ks * 32 + lg * 8];
#pragma unroll
    for (int nt = 0; nt < 4; nt++) {
      int col = nt * 16 + lr;
      float bv = f2b[col];
      f32x4 acc = {bv, bv, bv, bv};
#pragma unroll
      for (int ks = 0; ks < 4; ks++) {
        int byte = (col * 256 + ks * 64 + lg * 16) ^ ((col & 7) << 4);
        acc = __builtin_amdgcn_mfma_f32_16x16x32_bf16(a[ks], *(const short8v*)(lw2 + byte), acc, 0, 0, 0);
      }
#pragma unroll
      for (int j = 0; j < 4; j++) {
        size_t pix = pbase + m0 + lg * 4 + j;
        X[pix * 64 + col] += acc[j];
      }
    }
  }
}

// ---- 8x8 block means of LN1 (f32, exact routing path) ----
__global__ void k_pool8(const float* __restrict__ T, float* __restrict__ Y8) {
  int b = blockIdx.x;
  int c = threadIdx.x;
  int bx = b & 31, by = (b >> 5) & 31, n = b >> 10;
  float acc = 0.f;
  for (int r = 0; r < 8; r++)
    for (int s = 0; s < 8; s++) {
      int p = (n << 16) | ((by * 8 + r) << 8) | (bx * 8 + s);
      acc += T[(size_t)p * 64 + c];
    }
  Y8[(size_t)b * 64 + c] = acc * (1.f / 64.f);
}

// ---- fused window-mean + q/k projection ----
__global__ void __launch_bounds__(256) k_qkwin2(const float* __restrict__ Y8,
                                                const float* __restrict__ qw,
                                                const float* __restrict__ qb,
                                                float* __restrict__ QW,
                                                float* __restrict__ KW) {
  __shared__ float ym[4][68];
  int blk = blockIdx.x;
  int sel = blk >> 5;
  int r0 = (blk & 31) * 4;
  int tid = threadIdx.x;
  {
    int rl = tid >> 6, c = tid & 63;
    int row = r0 + rl;
    int n = row >> 6, win = row & 63;
    int wi = win >> 3, wj = win & 7;
    float acc = 0.f;
    for (int ti = 0; ti < 4; ti++)
      for (int tj = 0; tj < 4; tj++) {
        int y8 = (n * 32 + wi * 4 + ti) * 32 + wj * 4 + tj;
        acc += Y8[(size_t)y8 * 64 + c];
      }
    ym[rl][c] = acc * (1.f / 16.f);
  }
  __syncthreads();
  int rl = tid >> 6, c = tid & 63;
  int row = r0 + rl;
  int colg = sel * 64 + c;
  float acc = qb[colg];
  for (int k = 0; k < 64; k++) acc += ym[rl][k] * qw[k * 192 + colg];
  (sel ? KW : QW)[(size_t)row * 64 + c] = acc;
}

__global__ void k_kvp(const float* __restrict__ Y8, const float* __restrict__ qw,
                      const float* __restrict__ qb, float* __restrict__ KVP) {
  int t = blockIdx.x * blockDim.x + threadIdx.x;
  if (t >= 262144) return;
  int c2 = t & 127, tok = (t >> 7) & 15, win = (t >> 11) & 63, n = t >> 17;
  int wi = win >> 3, wj = win & 7, ti = tok >> 2, tj = tok & 3;
  int y8 = (n * 32 + wi * 4 + ti) * 32 + wj * 4 + tj;
  const float* y = Y8 + (size_t)y8 * 64;
  int col = 64 + c2;
  float acc = qb[col];
  for (int k = 0; k < 64; k++) acc += y[k] * qw[k * 192 + col];
  KVP[t] = acc;
}

// ---- routing: top-4 ----
__global__ void __launch_bounds__(64) k_route(const float* __restrict__ QW,
                                              const float* __restrict__ KW,
                                              int* __restrict__ RIDX) {
  __shared__ float kk[64][65];
  __shared__ float qq[64];
  int b = blockIdx.x;
  int lane = threadIdx.x;
  int n = b >> 6;
  qq[lane] = QW[(size_t)b * 64 + lane];
  for (int r = 0; r < 64; r++) kk[r][lane] = KW[(size_t)(n * 64 + r) * 64 + lane];
  __syncthreads();
  float t = 0.f;
  for (int c = 0; c < 64; c++) t += qq[c] * kk[lane][c];
  t *= 0.125f;
  int o0 = 0, o1 = 0, o2 = 0, o3 = 0;
#pragma unroll
  for (int j = 0; j < 4; j++) {
    float v = t; int idx = lane;
#pragma unroll
    for (int off = 32; off; off >>= 1) {
      float ov = __shfl_xor(v, off);
      int oi = __shfl_xor(idx, off);
      if (ov > v || (ov == v && oi < idx)) { v = ov; idx = oi; }
    }
    if (j == 0) o0 = idx; else if (j == 1) o1 = idx;
    else if (j == 2) o2 = idx; else o3 = idx;
    if (lane == idx) t = -1e30f;
  }
  if (lane == 0) {
    int* o = RIDX + (size_t)b * 4;
    o[0] = o0; o[1] = o1; o[2] = o2; o[3] = o3;
  }
}

// ---- MFMA attention -> bf16 output ----
__global__ void __launch_bounds__(256) k_attn_mf(const bf16* __restrict__ Qb,
                                                 const float* __restrict__ KVP,
                                                 const int* __restrict__ RIDX,
                                                 bf16* __restrict__ Sbf) {
  __shared__ bf16 ks[64][72];
  __shared__ bf16 vt[64][72];
  __shared__ bf16 pa[4][16][72];
  __shared__ float ldn[4][16];
  __shared__ int idx[4];
  int blk = blockIdx.x;
  int part = blk & 3, bw = blk >> 2;
  int n = bw >> 6, win = bw & 63;
  int tid = threadIdx.x;
  if (tid < 4) idx[tid] = RIDX[bw * 4 + tid];
  __syncthreads();
  {
    int tok = tid & 63;
    const float* src = KVP + ((size_t)(n * 64 + idx[tok >> 4]) * 16 + (tok & 15)) * 128;
    for (int cq = tid >> 6; cq < 16; cq += 4) {
      int c0 = cq * 4;
      const float4 k4 = *(const float4*)&src[c0];
      *(uint2*)&ks[tok][c0] = pk4(k4.x, k4.y, k4.z, k4.w);
      const float4 v4 = *(const float4*)&src[64 + c0];
      vt[c0 + 0][tok] = __float2bfloat16(v4.x);
      vt[c0 + 1][tok] = __float2bfloat16(v4.y);
      vt[c0 + 2][tok] = __float2bfloat16(v4.z);
      vt[c0 + 3][tok] = __float2bfloat16(v4.w);
    }
  }
  __syncthreads();
  int w = tid >> 6, lane = tid & 63;
  int lr = lane & 15, lg = lane >> 4;
  int wi = win >> 3, wj = win & 7;
  for (int it = 0; it < 4; it++) {
    int qbase = part * 256 + w * 64 + it * 16;
    int q_b = qbase + lr;
    int pix_b = (n << 16) | ((wi * 32 + (q_b >> 5)) << 8) | (wj * 32 + (q_b & 31));
    short8v qf0 = *(const short8v*)((const short*)Qb + (size_t)pix_b * 64 + lg * 8);
    short8v qf1 = *(const short8v*)((const short*)Qb + (size_t)pix_b * 64 + 32 + lg * 8);
    f32x4 p[4] = {{0,0,0,0},{0,0,0,0},{0,0,0,0},{0,0,0,0}};
#pragma unroll
    for (int mt = 0; mt < 4; mt++) {
      short8v a0 = *(const short8v*)&ks[mt * 16 + lr][lg * 8];
      p[mt] = __builtin_amdgcn_mfma_f32_16x16x32_bf16(a0, qf0, p[mt], 0, 0, 0);
    }
#pragma unroll
    for (int mt = 0; mt < 4; mt++) {
      short8v a1 = *(const short8v*)&ks[mt * 16 + lr][32 + lg * 8];
      p[mt] = __builtin_amdgcn_mfma_f32_16x16x32_bf16(a1, qf1, p[mt], 0, 0, 0);
    }
    float mx = -1e30f;
#pragma unroll
    for (int mt = 0; mt < 4; mt++)
#pragma unroll
      for (int j = 0; j < 4; j++) mx = fmaxf(mx, p[mt][j]);
    mx = fmaxf(mx, __shfl_xor(mx, 16));
    mx = fmaxf(mx, __shfl_xor(mx, 32));
    float e[4][4];
    float sum = 0.f;
#pragma unroll
    for (int mt = 0; mt < 4; mt++)
#pragma unroll
      for (int j = 0; j < 4; j++) { e[mt][j] = __expf(p[mt][j] - mx); sum += e[mt][j]; }
    sum += __shfl_xor(sum, 16);
    sum += __shfl_xor(sum, 32);
    if (lg == 0) ldn[w][lr] = sum;
#pragma unroll
    for (int mt = 0; mt < 4; mt++)
      *(uint2*)&pa[w][lr][mt * 16 + lg * 4] = pk4(e[mt][0], e[mt][1], e[mt][2], e[mt][3]);
    short8v pf0 = *(const short8v*)&pa[w][lr][lg * 8];
    short8v pf1 = *(const short8v*)&pa[w][lr][32 + lg * 8];
    f32x4 o4[4] = {{0,0,0,0},{0,0,0,0},{0,0,0,0},{0,0,0,0}};
#pragma unroll
    for (int nt = 0; nt < 4; nt++) {
      short8v v0 = *(const short8v*)&vt[nt * 16 + lr][lg * 8];
      o4[nt] = __builtin_amdgcn_mfma_f32_16x16x32_bf16(pf0, v0, o4[nt], 0, 0, 0);
    }
#pragma unroll
    for (int nt = 0; nt < 4; nt++) {
      short8v v1 = *(const short8v*)&vt[nt * 16 + lr][32 + lg * 8];
      o4[nt] = __builtin_amdgcn_mfma_f32_16x16x32_bf16(pf1, v1, o4[nt], 0, 0, 0);
    }
    float linv[4];
#pragma unroll
    for (int j = 0; j < 4; j++) linv[j] = 1.f / ldn[w][lg * 4 + j];
#pragma unroll
    for (int j = 0; j < 4; j++) {
      int q_o = qbase + lg * 4 + j;
      size_t pix_o = (n << 16) | ((wi * 32 + (q_o >> 5)) << 8) | (wj * 32 + (q_o & 31));
      bf16* op = Sbf + pix_o * 64 + lr;
#pragma unroll
      for (int nt = 0; nt < 4; nt++) op[nt * 16] = __float2bfloat16(o4[nt][j] * linv[j]);
    }
  }
}

// ---- LePE: 4 px/thread; Sb = bf16(Sbf + dw5x5(V)) ----
__global__ void __launch_bounds__(256) k_lepe4(const bf16* __restrict__ V,
                                               const bf16* __restrict__ Sbf,
                                               bf16* __restrict__ Sb,
                                               const float* __restrict__ wt,
                                               const float* __restrict__ bs) {
  __shared__ float w5[25][68];
  __shared__ float bb[64];
  int tid = threadIdx.x;
  for (int j = tid; j < 1600; j += 256) {
    int tap = j >> 6, c = j & 63;
    w5[tap][c] = wt[c * 25 + tap];
  }
  if (tid < 64) bb[tid] = bs[tid];
  __syncthreads();
  int gid = blockIdx.x * 256 + tid;
  int cg = gid & 15, pg = gid >> 4;
  int c0 = cg << 2;
  int w0 = (pg & 63) << 2, h = (pg >> 6) & 255, n = pg >> 14;
  int pbase = (n << 16) | (h << 8) | w0;
  float acc[4][4];
  {
    const float4 b4 = *(const float4*)&bb[c0];
#pragma unroll
    for (int px = 0; px < 4; px++) {
      acc[px][0] = b4.x; acc[px][1] = b4.y; acc[px][2] = b4.z; acc[px][3] = b4.w;
    }
  }
#pragma unroll
  for (int ky = 0; ky < 5; ky++) {
    int hh = h + ky - 2;
    if ((unsigned)hh >= 256u) continue;
    const bf16* vrow = V + (size_t)((n << 16) | (hh << 8)) * 64 + c0;
    float v[8][4];
#pragma unroll
    for (int dx = 0; dx < 8; dx++) {
      int ww = w0 + dx - 2;
      if ((unsigned)ww < 256u) ld4(vrow + (size_t)ww * 64, v[dx]);
      else { v[dx][0] = 0.f; v[dx][1] = 0.f; v[dx][2] = 0.f; v[dx][3] = 0.f; }
    }
#pragma unroll
    for (int kx = 0; kx < 5; kx++) {
      const float4 wv = *(const float4*)&w5[ky * 5 + kx][c0];
#pragma unroll
      for (int px = 0; px < 4; px++) {
        acc[px][0] += wv.x * v[px + kx][0]; acc[px][1] += wv.y * v[px + kx][1];
        acc[px][2] += wv.z * v[px + kx][2]; acc[px][3] += wv.w * v[px + kx][3];
      }
    }
  }
#pragma unroll
  for (int px = 0; px < 4; px++) {
    float s4[4];
    ld4(Sbf + (size_t)(pbase + px) * 64 + c0, s4);
    float o[4] = {s4[0] + acc[px][0], s4[1] + acc[px][1],
                  s4[2] + acc[px][2], s4[3] + acc[px][3]};
    st4(Sb + (size_t)(pbase + px) * 64 + c0, o);
  }
}

extern "C" void kernel_launch(void* const* d_in, const int* in_sizes, int n_in,
                              void* d_out, int out_size, void* d_ws, size_t ws_size,
                              hipStream_t stream) {
  (void)in_sizes; (void)n_in; (void)out_size; (void)ws_size;
  const float* xin = (const float*)d_in[0];
  auto Wp = [&](int i) { return (const float*)d_in[i]; };
  char* ws = (char*)d_ws;
  const size_t MB = 1u << 20;
  // layout (lifetime-checked):
  // 0..32   : X trunk f32 (persistent)
  // 32..64  : A res f32 (pcln->wo) | VH bf16 (wo_ln_fc1 writes after reading A)
  // 64..96  : T LN1 f32 (pool8) | Sbf bf16 (attn) | PWO bf16 (wo_ln_fc1)
  // 96..112 : Vb bf16 (pcln_qkv -> lepe)
  // 112..128: Qb bf16 (pcln_qkv -> attn) | Sb bf16 (lepe -> wo_ln_fc1)
  float* X  = (float*)(ws + 0 * MB);
  float* A  = (float*)(ws + 32 * MB);
  float* T  = (float*)(ws + 64 * MB);
  char*  sm = ws + 128 * MB;
  size_t off = 0;
  auto alloc = [&](size_t bytes) {
    void* p = sm + off;
    off += (bytes + 255) & ~(size_t)255;
    return p;
  };
  float* Y8   = (float*)alloc(2 * 32 * 32 * 64 * 4);
  float* QW   = (float*)alloc(2 * 64 * 64 * 4);
  float* KW   = (float*)alloc(2 * 64 * 64 * 4);
  float* KVP  = (float*)alloc(2 * 64 * 16 * 128 * 4);
  int*  RIDX  = (int*)alloc(2 * 64 * 4 * 4);
  float* bc   = (float*)alloc(128 * 4);
  bf16* WTq   = (bf16*)alloc(128 * 64 * 2);
  bf16* WTo   = (bf16*)alloc(64 * 64 * 2);
  bf16* WT2   = (bf16*)alloc(64 * 128 * 2);
  bf16* WTf1  = (bf16*)alloc(256 * 64 * 2);
  float* qbs  = (float*)alloc(64 * 4);
  bf16* Vb   = (bf16*)(ws + 96 * MB);    // [P][64]
  bf16* Qb   = (bf16*)(ws + 112 * MB);   // [P][64]
  bf16* Sbf  = (bf16*)T;                 // [P][64]
  bf16* Sb   = (bf16*)(ws + 112 * MB);   // [P][64] (Qb dead after attn)
  bf16* VH   = (bf16*)A;                 // [P][128] (A consumed in-kernel)
  bf16* PWO  = (bf16*)T;                 // [P][128] (T/Sbf dead)

  k_in_tr<<<dim3(2048), dim3(256), 0, stream>>>(xin, X);
  for (int i = 0; i < 2; i++) {
    const float *posw = Wp(1) + i * 64 * 9, *posb = Wp(2) + i * 64;
    const float *l1g = Wp(3) + i * 64, *l1b = Wp(4) + i * 64;
    const float *qkvw = Wp(5) + i * 64 * 192, *qkvb = Wp(6) + i * 192;
    const float *lpw = Wp(7) + i * 64 * 25, *lpb = Wp(8) + i * 64;
    const float *wow = Wp(9) + i * 64 * 64, *wob = Wp(10) + i * 64;
    const float *l2g = Wp(11) + i * 64, *l2b = Wp(12) + i * 64;
    const float *f1w = Wp(13) + i * 64 * 256, *f1b = Wp(14) + i * 256;
    const float *pww = Wp(15) + i * 128 * 128;
    const float *dww = Wp(16) + i * 128 * 9, *dwb = Wp(17) + i * 128;
    const float *f2w = Wp(18) + i * 128 * 64, *f2b = Wp(19) + i * 64;

    k_prep<<<dim3(145), dim3(256), 0, stream>>>(qkvw, qkvb, wow, f2w, f1w, f1b, pww,
                                                WTq, WTo, WT2, WTf1, qbs, bc);
    k_pcln_qkv<<<dim3(2048), dim3(256), 0, stream>>>(
        X, A, T, posw, posb, l1g, l1b, WTq, qbs, qkvb + 128, Qb, Vb);
    k_pool8<<<dim3(2048), dim3(64), 0, stream>>>(T, Y8);
    k_qkwin2<<<dim3(64), dim3(256), 0, stream>>>(Y8, qkvw, qkvb, QW, KW);
    k_kvp<<<dim3(1024), dim3(256), 0, stream>>>(Y8, qkvw, qkvb, KVP);
    k_route<<<dim3(128), dim3(64), 0, stream>>>(QW, KW, RIDX);
    k_attn_mf<<<dim3(512), dim3(256), 0, stream>>>(Qb, KVP, RIDX, Sbf);
    k_lepe4<<<dim3(2048), dim3(256), 0, stream>>>(Vb, Sbf, Sb, lpw, lpb);
    k_wo_ln_fc1<<<dim3(Pp / 128), dim3(256), 0, stream>>>(
        Sb, WTo, wob, A, X, l2g, l2b, WTf1, f1b + 128, bc, VH, PWO);
    k_glu_fc2<<<dim3(1024), dim3(256), 0, stream>>>(PWO, VH, dww, dwb, WT2, f2b, X);
  }
  k_out<<<dim3(2048), dim3(256), 0, stream>>>(X, (float*)d_out);
}

// Round 12
// 440.775 us; speedup vs baseline: 6.4439x; 1.0014x over previous
//
#include <hip/hip_runtime.h>
#include <hip/hip_bf16.h>

typedef __hip_bfloat16 bf16;
typedef __attribute__((ext_vector_type(8))) short short8v;
typedef __attribute__((ext_vector_type(4))) float f32x4;

static constexpr int Nn = 2, Hh = 256, Wd = 256;
static constexpr int Pp = Nn * Hh * Wd;  // 131072 pixels

__device__ inline void ld4(const float* p, float f[4]) {
  const float4 v = *(const float4*)p;
  f[0] = v.x; f[1] = v.y; f[2] = v.z; f[3] = v.w;
}
__device__ inline void ld4(const bf16* p, float f[4]) {
  uint2 u = *(const uint2*)p;
  f[0] = __uint_as_float(u.x << 16); f[1] = __uint_as_float(u.x & 0xffff0000u);
  f[2] = __uint_as_float(u.y << 16); f[3] = __uint_as_float(u.y & 0xffff0000u);
}
__device__ inline void st4(float* p, const float f[4]) {
  *(float4*)p = make_float4(f[0], f[1], f[2], f[3]);
}
__device__ inline void st4(bf16* p, const float f[4]) {
  union { bf16 h[4]; uint2 u; } x;
  x.h[0] = __float2bfloat16(f[0]); x.h[1] = __float2bfloat16(f[1]);
  x.h[2] = __float2bfloat16(f[2]); x.h[3] = __float2bfloat16(f[3]);
  *(uint2*)p = x.u;
}
__device__ inline uint2 pk4(float a, float b, float c, float d) {
  union { bf16 h[4]; uint2 u; } x;
  x.h[0] = __float2bfloat16(a); x.h[1] = __float2bfloat16(b);
  x.h[2] = __float2bfloat16(c); x.h[3] = __float2bfloat16(d);
  return x.u;
}
// XCD-aware swizzle for 2048-block grids (8 XCDs, 256 blocks each, h-contiguous)
__device__ inline int xcd_swz2048(int phys) { return (phys & 7) * 256 + (phys >> 3); }

// ---- NCHW f32 -> NHWC f32, LDS-tiled ----
__global__ void __launch_bounds__(256) k_in_tr(const float* __restrict__ xin,
                                               float* __restrict__ X) {
  __shared__ float t[64][65];
  int blk = blockIdx.x;
  int wt = blk & 3, h = (blk >> 2) & 255, n = blk >> 10;
  int w0 = wt * 64;
  int tx = threadIdx.x & 63, ty = threadIdx.x >> 6;
  const float* src = xin + ((size_t)n * 64 * 256 + h) * 256 + w0;
#pragma unroll
  for (int cc = 0; cc < 16; cc++) {
    int c = cc * 4 + ty;
    t[c][tx] = src[(size_t)c * 65536 + tx];
  }
  __syncthreads();
  float* dst = X + (size_t)(n * 65536 + h * 256 + w0) * 64;
#pragma unroll
  for (int jj = 0; jj < 16; jj++) {
    int j = jj * 4 + ty;
    dst[(size_t)j * 64 + tx] = t[tx][j];
  }
}

// ---- NHWC f32 -> NCHW f32 ----
__global__ void __launch_bounds__(256) k_out(const float* __restrict__ X,
                                             float* __restrict__ out) {
  __shared__ float t[64][65];
  int blk = blockIdx.x;
  int wt = blk & 3, h = (blk >> 2) & 255, n = blk >> 10;
  int w0 = wt * 64;
  int tx = threadIdx.x & 63, ty = threadIdx.x >> 6;
  const float* src = X + (size_t)(n * 65536 + h * 256 + w0) * 64;
#pragma unroll
  for (int jj = 0; jj < 16; jj++) {
    int j = jj * 4 + ty;
    t[tx][j] = src[(size_t)j * 64 + tx];
  }
  __syncthreads();
  float* dst = out + ((size_t)n * 64 * 256 + h) * 256 + w0;
#pragma unroll
  for (int cc = 0; cc < 16; cc++) {
    int c = cc * 4 + ty;
    dst[(size_t)c * 65536 + tx] = t[c][tx];
  }
}

// ---- fused posconv + LN1 + QKV MFMA GEMM (XCD-swizzled) ----
__global__ void __launch_bounds__(256) k_pcln_qkv(const float* __restrict__ X,
                                                  float* __restrict__ A,
                                                  float* __restrict__ T,
                                                  const float* __restrict__ pw,
                                                  const float* __restrict__ pb,
                                                  const float* __restrict__ g,
                                                  const float* __restrict__ b,
                                                  const bf16* __restrict__ WTq,
                                                  const float* __restrict__ qbs,
                                                  const float* __restrict__ vbias,
                                                  bf16* __restrict__ Qb,
                                                  bf16* __restrict__ Vb) {
  __shared__ float w9[9][68];
  __shared__ float bb[64];
  __shared__ bf16 yt[64][72];
  __shared__ char lw[128 * 64 * 2];
  int tid = threadIdx.x;
  for (int j = tid; j < 576; j += 256) {
    int tap = j >> 6, c = j & 63;
    w9[tap][c] = pw[c * 9 + tap];
  }
  if (tid < 64) bb[tid] = pb[tid];
  for (int ch = tid; ch < 1024; ch += 256) {
    int r = ch >> 3, cg = ch & 7;
    int byte = (r * 128 + cg * 16) ^ ((r & 7) << 4);
    *(uint4*)(lw + byte) = *(const uint4*)((const short*)WTq + ch * 8);
  }
  __syncthreads();
  int blk = xcd_swz2048(blockIdx.x);
  int gid = blk * 256 + tid;
  int cg = gid & 15, pg = gid >> 4;
  int c0 = cg << 2;
  int w0 = (pg & 63) << 2, h = (pg >> 6) & 255, n = pg >> 14;
  int pbase = (n << 16) | (h << 8) | w0;
  int pl0 = (tid >> 4) << 2;  // local pixel base (0..60)
  float acc[4][4];
  {
    const float4 b4 = *(const float4*)&bb[c0];
#pragma unroll
    for (int px = 0; px < 4; px++) {
      acc[px][0] = b4.x; acc[px][1] = b4.y; acc[px][2] = b4.z; acc[px][3] = b4.w;
    }
  }
  float xc[4][4];
#pragma unroll
  for (int ky = 0; ky < 3; ky++) {
    int hh = h + ky - 1;
    if ((unsigned)hh >= 256u) continue;
    const float* xrow = X + (size_t)((n << 16) | (hh << 8)) * 64 + c0;
    float v[6][4];
#pragma unroll
    for (int dx = 0; dx < 6; dx++) {
      int ww = w0 + dx - 1;
      if ((unsigned)ww < 256u) ld4(xrow + (size_t)ww * 64, v[dx]);
      else { v[dx][0] = 0.f; v[dx][1] = 0.f; v[dx][2] = 0.f; v[dx][3] = 0.f; }
    }
    if (ky == 1) {
#pragma unroll
      for (int px = 0; px < 4; px++)
#pragma unroll
        for (int j = 0; j < 4; j++) xc[px][j] = v[px + 1][j];
    }
#pragma unroll
    for (int kx = 0; kx < 3; kx++) {
      const float4 wv = *(const float4*)&w9[ky * 3 + kx][c0];
#pragma unroll
      for (int px = 0; px < 4; px++) {
        acc[px][0] += wv.x * v[px + kx][0]; acc[px][1] += wv.y * v[px + kx][1];
        acc[px][2] += wv.z * v[px + kx][2]; acc[px][3] += wv.w * v[px + kx][3];
      }
    }
  }
  const float4 g4 = *(const float4*)&g[c0];
  const float4 b4 = *(const float4*)&b[c0];
#pragma unroll
  for (int px = 0; px < 4; px++) {
    float a[4];
#pragma unroll
    for (int j = 0; j < 4; j++) a[j] = xc[px][j] + acc[px][j];
    st4(A + (size_t)(pbase + px) * 64 + c0, a);
    float s = a[0] + a[1] + a[2] + a[3];
#pragma unroll
    for (int off = 8; off; off >>= 1) s += __shfl_xor(s, off);
    float mean = s * (1.f / 64.f);
    float d[4], q = 0.f;
#pragma unroll
    for (int j = 0; j < 4; j++) { d[j] = a[j] - mean; q += d[j] * d[j]; }
#pragma unroll
    for (int off = 8; off; off >>= 1) q += __shfl_xor(q, off);
    float inv = rsqrtf(q * (1.f / 64.f) + 1e-6f);
    float y[4] = {d[0] * inv * g4.x + b4.x, d[1] * inv * g4.y + b4.y,
                  d[2] * inv * g4.z + b4.z, d[3] * inv * g4.w + b4.w};
    st4(T + (size_t)(pbase + px) * 64 + c0, y);
    st4(&yt[pl0 + px][c0], y);
  }
  __syncthreads();
  // QKV MFMA: tile base is block-uniform blk*64
  int wid = tid >> 6, lane = tid & 63;
  int lr = lane & 15, lg = lane >> 4;
  size_t mbase = (size_t)blk * 64;
  short8v a0 = *(const short8v*)&yt[wid * 16 + lr][lg * 8];
  short8v a1 = *(const short8v*)&yt[wid * 16 + lr][32 + lg * 8];
#pragma unroll
  for (int nt = 0; nt < 8; nt++) {
    int col = nt * 16 + lr;
    float bv = col < 64 ? qbs[col] : vbias[col - 64];
    f32x4 acc4 = {bv, bv, bv, bv};
    int byte = (col * 128 + lg * 16) ^ ((col & 7) << 4);
    acc4 = __builtin_amdgcn_mfma_f32_16x16x32_bf16(a0, *(const short8v*)(lw + byte), acc4, 0, 0, 0);
    byte = (col * 128 + 64 + lg * 16) ^ ((col & 7) << 4);
    acc4 = __builtin_amdgcn_mfma_f32_16x16x32_bf16(a1, *(const short8v*)(lw + byte), acc4, 0, 0, 0);
#pragma unroll
    for (int j = 0; j < 4; j++) {
      size_t pix = mbase + wid * 16 + lg * 4 + j;
      if (col < 64) Qb[pix * 64 + col] = __float2bfloat16(acc4[j]);
      else          Vb[pix * 64 + (col - 64)] = __float2bfloat16(acc4[j]);
    }
  }
}

// ---- merged weight prep ----
__global__ void k_prep(const float* __restrict__ qkvw, const float* __restrict__ qkvb,
                       const float* __restrict__ wow, const float* __restrict__ f2w,
                       const float* __restrict__ f1w, const float* __restrict__ f1b,
                       const float* __restrict__ pww,
                       bf16* __restrict__ WTq, bf16* __restrict__ WTo,
                       bf16* __restrict__ WT2, bf16* __restrict__ WTf1,
                       float* __restrict__ qbs, float* __restrict__ bc) {
  int t = blockIdx.x * 256 + threadIdx.x;
  if (t < 8192) {
    int r = t >> 6, k = t & 63;
    int src = r < 64 ? r : r + 64;
    float v = qkvw[k * 192 + src];
    if (r < 64) v *= 0.125f;
    WTq[t] = __float2bfloat16(v);
  } else if (t < 12288) {
    int t2 = t - 8192;
    int r = t2 >> 6, k = t2 & 63;
    WTo[t2] = __float2bfloat16(wow[k * 64 + r]);
  } else if (t < 20480) {
    int t2 = t - 12288;
    int r = t2 >> 7, k = t2 & 127;
    WT2[t2] = __float2bfloat16(f2w[k * 64 + r]);
  } else if (t < 28672) {
    int t2 = t - 20480;                    // WTf1 rows 0..127 = W1b^T
    int r = t2 >> 6, k = t2 & 63;
    WTf1[t2] = __float2bfloat16(f1w[k * 256 + 128 + r]);
  } else if (t < 36864) {                  // WTf1 rows 128..255 = (W1a@pw^T)^T
    int t2 = t - 28672;
    int o = t2 & 127, k = t2 >> 7;
    float acc = 0.f;
    for (int j = 0; j < 128; j++) acc += f1w[k * 256 + j] * pww[o * 128 + j];
    WTf1[(128 + o) * 64 + k] = __float2bfloat16(acc);
  } else if (t < 36992) {                  // bc = b1a @ pw^T
    int o = t - 36864;
    float bv = 0.f;
    for (int j = 0; j < 128; j++) bv += f1b[j] * pww[o * 128 + j];
    bc[o] = bv;
  }
  if (t < 64) qbs[t] = qkvb[t] * 0.125f;
}

// ---- fused wo GEMM + res + LN2 + FC1 GEMM ----
__global__ void __launch_bounds__(256) k_wo_ln_fc1(const bf16* __restrict__ In,
                                                   const bf16* __restrict__ WTo,
                                                   const float* __restrict__ wob,
                                                   const float* __restrict__ Res,
                                                   float* __restrict__ Xo,
                                                   const float* __restrict__ g,
                                                   const float* __restrict__ b,
                                                   const bf16* __restrict__ WTf1,
                                                   const float* __restrict__ b1,
                                                   const float* __restrict__ b2,
                                                   bf16* __restrict__ VH,
                                                   bf16* __restrict__ PWO) {
  __shared__ char lwo[64 * 64 * 2];
  __shared__ char lf1[256 * 64 * 2];
  __shared__ float xs[16][68];
  __shared__ bf16 a2t[16][72];
  int tid = threadIdx.x;
  for (int ch = tid; ch < 512; ch += 256) {
    int r = ch >> 3, cg = ch & 7;
    int byte = (r * 128 + cg * 16) ^ ((r & 7) << 4);
    *(uint4*)(lwo + byte) = *(const uint4*)((const short*)WTo + ch * 8);
  }
  for (int ch = tid; ch < 2048; ch += 256) {
    int r = ch >> 3, cg = ch & 7;
    int byte = (r * 128 + cg * 16) ^ ((r & 7) << 4);
    *(uint4*)(lf1 + byte) = *(const uint4*)((const short*)WTf1 + ch * 8);
  }
  __syncthreads();
  int wid = tid >> 6, lane = tid & 63;
  int lr = lane & 15, lg = lane >> 4;
  int col_o = wid * 16 + lr;
  int mb = blockIdx.x * 128;
  int row2 = tid >> 4, cq = (tid & 15) << 2;
  const float4 g4 = *(const float4*)&g[cq];
  const float4 b4 = *(const float4*)&b[cq];
  float bvo = wob[col_o];
  for (int ms = 0; ms < 8; ms++) {
    int m0 = mb + ms * 16;
    // phase 1: wo GEMM + residual
    {
      short8v a0 = *(const short8v*)((const short*)In + (size_t)(m0 + lr) * 64 + lg * 8);
      short8v a1 = *(const short8v*)((const short*)In + (size_t)(m0 + lr) * 64 + 32 + lg * 8);
      f32x4 acc = {bvo, bvo, bvo, bvo};
      int byte = (col_o * 128 + lg * 16) ^ ((col_o & 7) << 4);
      acc = __builtin_amdgcn_mfma_f32_16x16x32_bf16(a0, *(const short8v*)(lwo + byte), acc, 0, 0, 0);
      byte = (col_o * 128 + 64 + lg * 16) ^ ((col_o & 7) << 4);
      acc = __builtin_amdgcn_mfma_f32_16x16x32_bf16(a1, *(const short8v*)(lwo + byte), acc, 0, 0, 0);
#pragma unroll
      for (int j = 0; j < 4; j++) {
        float v = acc[j] + Res[(size_t)(m0 + lg * 4 + j) * 64 + col_o];
        Xo[(size_t)(m0 + lg * 4 + j) * 64 + col_o] = v;
        xs[lg * 4 + j][col_o] = v;
      }
    }
    __syncthreads();
    // phase 2: LN2 -> a2t
    {
      float a4[4] = {xs[row2][cq], xs[row2][cq + 1], xs[row2][cq + 2], xs[row2][cq + 3]};
      float s = a4[0] + a4[1] + a4[2] + a4[3];
#pragma unroll
      for (int off = 8; off; off >>= 1) s += __shfl_xor(s, off);
      float mean = s * (1.f / 64.f);
      float d[4], q = 0.f;
#pragma unroll
      for (int j = 0; j < 4; j++) { d[j] = a4[j] - mean; q += d[j] * d[j]; }
#pragma unroll
      for (int off = 8; off; off >>= 1) q += __shfl_xor(q, off);
      float inv = rsqrtf(q * (1.f / 64.f) + 1e-6f);
      float y[4] = {d[0] * inv * g4.x + b4.x, d[1] * inv * g4.y + b4.y,
                    d[2] * inv * g4.z + b4.z, d[3] * inv * g4.w + b4.w};
      st4(&a2t[row2][cq], y);
    }
    __syncthreads();
    // phase 3: FC1 GEMM (NC=256: VH 0..127, PWO 128..255)
    {
      short8v f0 = *(const short8v*)&a2t[lr][lg * 8];
      short8v f1 = *(const short8v*)&a2t[lr][32 + lg * 8];
#pragma unroll
      for (int t = 0; t < 4; t++) {
        int nt = wid * 4 + t;
        int col = nt * 16 + lr;
        float bv = col < 128 ? b1[col] : b2[col - 128];
        f32x4 acc = {bv, bv, bv, bv};
        int byte = (col * 128 + lg * 16) ^ ((col & 7) << 4);
        acc = __builtin_amdgcn_mfma_f32_16x16x32_bf16(f0, *(const short8v*)(lf1 + byte), acc, 0, 0, 0);
        byte = (col * 128 + 64 + lg * 16) ^ ((col & 7) << 4);
        acc = __builtin_amdgcn_mfma_f32_16x16x32_bf16(f1, *(const short8v*)(lf1 + byte), acc, 0, 0, 0);
#pragma unroll
        for (int j = 0; j < 4; j++) {
          size_t pix = m0 + lg * 4 + j;
          if (col < 128) VH[pix * 128 + col] = __float2bfloat16(acc[j]);
          else           PWO[pix * 128 + (col - 128)] = __float2bfloat16(acc[j]);
        }
      }
    }
    __syncthreads();
  }
}

// ---- fused GLU-dw + gelu*VH + fc2 GEMM + residual (64-px blocks, XCD-swizzled) ----
__global__ void __launch_bounds__(256) k_glu_fc2(const bf16* __restrict__ PWO,
                                                 const bf16* __restrict__ VH,
                                                 const float* __restrict__ wt,
                                                 const float* __restrict__ bs,
                                                 const bf16* __restrict__ WT2,
                                                 const float* __restrict__ f2b,
                                                 float* __restrict__ X) {
  __shared__ float wd[9][132];
  __shared__ float bb[128];
  __shared__ bf16 gt[64][136];
  __shared__ char lw2[64 * 128 * 2];
  int tid = threadIdx.x;
  for (int j = tid; j < 1152; j += 256) {
    int tap = j >> 7, c = j & 127;
    wd[tap][c] = wt[c * 9 + tap];
  }
  if (tid < 128) bb[tid] = bs[tid];
  for (int ch = tid; ch < 1024; ch += 256) {
    int r = ch >> 4, cg = ch & 15;
    int byte = (r * 256 + cg * 16) ^ ((r & 7) << 4);
    *(uint4*)(lw2 + byte) = *(const uint4*)((const short*)WT2 + ch * 8);
  }
  __syncthreads();
  int blk = xcd_swz2048(blockIdx.x);  // 2048 = ((n*256 + h)*4 + wt)
  int w0 = (blk & 3) * 64, h = (blk >> 2) & 255, n = blk >> 10;
  int pbase = (n << 16) | (h << 8) | w0;
  int cg = tid & 31, c0 = cg << 2;
  int pg = tid >> 5;               // 0..7
  const float4 bb4 = *(const float4*)&bb[c0];
#pragma unroll
  for (int pass = 0; pass < 2; pass++) {
    int wb = w0 + pass * 32 + pg * 4;  // this thread's 4-px base
    float acc[4][4];
#pragma unroll
    for (int px = 0; px < 4; px++) {
      acc[px][0] = bb4.x; acc[px][1] = bb4.y; acc[px][2] = bb4.z; acc[px][3] = bb4.w;
    }
#pragma unroll
    for (int ky = 0; ky < 3; ky++) {
      int hh = h + ky - 1;
      if ((unsigned)hh >= 256u) continue;
      const bf16* prow = PWO + (size_t)((n << 16) | (hh << 8)) * 128 + c0;
      float v[6][4];
#pragma unroll
      for (int dx = 0; dx < 6; dx++) {
        int ww = wb + dx - 1;
        if ((unsigned)ww < 256u) ld4(prow + (size_t)ww * 128, v[dx]);
        else { v[dx][0] = 0.f; v[dx][1] = 0.f; v[dx][2] = 0.f; v[dx][3] = 0.f; }
      }
#pragma unroll
      for (int kx = 0; kx < 3; kx++) {
        const float4 wv = *(const float4*)&wd[ky * 3 + kx][c0];
#pragma unroll
        for (int px = 0; px < 4; px++) {
          acc[px][0] += wv.x * v[px + kx][0]; acc[px][1] += wv.y * v[px + kx][1];
          acc[px][2] += wv.z * v[px + kx][2]; acc[px][3] += wv.w * v[px + kx][3];
        }
      }
    }
#pragma unroll
    for (int px = 0; px < 4; px++) {
      int pl = pass * 32 + pg * 4 + px;
      float vh[4];
      ld4(VH + (size_t)(pbase + pl) * 128 + c0, vh);
      float o[4];
#pragma unroll
      for (int j = 0; j < 4; j++) {
        float x = acc[px][j];
        float ge = 0.5f * x * (1.f + erff(x * 0.70710678118f));
        o[j] = ge * vh[j];
      }
      st4(&gt[pl][c0], o);
    }
  }
  __syncthreads();
  // fc2: K=128, N=64; 4 m-tiles, one per wave
  int wid = tid >> 6, lane = tid & 63;
  int lr = lane & 15, lg = lane >> 4;
  int m0 = wid * 16;
  short8v a[4];
#pragma unroll
  for (int ks = 0; ks < 4; ks++)
    a[ks] = *(const short8v*)&gt[m0 + lr][ks * 32 + lg * 8];
#pragma unroll
  for (int nt = 0; nt < 4; nt++) {
    int col = nt * 16 + lr;
    float bv = f2b[col];
    f32x4 acc = {bv, bv, bv, bv};
#pragma unroll
    for (int ks = 0; ks < 4; ks++) {
      int byte = (col * 256 + ks * 64 + lg * 16) ^ ((col & 7) << 4);
      acc = __builtin_amdgcn_mfma_f32_16x16x32_bf16(a[ks], *(const short8v*)(lw2 + byte), acc, 0, 0, 0);
    }
#pragma unroll
    for (int j = 0; j < 4; j++) {
      size_t pix = pbase + m0 + lg * 4 + j;
      X[pix * 64 + col] += acc[j];
    }
  }
}

// ---- 8x8 block means of LN1 (f32, exact routing path) ----
__global__ void k_pool8(const float* __restrict__ T, float* __restrict__ Y8) {
  int b = blockIdx.x;
  int c = threadIdx.x;
  int bx = b & 31, by = (b >> 5) & 31, n = b >> 10;
  float acc = 0.f;
  for (int r = 0; r < 8; r++)
    for (int s = 0; s < 8; s++) {
      int p = (n << 16) | ((by * 8 + r) << 8) | (bx * 8 + s);
      acc += T[(size_t)p * 64 + c];
    }
  Y8[(size_t)b * 64 + c] = acc * (1.f / 64.f);
}

// ---- fused window-mean + q/k projection ----
__global__ void __launch_bounds__(256) k_qkwin2(const float* __restrict__ Y8,
                                                const float* __restrict__ qw,
                                                const float* __restrict__ qb,
                                                float* __restrict__ QW,
                                                float* __restrict__ KW) {
  __shared__ float ym[4][68];
  int blk = blockIdx.x;
  int sel = blk >> 5;
  int r0 = (blk & 31) * 4;
  int tid = threadIdx.x;
  {
    int rl = tid >> 6, c = tid & 63;
    int row = r0 + rl;
    int n = row >> 6, win = row & 63;
    int wi = win >> 3, wj = win & 7;
    float acc = 0.f;
    for (int ti = 0; ti < 4; ti++)
      for (int tj = 0; tj < 4; tj++) {
        int y8 = (n * 32 + wi * 4 + ti) * 32 + wj * 4 + tj;
        acc += Y8[(size_t)y8 * 64 + c];
      }
    ym[rl][c] = acc * (1.f / 16.f);
  }
  __syncthreads();
  int rl = tid >> 6, c = tid & 63;
  int row = r0 + rl;
  int colg = sel * 64 + c;
  float acc = qb[colg];
  for (int k = 0; k < 64; k++) acc += ym[rl][k] * qw[k * 192 + colg];
  (sel ? KW : QW)[(size_t)row * 64 + c] = acc;
}

__global__ void k_kvp(const float* __restrict__ Y8, const float* __restrict__ qw,
                      const float* __restrict__ qb, float* __restrict__ KVP) {
  int t = blockIdx.x * blockDim.x + threadIdx.x;
  if (t >= 262144) return;
  int c2 = t & 127, tok = (t >> 7) & 15, win = (t >> 11) & 63, n = t >> 17;
  int wi = win >> 3, wj = win & 7, ti = tok >> 2, tj = tok & 3;
  int y8 = (n * 32 + wi * 4 + ti) * 32 + wj * 4 + tj;
  const float* y = Y8 + (size_t)y8 * 64;
  int col = 64 + c2;
  float acc = qb[col];
  for (int k = 0; k < 64; k++) acc += y[k] * qw[k * 192 + col];
  KVP[t] = acc;
}

// ---- routing: top-4 ----
__global__ void __launch_bounds__(64) k_route(const float* __restrict__ QW,
                                              const float* __restrict__ KW,
                                              int* __restrict__ RIDX) {
  __shared__ float kk[64][65];
  __shared__ float qq[64];
  int b = blockIdx.x;
  int lane = threadIdx.x;
  int n = b >> 6;
  qq[lane] = QW[(size_t)b * 64 + lane];
  for (int r = 0; r < 64; r++) kk[r][lane] = KW[(size_t)(n * 64 + r) * 64 + lane];
  __syncthreads();
  float t = 0.f;
  for (int c = 0; c < 64; c++) t += qq[c] * kk[lane][c];
  t *= 0.125f;
  int o0 = 0, o1 = 0, o2 = 0, o3 = 0;
#pragma unroll
  for (int j = 0; j < 4; j++) {
    float v = t; int idx = lane;
#pragma unroll
    for (int off = 32; off; off >>= 1) {
      float ov = __shfl_xor(v, off);
      int oi = __shfl_xor(idx, off);
      if (ov > v || (ov == v && oi < idx)) { v = ov; idx = oi; }
    }
    if (j == 0) o0 = idx; else if (j == 1) o1 = idx;
    else if (j == 2) o2 = idx; else o3 = idx;
    if (lane == idx) t = -1e30f;
  }
  if (lane == 0) {
    int* o = RIDX + (size_t)b * 4;
    o[0] = o0; o[1] = o1; o[2] = o2; o[3] = o3;
  }
}

// ---- MFMA attention -> bf16 output ----
__global__ void __launch_bounds__(256) k_attn_mf(const bf16* __restrict__ Qb,
                                                 const float* __restrict__ KVP,
                                                 const int* __restrict__ RIDX,
                                                 bf16* __restrict__ Sbf) {
  __shared__ bf16 ks[64][72];
  __shared__ bf16 vt[64][72];
  __shared__ bf16 pa[4][16][72];
  __shared__ float ldn[4][16];
  __shared__ int idx[4];
  int blk = blockIdx.x;
  int part = blk & 3, bw = blk >> 2;
  int n = bw >> 6, win = bw & 63;
  int tid = threadIdx.x;
  if (tid < 4) idx[tid] = RIDX[bw * 4 + tid];
  __syncthreads();
  {
    int tok = tid & 63;
    const float* src = KVP + ((size_t)(n * 64 + idx[tok >> 4]) * 16 + (tok & 15)) * 128;
    for (int cq = tid >> 6; cq < 16; cq += 4) {
      int c0 = cq * 4;
      const float4 k4 = *(const float4*)&src[c0];
      *(uint2*)&ks[tok][c0] = pk4(k4.x, k4.y, k4.z, k4.w);
      const float4 v4 = *(const float4*)&src[64 + c0];
      vt[c0 + 0][tok] = __float2bfloat16(v4.x);
      vt[c0 + 1][tok] = __float2bfloat16(v4.y);
      vt[c0 + 2][tok] = __float2bfloat16(v4.z);
      vt[c0 + 3][tok] = __float2bfloat16(v4.w);
    }
  }
  __syncthreads();
  int w = tid >> 6, lane = tid & 63;
  int lr = lane & 15, lg = lane >> 4;
  int wi = win >> 3, wj = win & 7;
  for (int it = 0; it < 4; it++) {
    int qbase = part * 256 + w * 64 + it * 16;
    int q_b = qbase + lr;
    int pix_b = (n << 16) | ((wi * 32 + (q_b >> 5)) << 8) | (wj * 32 + (q_b & 31));
    short8v qf0 = *(const short8v*)((const short*)Qb + (size_t)pix_b * 64 + lg * 8);
    short8v qf1 = *(const short8v*)((const short*)Qb + (size_t)pix_b * 64 + 32 + lg * 8);
    f32x4 p[4] = {{0,0,0,0},{0,0,0,0},{0,0,0,0},{0,0,0,0}};
#pragma unroll
    for (int mt = 0; mt < 4; mt++) {
      short8v a0 = *(const short8v*)&ks[mt * 16 + lr][lg * 8];
      p[mt] = __builtin_amdgcn_mfma_f32_16x16x32_bf16(a0, qf0, p[mt], 0, 0, 0);
    }
#pragma unroll
    for (int mt = 0; mt < 4; mt++) {
      short8v a1 = *(const short8v*)&ks[mt * 16 + lr][32 + lg * 8];
      p[mt] = __builtin_amdgcn_mfma_f32_16x16x32_bf16(a1, qf1, p[mt], 0, 0, 0);
    }
    float mx = -1e30f;
#pragma unroll
    for (int mt = 0; mt < 4; mt++)
#pragma unroll
      for (int j = 0; j < 4; j++) mx = fmaxf(mx, p[mt][j]);
    mx = fmaxf(mx, __shfl_xor(mx, 16));
    mx = fmaxf(mx, __shfl_xor(mx, 32));
    float e[4][4];
    float sum = 0.f;
#pragma unroll
    for (int mt = 0; mt < 4; mt++)
#pragma unroll
      for (int j = 0; j < 4; j++) { e[mt][j] = __expf(p[mt][j] - mx); sum += e[mt][j]; }
    sum += __shfl_xor(sum, 16);
    sum += __shfl_xor(sum, 32);
    if (lg == 0) ldn[w][lr] = sum;
#pragma unroll
    for (int mt = 0; mt < 4; mt++)
      *(uint2*)&pa[w][lr][mt * 16 + lg * 4] = pk4(e[mt][0], e[mt][1], e[mt][2], e[mt][3]);
    short8v pf0 = *(const short8v*)&pa[w][lr][lg * 8];
    short8v pf1 = *(const short8v*)&pa[w][lr][32 + lg * 8];
    f32x4 o4[4] = {{0,0,0,0},{0,0,0,0},{0,0,0,0},{0,0,0,0}};
#pragma unroll
    for (int nt = 0; nt < 4; nt++) {
      short8v v0 = *(const short8v*)&vt[nt * 16 + lr][lg * 8];
      o4[nt] = __builtin_amdgcn_mfma_f32_16x16x32_bf16(pf0, v0, o4[nt], 0, 0, 0);
    }
#pragma unroll
    for (int nt = 0; nt < 4; nt++) {
      short8v v1 = *(const short8v*)&vt[nt * 16 + lr][32 + lg * 8];
      o4[nt] = __builtin_amdgcn_mfma_f32_16x16x32_bf16(pf1, v1, o4[nt], 0, 0, 0);
    }
    float linv[4];
#pragma unroll
    for (int j = 0; j < 4; j++) linv[j] = 1.f / ldn[w][lg * 4 + j];
#pragma unroll
    for (int j = 0; j < 4; j++) {
      int q_o = qbase + lg * 4 + j;
      size_t pix_o = (n << 16) | ((wi * 32 + (q_o >> 5)) << 8) | (wj * 32 + (q_o & 31));
      bf16* op = Sbf + pix_o * 64 + lr;
#pragma unroll
      for (int nt = 0; nt < 4; nt++) op[nt * 16] = __float2bfloat16(o4[nt][j] * linv[j]);
    }
  }
}

// ---- LePE: 4 px/thread (XCD-swizzled); Sb = bf16(Sbf + dw5x5(V)) ----
__global__ void __launch_bounds__(256) k_lepe4(const bf16* __restrict__ V,
                                               const bf16* __restrict__ Sbf,
                                               bf16* __restrict__ Sb,
                                               const float* __restrict__ wt,
                                               const float* __restrict__ bs) {
  __shared__ float w5[25][68];
  __shared__ float bb[64];
  int tid = threadIdx.x;
  for (int j = tid; j < 1600; j += 256) {
    int tap = j >> 6, c = j & 63;
    w5[tap][c] = wt[c * 25 + tap];
  }
  if (tid < 64) bb[tid] = bs[tid];
  __syncthreads();
  int blk = xcd_swz2048(blockIdx.x);
  int gid = blk * 256 + tid;
  int cg = gid & 15, pg = gid >> 4;
  int c0 = cg << 2;
  int w0 = (pg & 63) << 2, h = (pg >> 6) & 255, n = pg >> 14;
  int pbase = (n << 16) | (h << 8) | w0;
  float acc[4][4];
  {
    const float4 b4 = *(const float4*)&bb[c0];
#pragma unroll
    for (int px = 0; px < 4; px++) {
      acc[px][0] = b4.x; acc[px][1] = b4.y; acc[px][2] = b4.z; acc[px][3] = b4.w;
    }
  }
#pragma unroll
  for (int ky = 0; ky < 5; ky++) {
    int hh = h + ky - 2;
    if ((unsigned)hh >= 256u) continue;
    const bf16* vrow = V + (size_t)((n << 16) | (hh << 8)) * 64 + c0;
    float v[8][4];
#pragma unroll
    for (int dx = 0; dx < 8; dx++) {
      int ww = w0 + dx - 2;
      if ((unsigned)ww < 256u) ld4(vrow + (size_t)ww * 64, v[dx]);
      else { v[dx][0] = 0.f; v[dx][1] = 0.f; v[dx][2] = 0.f; v[dx][3] = 0.f; }
    }
#pragma unroll
    for (int kx = 0; kx < 5; kx++) {
      const float4 wv = *(const float4*)&w5[ky * 5 + kx][c0];
#pragma unroll
      for (int px = 0; px < 4; px++) {
        acc[px][0] += wv.x * v[px + kx][0]; acc[px][1] += wv.y * v[px + kx][1];
        acc[px][2] += wv.z * v[px + kx][2]; acc[px][3] += wv.w * v[px + kx][3];
      }
    }
  }
#pragma unroll
  for (int px = 0; px < 4; px++) {
    float s4[4];
    ld4(Sbf + (size_t)(pbase + px) * 64 + c0, s4);
    float o[4] = {s4[0] + acc[px][0], s4[1] + acc[px][1],
                  s4[2] + acc[px][2], s4[3] + acc[px][3]};
    st4(Sb + (size_t)(pbase + px) * 64 + c0, o);
  }
}

extern "C" void kernel_launch(void* const* d_in, const int* in_sizes, int n_in,
                              void* d_out, int out_size, void* d_ws, size_t ws_size,
                              hipStream_t stream) {
  (void)in_sizes; (void)n_in; (void)out_size; (void)ws_size;
  const float* xin = (const float*)d_in[0];
  auto Wp = [&](int i) { return (const float*)d_in[i]; };
  char* ws = (char*)d_ws;
  const size_t MB = 1u << 20;
  float* X  = (float*)(ws + 0 * MB);
  float* A  = (float*)(ws + 32 * MB);
  float* T  = (float*)(ws + 64 * MB);
  char*  sm = ws + 128 * MB;
  size_t off = 0;
  auto alloc = [&](size_t bytes) {
    void* p = sm + off;
    off += (bytes + 255) & ~(size_t)255;
    return p;
  };
  float* Y8   = (float*)alloc(2 * 32 * 32 * 64 * 4);
  float* QW   = (float*)alloc(2 * 64 * 64 * 4);
  float* KW   = (float*)alloc(2 * 64 * 64 * 4);
  float* KVP  = (float*)alloc(2 * 64 * 16 * 128 * 4);
  int*  RIDX  = (int*)alloc(2 * 64 * 4 * 4);
  float* bc   = (float*)alloc(128 * 4);
  bf16* WTq   = (bf16*)alloc(128 * 64 * 2);
  bf16* WTo   = (bf16*)alloc(64 * 64 * 2);
  bf16* WT2   = (bf16*)alloc(64 * 128 * 2);
  bf16* WTf1  = (bf16*)alloc(256 * 64 * 2);
  float* qbs  = (float*)alloc(64 * 4);
  bf16* Vb   = (bf16*)(ws + 96 * MB);    // [P][64]
  bf16* Qb   = (bf16*)(ws + 112 * MB);   // [P][64]
  bf16* Sbf  = (bf16*)T;                 // [P][64]
  bf16* Sb   = (bf16*)(ws + 112 * MB);   // [P][64] (Qb dead after attn)
  bf16* VH   = (bf16*)A;                 // [P][128] (A consumed in-kernel)
  bf16* PWO  = (bf16*)T;                 // [P][128] (T/Sbf dead)

  k_in_tr<<<dim3(2048), dim3(256), 0, stream>>>(xin, X);
  for (int i = 0; i < 2; i++) {
    const float *posw = Wp(1) + i * 64 * 9, *posb = Wp(2) + i * 64;
    const float *l1g = Wp(3) + i * 64, *l1b = Wp(4) + i * 64;
    const float *qkvw = Wp(5) + i * 64 * 192, *qkvb = Wp(6) + i * 192;
    const float *lpw = Wp(7) + i * 64 * 25, *lpb = Wp(8) + i * 64;
    const float *wow = Wp(9) + i * 64 * 64, *wob = Wp(10) + i * 64;
    const float *l2g = Wp(11) + i * 64, *l2b = Wp(12) + i * 64;
    const float *f1w = Wp(13) + i * 64 * 256, *f1b = Wp(14) + i * 256;
    const float *pww = Wp(15) + i * 128 * 128;
    const float *dww = Wp(16) + i * 128 * 9, *dwb = Wp(17) + i * 128;
    const float *f2w = Wp(18) + i * 128 * 64, *f2b = Wp(19) + i * 64;

    k_prep<<<dim3(145), dim3(256), 0, stream>>>(qkvw, qkvb, wow, f2w, f1w, f1b, pww,
                                                WTq, WTo, WT2, WTf1, qbs, bc);
    k_pcln_qkv<<<dim3(2048), dim3(256), 0, stream>>>(
        X, A, T, posw, posb, l1g, l1b, WTq, qbs, qkvb + 128, Qb, Vb);
    k_pool8<<<dim3(2048), dim3(64), 0, stream>>>(T, Y8);
    k_qkwin2<<<dim3(64), dim3(256), 0, stream>>>(Y8, qkvw, qkvb, QW, KW);
    k_kvp<<<dim3(1024), dim3(256), 0, stream>>>(Y8, qkvw, qkvb, KVP);
    k_route<<<dim3(128), dim3(64), 0, stream>>>(QW, KW, RIDX);
    k_attn_mf<<<dim3(512), dim3(256), 0, stream>>>(Qb, KVP, RIDX, Sbf);
    k_lepe4<<<dim3(2048), dim3(256), 0, stream>>>(Vb, Sbf, Sb, lpw, lpb);
    k_wo_ln_fc1<<<dim3(Pp / 128), dim3(256), 0, stream>>>(
        Sb, WTo, wob, A, X, l2g, l2b, WTf1, f1b + 128, bc, VH, PWO);
    k_glu_fc2<<<dim3(2048), dim3(256), 0, stream>>>(PWO, VH, dww, dwb, WT2, f2b, X);
  }
  k_out<<<dim3(2048), dim3(256), 0, stream>>>(X, (float*)d_out);
}